// Round 1
// baseline (2278.579 us; speedup 1.0000x reference)
//
#include <hip/hip_runtime.h>
#include <cstddef>

// Shapes (fixed)
#define NB 512     // batch B
#define NM 64      // M sentences
#define NV 20000   // vocab V
#define NE 1024    // E
#define ND 384     // D
#define NT 100     // T topics
#define EPS 1e-5f

__device__ __forceinline__ float softplus_f(float x) {
    return fmaxf(x, 0.f) + log1pf(expf(-fabsf(x)));
}

// ---------------------------------------------------------------------------
// Generic tiled GEMM: C[m,n] = act( sum_k A[m,k]*Bw[n,k] + bias[n] )
// A: [M,K] row-major, Bw: [N,K] row-major (i.e. B^T layout). ACT: 0=none, 1=softplus.
// Tiles 64x64x16, 256 threads, 4x4 per thread.
// ---------------------------------------------------------------------------
template<int ACT>
__global__ __launch_bounds__(256) void gemm_bt(const float* __restrict__ A,
                                               const float* __restrict__ Bw,
                                               const float* __restrict__ bias,
                                               float* __restrict__ C,
                                               int M, int N, int K) {
    __shared__ float As[16][65];
    __shared__ float Bs[16][65];
    const int tid = threadIdx.x;
    const int tx = tid & 15, ty = tid >> 4;
    const int row0 = blockIdx.y * 64, col0 = blockIdx.x * 64;
    const int lr = tid >> 2;        // 0..63
    const int lk = (tid & 3) * 4;   // 0,4,8,12

    float acc[4][4] = {};

    for (int k0 = 0; k0 < K; k0 += 16) {
        // load A tile (64 rows x 16 k)
        {
            const int r = row0 + lr;
            if (r < M && (k0 + lk + 3) < K) {
                const float4 v = *reinterpret_cast<const float4*>(&A[(size_t)r * K + k0 + lk]);
                As[lk + 0][lr] = v.x; As[lk + 1][lr] = v.y;
                As[lk + 2][lr] = v.z; As[lk + 3][lr] = v.w;
            } else {
                #pragma unroll
                for (int j = 0; j < 4; ++j) {
                    const int k = k0 + lk + j;
                    As[lk + j][lr] = (r < M && k < K) ? A[(size_t)r * K + k] : 0.f;
                }
            }
            const int n = col0 + lr;
            if (n < N && (k0 + lk + 3) < K) {
                const float4 v = *reinterpret_cast<const float4*>(&Bw[(size_t)n * K + k0 + lk]);
                Bs[lk + 0][lr] = v.x; Bs[lk + 1][lr] = v.y;
                Bs[lk + 2][lr] = v.z; Bs[lk + 3][lr] = v.w;
            } else {
                #pragma unroll
                for (int j = 0; j < 4; ++j) {
                    const int k = k0 + lk + j;
                    Bs[lk + j][lr] = (n < N && k < K) ? Bw[(size_t)n * K + k] : 0.f;
                }
            }
        }
        __syncthreads();
        #pragma unroll
        for (int kk = 0; kk < 16; ++kk) {
            float a[4], b[4];
            #pragma unroll
            for (int i = 0; i < 4; ++i) a[i] = As[kk][ty + 16 * i];
            #pragma unroll
            for (int j = 0; j < 4; ++j) b[j] = Bs[kk][tx + 16 * j];
            #pragma unroll
            for (int i = 0; i < 4; ++i)
                #pragma unroll
                for (int j = 0; j < 4; ++j)
                    acc[i][j] = fmaf(a[i], b[j], acc[i][j]);
        }
        __syncthreads();
    }

    #pragma unroll
    for (int i = 0; i < 4; ++i) {
        const int row = row0 + ty + 16 * i;
        #pragma unroll
        for (int j = 0; j < 4; ++j) {
            const int col = col0 + tx + 16 * j;
            if (row < M && col < N) {
                float v = acc[i][j] + bias[col];
                if (ACT == 1) v = softplus_f(v);
                C[(size_t)row * N + col] = v;
            }
        }
    }
}

// ---------------------------------------------------------------------------
// qk = q @ k_w  (C[m,n] = sum_k A[m,k]*B[k,n]); tiny GEMM, naive.
// ---------------------------------------------------------------------------
__global__ __launch_bounds__(128) void gemm_nn(const float* __restrict__ A,
                                               const float* __restrict__ B,
                                               float* __restrict__ C,
                                               int M, int N, int K) {
    const int n = blockIdx.x * 128 + threadIdx.x;
    const int m = blockIdx.y;
    if (n >= N) return;
    float acc = 0.f;
    for (int k = 0; k < K; ++k)
        acc = fmaf(A[(size_t)m * K + k], B[(size_t)k * N + n], acc);
    C[(size_t)m * N + n] = acc;
}

// ---------------------------------------------------------------------------
// Fused ragged attention: scores -> masked softmax -> c[b,d] = sum_m alpha*emb
// qk: [B,D]; emb: [B,M,D]; lengths: [B]; c: [B,D]
// (q . k_b term is constant over m -> cancels in softmax, dropped.)
// ---------------------------------------------------------------------------
__global__ __launch_bounds__(256) void attn_kernel(const float* __restrict__ qk,
                                                   const float* __restrict__ emb,
                                                   const int* __restrict__ lengths,
                                                   float* __restrict__ c) {
    const int b = blockIdx.x;
    const int tid = threadIdx.x;
    __shared__ float qs[ND];
    __shared__ float sc[NM];   // scores then alpha

    for (int d = tid; d < ND; d += 256) qs[d] = qk[(size_t)b * ND + d];
    __syncthreads();

    const int wave = tid >> 6, lane = tid & 63;
    const float scale = 0.05103103630798288f;  // 1/sqrt(384)
    const float* eb = emb + (size_t)b * NM * ND;

    for (int m = wave; m < NM; m += 4) {
        float s = 0.f;
        for (int d = lane; d < ND; d += 64) s = fmaf(eb[m * ND + d], qs[d], s);
        #pragma unroll
        for (int off = 32; off; off >>= 1) s += __shfl_xor(s, off);
        if (lane == 0) sc[m] = s * scale;
    }
    __syncthreads();

    const int len = lengths[b];
    if (tid < 64) {
        float s = (tid < len) ? sc[tid] : -INFINITY;
        float mx = s;
        #pragma unroll
        for (int off = 32; off; off >>= 1) mx = fmaxf(mx, __shfl_xor(mx, off));
        float e = (tid < len) ? expf(s - mx) : 0.f;
        float sum = e;
        #pragma unroll
        for (int off = 32; off; off >>= 1) sum += __shfl_xor(sum, off);
        sc[tid] = e / sum;
    }
    __syncthreads();

    for (int d = tid; d < ND; d += 256) {
        float acc = 0.f;
        for (int m = 0; m < len; ++m) acc = fmaf(sc[m], eb[m * ND + d], acc);
        c[(size_t)b * ND + d] = acc;
    }
}

// ---------------------------------------------------------------------------
// BatchNorm over batch axis for mu_pre / lv_pre ([B,T]); grid (T, 2).
// ---------------------------------------------------------------------------
__global__ __launch_bounds__(256) void bn_batch(const float* __restrict__ mu_pre,
                                                const float* __restrict__ lv_pre,
                                                const float* __restrict__ mbnb,
                                                const float* __restrict__ lbnb,
                                                float* __restrict__ mu,
                                                float* __restrict__ lv) {
    const int t = blockIdx.x;
    const int sel = blockIdx.y;
    const float* src = sel ? lv_pre : mu_pre;
    const float* bnb = sel ? lbnb : mbnb;
    float* dst = sel ? lv : mu;
    const int tid = threadIdx.x;

    float s = 0.f, ss = 0.f;
    for (int b = tid; b < NB; b += 256) {
        const float v = src[(size_t)b * NT + t];
        s += v; ss += v * v;
    }
    __shared__ float rs[256], rss[256];
    rs[tid] = s; rss[tid] = ss;
    __syncthreads();
    for (int off = 128; off; off >>= 1) {
        if (tid < off) { rs[tid] += rs[tid + off]; rss[tid] += rss[tid + off]; }
        __syncthreads();
    }
    const float mean = rs[0] / (float)NB;
    const float var = rss[0] / (float)NB - mean * mean;
    const float rstd = rsqrtf(var + EPS);
    const float bb = bnb[t];
    for (int b = tid; b < NB; b += 256) {
        dst[(size_t)b * NT + t] = (src[(size_t)b * NT + t] - mean) * rstd + bb;
    }
}

// ---------------------------------------------------------------------------
// Per-row softmax over T (theta) + KL partial per row.
// ---------------------------------------------------------------------------
__global__ __launch_bounds__(128) void theta_kl(const float* __restrict__ mu,
                                                const float* __restrict__ lv,
                                                float* __restrict__ theta,
                                                float* __restrict__ kld_p) {
    const int b = blockIdx.x, tid = threadIdx.x;
    const float var2 = 1.0f - 1.0f / (float)NT;     // 0.99
    const float inv_var2 = 1.0f / var2;
    __shared__ float red[128];

    const float m = (tid < NT) ? mu[(size_t)b * NT + tid] : -INFINITY;
    red[tid] = m;
    __syncthreads();
    for (int off = 64; off; off >>= 1) {
        if (tid < off) red[tid] = fmaxf(red[tid], red[tid + off]);
        __syncthreads();
    }
    const float mx = red[0];
    __syncthreads();

    const float e = (tid < NT) ? expf(m - mx) : 0.f;
    red[tid] = e;
    __syncthreads();
    for (int off = 64; off; off >>= 1) {
        if (tid < off) red[tid] += red[tid + off];
        __syncthreads();
    }
    const float sum = red[0];
    __syncthreads();
    if (tid < NT) theta[(size_t)b * NT + tid] = e / sum;

    float term = 0.f;
    if (tid < NT) {
        const float l = lv[(size_t)b * NT + tid];
        term = expf(l) * inv_var2 + m * m * inv_var2 - l;
    }
    red[tid] = term;
    __syncthreads();
    for (int off = 64; off; off >>= 1) {
        if (tid < off) red[tid] += red[tid + off];
        __syncthreads();
    }
    if (tid == 0)
        kld_p[b] = 0.5f * (red[0] + (float)NT * logf(var2) - (float)NT);
}

// ---------------------------------------------------------------------------
// Per-column (feature) BN stats over batch for logit [B,V].
// ---------------------------------------------------------------------------
__global__ __launch_bounds__(256) void col_stats(const float* __restrict__ logit,
                                                 float* __restrict__ cmu,
                                                 float* __restrict__ crstd) {
    const int v = blockIdx.x * 256 + threadIdx.x;
    if (v >= NV) return;
    float s = 0.f, ss = 0.f;
    for (int b = 0; b < NB; ++b) {
        const float x = logit[(size_t)b * NV + v];
        s += x; ss += x * x;
    }
    const float mean = s / (float)NB;
    cmu[v] = mean;
    crstd[v] = rsqrtf(ss / (float)NB - mean * mean + EPS);
}

// ---------------------------------------------------------------------------
// Per-row: z = (logit-cmu)*crstd + dbnb; online logsumexp; then
// recon_p[b] = sum_v x[b,v] * (z - lse)   (log_softmax dot x)
// ---------------------------------------------------------------------------
__global__ __launch_bounds__(256) void row_recon(const float* __restrict__ logit,
                                                 const float* __restrict__ cmu,
                                                 const float* __restrict__ crstd,
                                                 const float* __restrict__ dbnb,
                                                 const float* __restrict__ x,
                                                 float* __restrict__ recon_p) {
    const int b = blockIdx.x, tid = threadIdx.x;
    const float* lr = logit + (size_t)b * NV;
    const float* xr = x + (size_t)b * NV;

    // pass 1: online LSE
    float m_i = -INFINITY, s_i = 0.f;
    for (int v = tid; v < NV; v += 256) {
        const float z = (lr[v] - cmu[v]) * crstd[v] + dbnb[v];
        if (z > m_i) { s_i = s_i * expf(m_i - z) + 1.f; m_i = z; }
        else s_i += expf(z - m_i);
    }
    __shared__ float rm[256], rsum[256];
    rm[tid] = m_i; rsum[tid] = s_i;
    __syncthreads();
    for (int off = 128; off; off >>= 1) {
        if (tid < off) {
            const float m1 = rm[tid], m2 = rm[tid + off];
            const float s1 = rsum[tid], s2 = rsum[tid + off];
            const float mm = fmaxf(m1, m2);
            rm[tid] = mm;
            rsum[tid] = s1 * expf(m1 - mm) + s2 * expf(m2 - mm);
        }
        __syncthreads();
    }
    const float lse = rm[0] + logf(rsum[0]);
    __syncthreads();

    // pass 2: dot with x
    float acc = 0.f;
    for (int v = tid; v < NV; v += 256) {
        const float z = (lr[v] - cmu[v]) * crstd[v] + dbnb[v];
        acc = fmaf(xr[v], z - lse, acc);
    }
    rsum[tid] = acc;
    __syncthreads();
    for (int off = 128; off; off >>= 1) {
        if (tid < off) rsum[tid] += rsum[tid + off];
        __syncthreads();
    }
    if (tid == 0) recon_p[b] = rsum[0];
}

// ---------------------------------------------------------------------------
// Final: out = -mean(recon_p) + mean(kld_p)
// ---------------------------------------------------------------------------
__global__ __launch_bounds__(512) void finalize(const float* __restrict__ recon_p,
                                                const float* __restrict__ kld_p,
                                                float* __restrict__ out) {
    const int tid = threadIdx.x;
    __shared__ float r1[512], r2[512];
    r1[tid] = recon_p[tid];
    r2[tid] = kld_p[tid];
    __syncthreads();
    for (int off = 256; off; off >>= 1) {
        if (tid < off) { r1[tid] += r1[tid + off]; r2[tid] += r2[tid + off]; }
        __syncthreads();
    }
    if (tid == 0) out[0] = (-r1[0] + r2[0]) / (float)NB;
}

extern "C" void kernel_launch(void* const* d_in, const int* in_sizes, int n_in,
                              void* d_out, int out_size, void* d_ws, size_t ws_size,
                              hipStream_t stream) {
    const float* x       = (const float*)d_in[0];
    const float* emb     = (const float*)d_in[1];
    const int*   lengths = (const int*)d_in[2];
    const float* fc11_w  = (const float*)d_in[3];
    const float* fc11_b  = (const float*)d_in[4];
    const float* fc12_w  = (const float*)d_in[5];
    const float* fc12_b  = (const float*)d_in[6];
    const float* q_w     = (const float*)d_in[7];
    const float* q_b     = (const float*)d_in[8];
    const float* k_w     = (const float*)d_in[9];
    // d_in[10] = k_b: constant-over-m shift, cancels in softmax -> unused
    const float* v_w     = (const float*)d_in[11];
    const float* v_b     = (const float*)d_in[12];
    const float* mean_w  = (const float*)d_in[13];
    const float* mean_b  = (const float*)d_in[14];
    const float* lvw     = (const float*)d_in[15];
    const float* lvb     = (const float*)d_in[16];
    const float* mbnb    = (const float*)d_in[17];
    const float* lbnb    = (const float*)d_in[18];
    const float* dec_w   = (const float*)d_in[19];
    const float* dec_b   = (const float*)d_in[20];
    const float* dbnb    = (const float*)d_in[21];
    float* out = (float*)d_out;

    float* w = (float*)d_ws;
    float* e1    = w;  w += (size_t)NB * NE;
    float* h     = w;  w += (size_t)NB * NE;
    float* q     = w;  w += (size_t)NB * ND;
    float* qk    = w;  w += (size_t)NB * ND;
    float* c     = w;  w += (size_t)NB * ND;
    float* di    = w;  w += (size_t)NB * ND;
    float* mupre = w;  w += (size_t)NB * NT;
    float* lvpre = w;  w += (size_t)NB * NT;
    float* mu    = w;  w += (size_t)NB * NT;
    float* lv    = w;  w += (size_t)NB * NT;
    float* theta = w;  w += (size_t)NB * NT;
    float* logit = w;  w += (size_t)NB * NV;
    float* cmu   = w;  w += NV;
    float* crstd = w;  w += NV;
    float* rp    = w;  w += NB;
    float* kp    = w;  w += NB;

    const dim3 blk(256);

    // encoder MLP
    gemm_bt<1><<<dim3(16, 8), blk, 0, stream>>>(x, fc11_w, fc11_b, e1, NB, NE, NV);
    gemm_bt<1><<<dim3(16, 8), blk, 0, stream>>>(e1, fc12_w, fc12_b, h, NB, NE, NE);
    // q projection
    gemm_bt<0><<<dim3(6, 8), blk, 0, stream>>>(h, q_w, q_b, q, NB, ND, NE);
    // qk = q @ k_w
    gemm_nn<<<dim3(3, NB), dim3(128), 0, stream>>>(q, k_w, qk, NB, ND, ND);
    // fused attention -> c = sum_m alpha*emb
    attn_kernel<<<NB, 256, 0, stream>>>(qk, emb, lengths, c);
    // d_i = c @ v_w^T + v_b
    gemm_bt<0><<<dim3(6, 8), blk, 0, stream>>>(c, v_w, v_b, di, NB, ND, ND);
    // mean / logvar heads
    gemm_bt<0><<<dim3(2, 8), blk, 0, stream>>>(di, mean_w, mean_b, mupre, NB, NT, ND);
    gemm_bt<0><<<dim3(2, 8), blk, 0, stream>>>(di, lvw, lvb, lvpre, NB, NT, ND);
    // batchnorm both heads
    bn_batch<<<dim3(NT, 2), 256, 0, stream>>>(mupre, lvpre, mbnb, lbnb, mu, lv);
    // theta softmax + KL partials
    theta_kl<<<NB, 128, 0, stream>>>(mu, lv, theta, kp);
    // decoder logits
    gemm_bt<0><<<dim3(313, 8), blk, 0, stream>>>(theta, dec_w, dec_b, logit, NB, NV, NT);
    // column BN stats
    col_stats<<<(NV + 255) / 256, 256, 0, stream>>>(logit, cmu, crstd);
    // per-row log-softmax dot x
    row_recon<<<NB, 256, 0, stream>>>(logit, cmu, crstd, dbnb, x, rp);
    // final scalar
    finalize<<<1, 512, 0, stream>>>(rp, kp, out);
}

// Round 2
// 632.603 us; speedup vs baseline: 3.6019x; 3.6019x over previous
//
#include <hip/hip_runtime.h>
#include <cstddef>

// Shapes (fixed)
#define NB 512     // batch B
#define NM 64      // M sentences
#define NV 20000   // vocab V
#define NE 1024    // E
#define ND 384     // D
#define NT 100     // T topics
#define EPS 1e-5f

typedef __bf16 bf16x8 __attribute__((ext_vector_type(8)));
typedef float f32x4 __attribute__((ext_vector_type(4)));

__device__ __forceinline__ float softplus_f(float x) {
    return fmaxf(x, 0.f) + log1pf(expf(-fabsf(x)));
}

__device__ __forceinline__ unsigned short f2bf(float f) {
    unsigned u = __builtin_bit_cast(unsigned, f);
    unsigned r = u + 0x7FFFu + ((u >> 16) & 1u);   // RNE
    return (unsigned short)(r >> 16);
}

// ---------------------------------------------------------------------------
// f32 -> bf16 bulk convert; each thread does 8 elements (32B in, 16B out).
// Grid must satisfy grid*256*8 == n exactly (all our sizes are multiples).
// ---------------------------------------------------------------------------
__global__ __launch_bounds__(256) void f32_to_bf16_vec(const float* __restrict__ in,
                                                       unsigned short* __restrict__ out) {
    const size_t i = ((size_t)blockIdx.x * 256 + threadIdx.x) * 8;
    const float4 a = *reinterpret_cast<const float4*>(in + i);
    const float4 b = *reinterpret_cast<const float4*>(in + i + 4);
    union { unsigned short u[8]; uint4 v; } r;
    r.u[0] = f2bf(a.x); r.u[1] = f2bf(a.y); r.u[2] = f2bf(a.z); r.u[3] = f2bf(a.w);
    r.u[4] = f2bf(b.x); r.u[5] = f2bf(b.y); r.u[6] = f2bf(b.z); r.u[7] = f2bf(b.w);
    *reinterpret_cast<uint4*>(out + i) = r.v;
}

// ---------------------------------------------------------------------------
// Split-K bf16 MFMA GEMM: partial[s][m][n] = sum_{k in chunk s} A[m,k]*Bw[n,k]
// A: [M,K] bf16 row-major; Bw: [N,K] bf16 row-major (B^T layout).
// 128x128 tile, BK=32, 256 threads = 4 waves (2x2), each wave 4x4 frags of
// 16x16x32. global_load_lds width-16 staging (m97 structure).
// M,N multiples of 128; K multiple of 32.
// ---------------------------------------------------------------------------
#define BM 128
#define BN 128
#define BK 32

__global__ __launch_bounds__(256) void gemm_mfma_splitk(
        const unsigned short* __restrict__ A,
        const unsigned short* __restrict__ Bw,
        float* __restrict__ partial,
        int M, int N, int K, int S, int steps_total) {
    __shared__ __align__(16) unsigned short Asl[BM * BK];  // 8 KB
    __shared__ __align__(16) unsigned short Bsl[BN * BK];  // 8 KB
    const int tid = threadIdx.x;
    const int bn = blockIdx.x, bm = blockIdx.y, s = blockIdx.z;
    const int row0 = bm * BM, col0 = bn * BN;
    const int k_begin = (int)(((long)s * steps_total) / S) * BK;
    const int k_end   = (int)(((long)(s + 1) * steps_total) / S) * BK;

    // staging coords: issue i covers linear ids li = i*256+tid, 8 bf16 each
    const int srow = tid >> 2;            // + i*64
    const int scol = (tid & 3) * 8;

    const int wave = tid >> 6, lane = tid & 63;
    const int wm = wave >> 1, wn = wave & 1;       // 2x2 wave grid
    const int lrow = lane & 15, lkb = lane >> 4;   // frag index, k-subgroup

    f32x4 acc[4][4] = {};

    const unsigned short* Ab = A + (size_t)row0 * K;
    const unsigned short* Bb = Bw + (size_t)col0 * K;

    for (int k0 = k_begin; k0 < k_end; k0 += BK) {
        #pragma unroll
        for (int i = 0; i < 2; ++i) {
            const int r = i * 64 + srow;
            __builtin_amdgcn_global_load_lds(
                (const __attribute__((address_space(1))) void*)(Ab + (size_t)r * K + k0 + scol),
                (__attribute__((address_space(3))) void*)(&Asl[(i * 256 + tid) * 8]),
                16, 0, 0);
            __builtin_amdgcn_global_load_lds(
                (const __attribute__((address_space(1))) void*)(Bb + (size_t)r * K + k0 + scol),
                (__attribute__((address_space(3))) void*)(&Bsl[(i * 256 + tid) * 8]),
                16, 0, 0);
        }
        __syncthreads();

        bf16x8 af[4], bfr[4];
        #pragma unroll
        for (int i = 0; i < 4; ++i) {
            af[i]  = *reinterpret_cast<const bf16x8*>(&Asl[(wm * 64 + i * 16 + lrow) * BK + lkb * 8]);
            bfr[i] = *reinterpret_cast<const bf16x8*>(&Bsl[(wn * 64 + i * 16 + lrow) * BK + lkb * 8]);
        }
        #pragma unroll
        for (int i = 0; i < 4; ++i)
            #pragma unroll
            for (int j = 0; j < 4; ++j)
                acc[i][j] = __builtin_amdgcn_mfma_f32_16x16x32_bf16(af[i], bfr[j], acc[i][j], 0, 0, 0);
        __syncthreads();
    }

    float* P = partial + (size_t)s * M * N;
    #pragma unroll
    for (int i = 0; i < 4; ++i) {
        const int rbase = row0 + wm * 64 + i * 16 + lkb * 4;
        #pragma unroll
        for (int j = 0; j < 4; ++j) {
            const int col = col0 + wn * 64 + j * 16 + lrow;
            #pragma unroll
            for (int r = 0; r < 4; ++r)
                P[(size_t)(rbase + r) * N + col] = acc[i][j][r];
        }
    }
}

// ---------------------------------------------------------------------------
// Split-K reduce + bias + optional softplus; output f32 or bf16.
// ---------------------------------------------------------------------------
template<int OUT_BF16, int ACT>
__global__ __launch_bounds__(256) void reduce_splitk(const float* __restrict__ partial,
                                                     const float* __restrict__ bias,
                                                     void* __restrict__ out,
                                                     int MN, int N, int S) {
    const int i = blockIdx.x * 256 + threadIdx.x;
    if (i >= MN) return;
    float sum = 0.f;
    for (int s = 0; s < S; ++s) sum += partial[(size_t)s * MN + i];
    sum += bias[i % N];
    if (ACT) sum = softplus_f(sum);
    if (OUT_BF16) ((unsigned short*)out)[i] = f2bf(sum);
    else          ((float*)out)[i] = sum;
}

// ---------------------------------------------------------------------------
// Generic tiled fp32 GEMM: C[m,n] = act( sum_k A[m,k]*Bw[n,k] + bias[n] )
// ---------------------------------------------------------------------------
template<int ACT>
__global__ __launch_bounds__(256) void gemm_bt(const float* __restrict__ A,
                                               const float* __restrict__ Bw,
                                               const float* __restrict__ bias,
                                               float* __restrict__ C,
                                               int M, int N, int K) {
    __shared__ float As[16][65];
    __shared__ float Bs[16][65];
    const int tid = threadIdx.x;
    const int tx = tid & 15, ty = tid >> 4;
    const int row0 = blockIdx.y * 64, col0 = blockIdx.x * 64;
    const int lr = tid >> 2;
    const int lk = (tid & 3) * 4;

    float acc[4][4] = {};

    for (int k0 = 0; k0 < K; k0 += 16) {
        {
            const int r = row0 + lr;
            if (r < M && (k0 + lk + 3) < K) {
                const float4 v = *reinterpret_cast<const float4*>(&A[(size_t)r * K + k0 + lk]);
                As[lk + 0][lr] = v.x; As[lk + 1][lr] = v.y;
                As[lk + 2][lr] = v.z; As[lk + 3][lr] = v.w;
            } else {
                #pragma unroll
                for (int j = 0; j < 4; ++j) {
                    const int k = k0 + lk + j;
                    As[lk + j][lr] = (r < M && k < K) ? A[(size_t)r * K + k] : 0.f;
                }
            }
            const int n = col0 + lr;
            if (n < N && (k0 + lk + 3) < K) {
                const float4 v = *reinterpret_cast<const float4*>(&Bw[(size_t)n * K + k0 + lk]);
                Bs[lk + 0][lr] = v.x; Bs[lk + 1][lr] = v.y;
                Bs[lk + 2][lr] = v.z; Bs[lk + 3][lr] = v.w;
            } else {
                #pragma unroll
                for (int j = 0; j < 4; ++j) {
                    const int k = k0 + lk + j;
                    Bs[lk + j][lr] = (n < N && k < K) ? Bw[(size_t)n * K + k] : 0.f;
                }
            }
        }
        __syncthreads();
        #pragma unroll
        for (int kk = 0; kk < 16; ++kk) {
            float a[4], b[4];
            #pragma unroll
            for (int i = 0; i < 4; ++i) a[i] = As[kk][ty + 16 * i];
            #pragma unroll
            for (int j = 0; j < 4; ++j) b[j] = Bs[kk][tx + 16 * j];
            #pragma unroll
            for (int i = 0; i < 4; ++i)
                #pragma unroll
                for (int j = 0; j < 4; ++j)
                    acc[i][j] = fmaf(a[i], b[j], acc[i][j]);
        }
        __syncthreads();
    }

    #pragma unroll
    for (int i = 0; i < 4; ++i) {
        const int row = row0 + ty + 16 * i;
        #pragma unroll
        for (int j = 0; j < 4; ++j) {
            const int col = col0 + tx + 16 * j;
            if (row < M && col < N) {
                float v = acc[i][j] + bias[col];
                if (ACT == 1) v = softplus_f(v);
                C[(size_t)row * N + col] = v;
            }
        }
    }
}

// ---------------------------------------------------------------------------
// qk = q @ k_w  (C[m,n] = sum_k A[m,k]*B[k,n]); tiny GEMM, naive.
// ---------------------------------------------------------------------------
__global__ __launch_bounds__(128) void gemm_nn(const float* __restrict__ A,
                                               const float* __restrict__ B,
                                               float* __restrict__ C,
                                               int M, int N, int K) {
    const int n = blockIdx.x * 128 + threadIdx.x;
    const int m = blockIdx.y;
    if (n >= N) return;
    float acc = 0.f;
    for (int k = 0; k < K; ++k)
        acc = fmaf(A[(size_t)m * K + k], B[(size_t)k * N + n], acc);
    C[(size_t)m * N + n] = acc;
}

// ---------------------------------------------------------------------------
// Fused ragged attention: scores -> masked softmax -> c[b,d] = sum_m alpha*emb
// (q . k_b is constant over m -> cancels in softmax, dropped.)
// ---------------------------------------------------------------------------
__global__ __launch_bounds__(256) void attn_kernel(const float* __restrict__ qk,
                                                   const float* __restrict__ emb,
                                                   const int* __restrict__ lengths,
                                                   float* __restrict__ c) {
    const int b = blockIdx.x;
    const int tid = threadIdx.x;
    __shared__ float qs[ND];
    __shared__ float sc[NM];

    for (int d = tid; d < ND; d += 256) qs[d] = qk[(size_t)b * ND + d];
    __syncthreads();

    const int wave = tid >> 6, lane = tid & 63;
    const float scale = 0.05103103630798288f;  // 1/sqrt(384)
    const float* eb = emb + (size_t)b * NM * ND;

    for (int m = wave; m < NM; m += 4) {
        float s = 0.f;
        for (int d = lane; d < ND; d += 64) s = fmaf(eb[m * ND + d], qs[d], s);
        #pragma unroll
        for (int off = 32; off; off >>= 1) s += __shfl_xor(s, off);
        if (lane == 0) sc[m] = s * scale;
    }
    __syncthreads();

    const int len = lengths[b];
    if (tid < 64) {
        float s = (tid < len) ? sc[tid] : -INFINITY;
        float mx = s;
        #pragma unroll
        for (int off = 32; off; off >>= 1) mx = fmaxf(mx, __shfl_xor(mx, off));
        float e = (tid < len) ? expf(s - mx) : 0.f;
        float sum = e;
        #pragma unroll
        for (int off = 32; off; off >>= 1) sum += __shfl_xor(sum, off);
        sc[tid] = e / sum;
    }
    __syncthreads();

    for (int d = tid; d < ND; d += 256) {
        float acc = 0.f;
        for (int m = 0; m < len; ++m) acc = fmaf(sc[m], eb[m * ND + d], acc);
        c[(size_t)b * ND + d] = acc;
    }
}

// ---------------------------------------------------------------------------
// BatchNorm over batch axis for mu_pre / lv_pre ([B,T]); grid (T, 2).
// ---------------------------------------------------------------------------
__global__ __launch_bounds__(256) void bn_batch(const float* __restrict__ mu_pre,
                                                const float* __restrict__ lv_pre,
                                                const float* __restrict__ mbnb,
                                                const float* __restrict__ lbnb,
                                                float* __restrict__ mu,
                                                float* __restrict__ lv) {
    const int t = blockIdx.x;
    const int sel = blockIdx.y;
    const float* src = sel ? lv_pre : mu_pre;
    const float* bnb = sel ? lbnb : mbnb;
    float* dst = sel ? lv : mu;
    const int tid = threadIdx.x;

    float s = 0.f, ss = 0.f;
    for (int b = tid; b < NB; b += 256) {
        const float v = src[(size_t)b * NT + t];
        s += v; ss += v * v;
    }
    __shared__ float rs[256], rss[256];
    rs[tid] = s; rss[tid] = ss;
    __syncthreads();
    for (int off = 128; off; off >>= 1) {
        if (tid < off) { rs[tid] += rs[tid + off]; rss[tid] += rss[tid + off]; }
        __syncthreads();
    }
    const float mean = rs[0] / (float)NB;
    const float var = rss[0] / (float)NB - mean * mean;
    const float rstd = rsqrtf(var + EPS);
    const float bb = bnb[t];
    for (int b = tid; b < NB; b += 256) {
        dst[(size_t)b * NT + t] = (src[(size_t)b * NT + t] - mean) * rstd + bb;
    }
}

// ---------------------------------------------------------------------------
// Per-row softmax over T (theta) + KL partial per row.
// ---------------------------------------------------------------------------
__global__ __launch_bounds__(128) void theta_kl(const float* __restrict__ mu,
                                                const float* __restrict__ lv,
                                                float* __restrict__ theta,
                                                float* __restrict__ kld_p) {
    const int b = blockIdx.x, tid = threadIdx.x;
    const float var2 = 1.0f - 1.0f / (float)NT;
    const float inv_var2 = 1.0f / var2;
    __shared__ float red[128];

    const float m = (tid < NT) ? mu[(size_t)b * NT + tid] : -INFINITY;
    red[tid] = m;
    __syncthreads();
    for (int off = 64; off; off >>= 1) {
        if (tid < off) red[tid] = fmaxf(red[tid], red[tid + off]);
        __syncthreads();
    }
    const float mx = red[0];
    __syncthreads();

    const float e = (tid < NT) ? expf(m - mx) : 0.f;
    red[tid] = e;
    __syncthreads();
    for (int off = 64; off; off >>= 1) {
        if (tid < off) red[tid] += red[tid + off];
        __syncthreads();
    }
    const float sum = red[0];
    __syncthreads();
    if (tid < NT) theta[(size_t)b * NT + tid] = e / sum;

    float term = 0.f;
    if (tid < NT) {
        const float l = lv[(size_t)b * NT + tid];
        term = expf(l) * inv_var2 + m * m * inv_var2 - l;
    }
    red[tid] = term;
    __syncthreads();
    for (int off = 64; off; off >>= 1) {
        if (tid < off) red[tid] += red[tid + off];
        __syncthreads();
    }
    if (tid == 0)
        kld_p[b] = 0.5f * (red[0] + (float)NT * logf(var2) - (float)NT);
}

// ---------------------------------------------------------------------------
// Per-column (feature) BN stats over batch for logit [B,V].
// ---------------------------------------------------------------------------
__global__ __launch_bounds__(256) void col_stats(const float* __restrict__ logit,
                                                 float* __restrict__ cmu,
                                                 float* __restrict__ crstd) {
    const int v = blockIdx.x * 256 + threadIdx.x;
    if (v >= NV) return;
    float s = 0.f, ss = 0.f;
    for (int b = 0; b < NB; ++b) {
        const float x = logit[(size_t)b * NV + v];
        s += x; ss += x * x;
    }
    const float mean = s / (float)NB;
    cmu[v] = mean;
    crstd[v] = rsqrtf(ss / (float)NB - mean * mean + EPS);
}

// ---------------------------------------------------------------------------
// Per-row: z = (logit-cmu)*crstd + dbnb; online LSE; recon_p[b] = sum x*(z-lse)
// ---------------------------------------------------------------------------
__global__ __launch_bounds__(256) void row_recon(const float* __restrict__ logit,
                                                 const float* __restrict__ cmu,
                                                 const float* __restrict__ crstd,
                                                 const float* __restrict__ dbnb,
                                                 const float* __restrict__ x,
                                                 float* __restrict__ recon_p) {
    const int b = blockIdx.x, tid = threadIdx.x;
    const float* lr = logit + (size_t)b * NV;
    const float* xr = x + (size_t)b * NV;

    float m_i = -INFINITY, s_i = 0.f;
    for (int v = tid; v < NV; v += 256) {
        const float z = (lr[v] - cmu[v]) * crstd[v] + dbnb[v];
        if (z > m_i) { s_i = s_i * expf(m_i - z) + 1.f; m_i = z; }
        else s_i += expf(z - m_i);
    }
    __shared__ float rm[256], rsum[256];
    rm[tid] = m_i; rsum[tid] = s_i;
    __syncthreads();
    for (int off = 128; off; off >>= 1) {
        if (tid < off) {
            const float m1 = rm[tid], m2 = rm[tid + off];
            const float s1 = rsum[tid], s2 = rsum[tid + off];
            const float mm = fmaxf(m1, m2);
            rm[tid] = mm;
            rsum[tid] = s1 * expf(m1 - mm) + s2 * expf(m2 - mm);
        }
        __syncthreads();
    }
    const float lse = rm[0] + logf(rsum[0]);
    __syncthreads();

    float acc = 0.f;
    for (int v = tid; v < NV; v += 256) {
        const float z = (lr[v] - cmu[v]) * crstd[v] + dbnb[v];
        acc = fmaf(xr[v], z - lse, acc);
    }
    rsum[tid] = acc;
    __syncthreads();
    for (int off = 128; off; off >>= 1) {
        if (tid < off) rsum[tid] += rsum[tid + off];
        __syncthreads();
    }
    if (tid == 0) recon_p[b] = rsum[0];
}

// ---------------------------------------------------------------------------
// Final: out = -mean(recon_p) + mean(kld_p)
// ---------------------------------------------------------------------------
__global__ __launch_bounds__(512) void finalize(const float* __restrict__ recon_p,
                                                const float* __restrict__ kld_p,
                                                float* __restrict__ out) {
    const int tid = threadIdx.x;
    __shared__ float r1[512], r2[512];
    r1[tid] = recon_p[tid];
    r2[tid] = kld_p[tid];
    __syncthreads();
    for (int off = 256; off; off >>= 1) {
        if (tid < off) { r1[tid] += r1[tid + off]; r2[tid] += r2[tid + off]; }
        __syncthreads();
    }
    if (tid == 0) out[0] = (-r1[0] + r2[0]) / (float)NB;
}

extern "C" void kernel_launch(void* const* d_in, const int* in_sizes, int n_in,
                              void* d_out, int out_size, void* d_ws, size_t ws_size,
                              hipStream_t stream) {
    const float* x       = (const float*)d_in[0];
    const float* emb     = (const float*)d_in[1];
    const int*   lengths = (const int*)d_in[2];
    const float* fc11_w  = (const float*)d_in[3];
    const float* fc11_b  = (const float*)d_in[4];
    const float* fc12_w  = (const float*)d_in[5];
    const float* fc12_b  = (const float*)d_in[6];
    const float* q_w     = (const float*)d_in[7];
    const float* q_b     = (const float*)d_in[8];
    const float* k_w     = (const float*)d_in[9];
    // d_in[10] = k_b: cancels in softmax -> unused
    const float* v_w     = (const float*)d_in[11];
    const float* v_b     = (const float*)d_in[12];
    const float* mean_w  = (const float*)d_in[13];
    const float* mean_b  = (const float*)d_in[14];
    const float* lvw     = (const float*)d_in[15];
    const float* lvb     = (const float*)d_in[16];
    const float* mbnb    = (const float*)d_in[17];
    const float* lbnb    = (const float*)d_in[18];
    const float* dec_w   = (const float*)d_in[19];
    const float* dec_b   = (const float*)d_in[20];
    const float* dbnb    = (const float*)d_in[21];
    float* out = (float*)d_out;

    char* base = (char*)d_ws;
    size_t off = 0;
    auto alloc = [&](size_t bytes) -> void* {
        void* p = base + off;
        off += (bytes + 255) & ~(size_t)255;
        return p;
    };

    // logit (f32, 40.96MB) aliases bf16 fc11_w (40.96MB): wb11 dead before
    // the decoder GEMM writes logit (stream-ordered).
    float*          logit = (float*)alloc((size_t)NB * NV * 4);
    unsigned short* wb11  = (unsigned short*)logit;
    unsigned short* xb    = (unsigned short*)alloc((size_t)NB * NV * 2);
    unsigned short* w12b  = (unsigned short*)alloc((size_t)NE * NE * 2);
    float*          part  = (float*)alloc((size_t)8 * NB * NE * 4);
    unsigned short* e1b   = (unsigned short*)alloc((size_t)NB * NE * 2);
    float* h     = (float*)alloc((size_t)NB * NE * 4);
    float* q     = (float*)alloc((size_t)NB * ND * 4);
    float* qk    = (float*)alloc((size_t)NB * ND * 4);
    float* c     = (float*)alloc((size_t)NB * ND * 4);
    float* di    = (float*)alloc((size_t)NB * ND * 4);
    float* mupre = (float*)alloc((size_t)NB * NT * 4);
    float* lvpre = (float*)alloc((size_t)NB * NT * 4);
    float* mu    = (float*)alloc((size_t)NB * NT * 4);
    float* lv    = (float*)alloc((size_t)NB * NT * 4);
    float* theta = (float*)alloc((size_t)NB * NT * 4);
    float* cmu   = (float*)alloc((size_t)NV * 4);
    float* crstd = (float*)alloc((size_t)NV * 4);
    float* rp    = (float*)alloc((size_t)NB * 4);
    float* kp    = (float*)alloc((size_t)NB * 4);

    const dim3 blk(256);

    // ---- bf16 conversions (sizes all multiples of 2048 elems) ----
    f32_to_bf16_vec<<<(NB * NV) / 2048, blk, 0, stream>>>(x, xb);          // 5000 blocks
    f32_to_bf16_vec<<<(NE * NV) / 2048, blk, 0, stream>>>(fc11_w, wb11);   // 10000 blocks
    f32_to_bf16_vec<<<(NE * NE) / 2048, blk, 0, stream>>>(fc12_w, w12b);   // 512 blocks

    // ---- fc11: e1 = softplus(x @ fc11_w^T + b), bf16 MFMA split-K ----
    gemm_mfma_splitk<<<dim3(NE / BN, NB / BM, 8), blk, 0, stream>>>(
        xb, wb11, part, NB, NE, NV, 8, NV / BK);           // 625 k-steps
    reduce_splitk<1, 1><<<(NB * NE + 255) / 256, blk, 0, stream>>>(
        part, fc11_b, e1b, NB * NE, NE, 8);

    // ---- fc12: h = softplus(e1 @ fc12_w^T + b), bf16 MFMA split-K ----
    gemm_mfma_splitk<<<dim3(NE / BN, NB / BM, 8), blk, 0, stream>>>(
        e1b, w12b, part, NB, NE, NE, 8, NE / BK);          // 32 k-steps
    reduce_splitk<0, 1><<<(NB * NE + 255) / 256, blk, 0, stream>>>(
        part, fc12_b, h, NB * NE, NE, 8);

    // ---- q projection (fp32) ----
    gemm_bt<0><<<dim3(6, 8), blk, 0, stream>>>(h, q_w, q_b, q, NB, ND, NE);
    // qk = q @ k_w
    gemm_nn<<<dim3(3, NB), dim3(128), 0, stream>>>(q, k_w, qk, NB, ND, ND);
    // fused attention -> c = sum_m alpha*emb
    attn_kernel<<<NB, 256, 0, stream>>>(qk, emb, lengths, c);
    // d_i = c @ v_w^T + v_b
    gemm_bt<0><<<dim3(6, 8), blk, 0, stream>>>(c, v_w, v_b, di, NB, ND, ND);
    // mean / logvar heads
    gemm_bt<0><<<dim3(2, 8), blk, 0, stream>>>(di, mean_w, mean_b, mupre, NB, NT, ND);
    gemm_bt<0><<<dim3(2, 8), blk, 0, stream>>>(di, lvw, lvb, lvpre, NB, NT, ND);
    // batchnorm both heads
    bn_batch<<<dim3(NT, 2), 256, 0, stream>>>(mupre, lvpre, mbnb, lbnb, mu, lv);
    // theta softmax + KL partials
    theta_kl<<<NB, 128, 0, stream>>>(mu, lv, theta, kp);
    // decoder logits
    gemm_bt<0><<<dim3(313, 8), blk, 0, stream>>>(theta, dec_w, dec_b, logit, NB, NV, NT);
    // column BN stats
    col_stats<<<(NV + 255) / 256, 256, 0, stream>>>(logit, cmu, crstd);
    // per-row log-softmax dot x
    row_recon<<<NB, 256, 0, stream>>>(logit, cmu, crstd, dbnb, x, rp);
    // final scalar
    finalize<<<1, 512, 0, stream>>>(rp, kp, out);
}

// Round 3
// 351.086 us; speedup vs baseline: 6.4901x; 1.8018x over previous
//
#include <hip/hip_runtime.h>
#include <cstddef>

// Shapes (fixed)
#define NB 512     // batch B
#define NM 64      // M sentences
#define NV 20000   // vocab V
#define NE 1024    // E
#define ND 384     // D
#define NT 100     // T topics
#define EPS 1e-5f

#define NVP 20096  // NV padded to 157*128
#define NKP 128    // decoder K padded (100 -> 128)
#define NHS 256    // stacked heads rows (100 mean | pad | 100 logvar | pad)

typedef __bf16 bf16x8 __attribute__((ext_vector_type(8)));
typedef float f32x4 __attribute__((ext_vector_type(4)));

__device__ __forceinline__ float softplus_f(float x) {
    return fmaxf(x, 0.f) + log1pf(expf(-fabsf(x)));
}

__device__ __forceinline__ unsigned short f2bf(float f) {
    unsigned u = __builtin_bit_cast(unsigned, f);
    unsigned r = u + 0x7FFFu + ((u >> 16) & 1u);   // RNE
    return (unsigned short)(r >> 16);
}

// ---------------------------------------------------------------------------
// f32 -> bf16 bulk convert; 8 elems/thread. n must be multiple of 2048.
// ---------------------------------------------------------------------------
__global__ __launch_bounds__(256) void f32_to_bf16_vec(const float* __restrict__ in,
                                                       unsigned short* __restrict__ out) {
    const size_t i = ((size_t)blockIdx.x * 256 + threadIdx.x) * 8;
    const float4 a = *reinterpret_cast<const float4*>(in + i);
    const float4 b = *reinterpret_cast<const float4*>(in + i + 4);
    union { unsigned short u[8]; uint4 v; } r;
    r.u[0] = f2bf(a.x); r.u[1] = f2bf(a.y); r.u[2] = f2bf(a.z); r.u[3] = f2bf(a.w);
    r.u[4] = f2bf(b.x); r.u[5] = f2bf(b.y); r.u[6] = f2bf(b.z); r.u[7] = f2bf(b.w);
    *reinterpret_cast<uint4*>(out + i) = r.v;
}

// ---------------------------------------------------------------------------
// k_w [E,D]=[384,384] f32 -> out [D,E] bf16 (transpose-convert).
// block (32,8), grid (12,12). tile[33] pad kills bank conflicts.
// ---------------------------------------------------------------------------
__global__ __launch_bounds__(256) void transpose_convert_384(const float* __restrict__ in,
                                                             unsigned short* __restrict__ out) {
    __shared__ float tile[32][33];
    const int bx = blockIdx.x * 32;  // d block
    const int by = blockIdx.y * 32;  // e block
    const int tx = threadIdx.x, ty = threadIdx.y;
    #pragma unroll
    for (int i = 0; i < 4; ++i)
        tile[ty + 8 * i][tx] = in[(by + ty + 8 * i) * ND + bx + tx];  // [e_loc][d_loc]
    __syncthreads();
    #pragma unroll
    for (int i = 0; i < 4; ++i)
        out[(size_t)(bx + ty + 8 * i) * ND + by + tx] = f2bf(tile[tx][ty + 8 * i]);
}

// ---------------------------------------------------------------------------
// Stack mean_w/logvar_w into [256,384] bf16 (rows 0-99, 128-227; rest 0).
// grid = 256 (row per block), 256 threads.
// ---------------------------------------------------------------------------
__global__ __launch_bounds__(256) void stack_heads_w(const float* __restrict__ mw,
                                                     const float* __restrict__ lw,
                                                     unsigned short* __restrict__ out) {
    const int r = blockIdx.x;
    const float* src = (r < NT) ? (mw + (size_t)r * ND)
                     : (r >= 128 && r < 128 + NT) ? (lw + (size_t)(r - 128) * ND) : nullptr;
    for (int c = threadIdx.x; c < ND; c += 256)
        out[(size_t)r * ND + c] = src ? f2bf(src[c]) : (unsigned short)0;
}

__global__ __launch_bounds__(256) void stack_heads_b(const float* __restrict__ mb,
                                                     const float* __restrict__ lb,
                                                     float* __restrict__ out) {
    const int r = threadIdx.x;
    out[r] = (r < NT) ? mb[r] : (r >= 128 && r < 128 + NT) ? lb[r - 128] : 0.f;
}

// ---------------------------------------------------------------------------
// dec_w [NV,NT] f32 -> [NVP,NKP] bf16 zero-padded. grid NVP blocks x 128 thr.
// ---------------------------------------------------------------------------
__global__ __launch_bounds__(128) void pad_decw(const float* __restrict__ in,
                                                unsigned short* __restrict__ out) {
    const int n = blockIdx.x, k = threadIdx.x;
    out[(size_t)n * NKP + k] = (n < NV && k < NT) ? f2bf(in[(size_t)n * NT + k]) : (unsigned short)0;
}

// theta [B,NT] f32 -> [B,NKP] bf16 zero-padded. grid NB x 128.
__global__ __launch_bounds__(128) void pad_theta(const float* __restrict__ in,
                                                 unsigned short* __restrict__ out) {
    const int b = blockIdx.x, k = threadIdx.x;
    out[(size_t)b * NKP + k] = (k < NT) ? f2bf(in[(size_t)b * NT + k]) : (unsigned short)0;
}

// ---------------------------------------------------------------------------
// MFMA GEMM core: 128x128 tile, BK=32, 4 waves (2x2), 16x16x32 bf16 frags.
// ---------------------------------------------------------------------------
#define BM 128
#define BN 128
#define BK 32

// Split-K partials: partial[s][m][n] = sum_{k in chunk s} A[m,k]*Bw[n,k]
__global__ __launch_bounds__(256) void gemm_mfma_splitk(
        const unsigned short* __restrict__ A,
        const unsigned short* __restrict__ Bw,
        float* __restrict__ partial,
        int M, int N, int K, int S, int steps_total) {
    __shared__ __align__(16) unsigned short Asl[BM * BK];
    __shared__ __align__(16) unsigned short Bsl[BN * BK];
    const int tid = threadIdx.x;
    const int bn = blockIdx.x, bm = blockIdx.y, s = blockIdx.z;
    const int row0 = bm * BM, col0 = bn * BN;
    const int k_begin = (int)(((long)s * steps_total) / S) * BK;
    const int k_end   = (int)(((long)(s + 1) * steps_total) / S) * BK;

    const int srow = tid >> 2;
    const int scol = (tid & 3) * 8;
    const int wave = tid >> 6, lane = tid & 63;
    const int wm = wave >> 1, wn = wave & 1;
    const int lrow = lane & 15, lkb = lane >> 4;

    f32x4 acc[4][4] = {};
    const unsigned short* Ab = A + (size_t)row0 * K;
    const unsigned short* Bb = Bw + (size_t)col0 * K;

    for (int k0 = k_begin; k0 < k_end; k0 += BK) {
        #pragma unroll
        for (int i = 0; i < 2; ++i) {
            const int r = i * 64 + srow;
            __builtin_amdgcn_global_load_lds(
                (const __attribute__((address_space(1))) void*)(Ab + (size_t)r * K + k0 + scol),
                (__attribute__((address_space(3))) void*)(&Asl[(i * 256 + tid) * 8]),
                16, 0, 0);
            __builtin_amdgcn_global_load_lds(
                (const __attribute__((address_space(1))) void*)(Bb + (size_t)r * K + k0 + scol),
                (__attribute__((address_space(3))) void*)(&Bsl[(i * 256 + tid) * 8]),
                16, 0, 0);
        }
        __syncthreads();
        bf16x8 af[4], bfr[4];
        #pragma unroll
        for (int i = 0; i < 4; ++i) {
            af[i]  = *reinterpret_cast<const bf16x8*>(&Asl[(wm * 64 + i * 16 + lrow) * BK + lkb * 8]);
            bfr[i] = *reinterpret_cast<const bf16x8*>(&Bsl[(wn * 64 + i * 16 + lrow) * BK + lkb * 8]);
        }
        #pragma unroll
        for (int i = 0; i < 4; ++i)
            #pragma unroll
            for (int j = 0; j < 4; ++j)
                acc[i][j] = __builtin_amdgcn_mfma_f32_16x16x32_bf16(af[i], bfr[j], acc[i][j], 0, 0, 0);
        __syncthreads();
    }

    float* P = partial + (size_t)s * M * N;
    #pragma unroll
    for (int i = 0; i < 4; ++i) {
        const int rbase = row0 + wm * 64 + i * 16 + lkb * 4;
        #pragma unroll
        for (int j = 0; j < 4; ++j) {
            const int col = col0 + wn * 64 + j * 16 + lrow;
            #pragma unroll
            for (int r = 0; r < 4; ++r)
                P[(size_t)(rbase + r) * N + col] = acc[i][j][r];
        }
    }
}

// Single-pass MFMA GEMM with fused epilogue: C = act(A@Bw^T + bias).
// Bw has gridDim.x*BN rows (possibly padded); writes masked to col < Nout.
template<int OUT_BF16, int ACT, int HASBIAS>
__global__ __launch_bounds__(256) void gemm_mfma(
        const unsigned short* __restrict__ A,
        const unsigned short* __restrict__ Bw,
        const float* __restrict__ bias,
        void* __restrict__ Cout,
        int M, int Nout, int K) {
    __shared__ __align__(16) unsigned short Asl[BM * BK];
    __shared__ __align__(16) unsigned short Bsl[BN * BK];
    const int tid = threadIdx.x;
    const int row0 = blockIdx.y * BM, col0 = blockIdx.x * BN;
    const int srow = tid >> 2;
    const int scol = (tid & 3) * 8;
    const int wave = tid >> 6, lane = tid & 63;
    const int wm = wave >> 1, wn = wave & 1;
    const int lrow = lane & 15, lkb = lane >> 4;

    f32x4 acc[4][4] = {};
    const unsigned short* Ab = A + (size_t)row0 * K;
    const unsigned short* Bb = Bw + (size_t)col0 * K;

    for (int k0 = 0; k0 < K; k0 += BK) {
        #pragma unroll
        for (int i = 0; i < 2; ++i) {
            const int r = i * 64 + srow;
            __builtin_amdgcn_global_load_lds(
                (const __attribute__((address_space(1))) void*)(Ab + (size_t)r * K + k0 + scol),
                (__attribute__((address_space(3))) void*)(&Asl[(i * 256 + tid) * 8]),
                16, 0, 0);
            __builtin_amdgcn_global_load_lds(
                (const __attribute__((address_space(1))) void*)(Bb + (size_t)r * K + k0 + scol),
                (__attribute__((address_space(3))) void*)(&Bsl[(i * 256 + tid) * 8]),
                16, 0, 0);
        }
        __syncthreads();
        bf16x8 af[4], bfr[4];
        #pragma unroll
        for (int i = 0; i < 4; ++i) {
            af[i]  = *reinterpret_cast<const bf16x8*>(&Asl[(wm * 64 + i * 16 + lrow) * BK + lkb * 8]);
            bfr[i] = *reinterpret_cast<const bf16x8*>(&Bsl[(wn * 64 + i * 16 + lrow) * BK + lkb * 8]);
        }
        #pragma unroll
        for (int i = 0; i < 4; ++i)
            #pragma unroll
            for (int j = 0; j < 4; ++j)
                acc[i][j] = __builtin_amdgcn_mfma_f32_16x16x32_bf16(af[i], bfr[j], acc[i][j], 0, 0, 0);
        __syncthreads();
    }

    #pragma unroll
    for (int j = 0; j < 4; ++j) {
        const int col = col0 + wn * 64 + j * 16 + lrow;
        if (col >= Nout) continue;
        const float bv = HASBIAS ? bias[col] : 0.f;
        #pragma unroll
        for (int i = 0; i < 4; ++i) {
            const int rbase = row0 + wm * 64 + i * 16 + lkb * 4;
            #pragma unroll
            for (int r = 0; r < 4; ++r) {
                float v = acc[i][j][r] + bv;
                if (ACT == 1) v = softplus_f(v);
                if (OUT_BF16)
                    ((unsigned short*)Cout)[(size_t)(rbase + r) * Nout + col] = f2bf(v);
                else
                    ((float*)Cout)[(size_t)(rbase + r) * Nout + col] = v;
            }
        }
    }
}

// ---------------------------------------------------------------------------
// Split-K reduce + bias + optional softplus; output f32 or bf16.
// ---------------------------------------------------------------------------
template<int OUT_BF16, int ACT>
__global__ __launch_bounds__(256) void reduce_splitk(const float* __restrict__ partial,
                                                     const float* __restrict__ bias,
                                                     void* __restrict__ out,
                                                     int MN, int N, int S) {
    const int i = blockIdx.x * 256 + threadIdx.x;
    if (i >= MN) return;
    float sum = 0.f;
    for (int s = 0; s < S; ++s) sum += partial[(size_t)s * MN + i];
    sum += bias[i % N];
    if (ACT) sum = softplus_f(sum);
    if (OUT_BF16) ((unsigned short*)out)[i] = f2bf(sum);
    else          ((float*)out)[i] = sum;
}

// ---------------------------------------------------------------------------
// Fused ragged attention: scores -> masked softmax -> c[b,d] = sum_m alpha*emb
// (k_b cancels in softmax; alpha sums to 1 so v-bias applied post-GEMM.)
// ---------------------------------------------------------------------------
__global__ __launch_bounds__(256) void attn_kernel(const float* __restrict__ qk,
                                                   const float* __restrict__ emb,
                                                   const int* __restrict__ lengths,
                                                   float* __restrict__ c) {
    const int b = blockIdx.x;
    const int tid = threadIdx.x;
    __shared__ float qs[ND];
    __shared__ float sc[NM];

    for (int d = tid; d < ND; d += 256) qs[d] = qk[(size_t)b * ND + d];
    __syncthreads();

    const int wave = tid >> 6, lane = tid & 63;
    const float scale = 0.05103103630798288f;  // 1/sqrt(384)
    const float* eb = emb + (size_t)b * NM * ND;

    for (int m = wave; m < NM; m += 4) {
        float s = 0.f;
        for (int d = lane; d < ND; d += 64) s = fmaf(eb[m * ND + d], qs[d], s);
        #pragma unroll
        for (int off = 32; off; off >>= 1) s += __shfl_xor(s, off);
        if (lane == 0) sc[m] = s * scale;
    }
    __syncthreads();

    const int len = lengths[b];
    if (tid < 64) {
        float s = (tid < len) ? sc[tid] : -INFINITY;
        float mx = s;
        #pragma unroll
        for (int off = 32; off; off >>= 1) mx = fmaxf(mx, __shfl_xor(mx, off));
        float e = (tid < len) ? expf(s - mx) : 0.f;
        float sum = e;
        #pragma unroll
        for (int off = 32; off; off >>= 1) sum += __shfl_xor(sum, off);
        sc[tid] = e / sum;
    }
    __syncthreads();

    for (int d = tid; d < ND; d += 256) {
        float acc = 0.f;
        for (int m = 0; m < len; ++m) acc = fmaf(sc[m], eb[m * ND + d], acc);
        c[(size_t)b * ND + d] = acc;
    }
}

// ---------------------------------------------------------------------------
// BatchNorm over batch axis reading stacked heads hl [B,256]:
// mu from col t, lv from col 128+t. grid (NT, 2).
// ---------------------------------------------------------------------------
__global__ __launch_bounds__(256) void bn_batch(const float* __restrict__ hl,
                                                const float* __restrict__ mbnb,
                                                const float* __restrict__ lbnb,
                                                float* __restrict__ mu,
                                                float* __restrict__ lv) {
    const int t = blockIdx.x;
    const int sel = blockIdx.y;
    const int col = sel ? 128 + t : t;
    const float* bnb = sel ? lbnb : mbnb;
    float* dst = sel ? lv : mu;
    const int tid = threadIdx.x;

    float s = 0.f, ss = 0.f;
    for (int b = tid; b < NB; b += 256) {
        const float v = hl[(size_t)b * NHS + col];
        s += v; ss += v * v;
    }
    __shared__ float rs[256], rss[256];
    rs[tid] = s; rss[tid] = ss;
    __syncthreads();
    for (int off = 128; off; off >>= 1) {
        if (tid < off) { rs[tid] += rs[tid + off]; rss[tid] += rss[tid + off]; }
        __syncthreads();
    }
    const float mean = rs[0] / (float)NB;
    const float var = rss[0] / (float)NB - mean * mean;
    const float rstd = rsqrtf(var + EPS);
    const float bb = bnb[t];
    for (int b = tid; b < NB; b += 256) {
        dst[(size_t)b * NT + t] = (hl[(size_t)b * NHS + col] - mean) * rstd + bb;
    }
}

// ---------------------------------------------------------------------------
// Per-row softmax over T (theta) + KL partial per row.
// ---------------------------------------------------------------------------
__global__ __launch_bounds__(128) void theta_kl(const float* __restrict__ mu,
                                                const float* __restrict__ lv,
                                                float* __restrict__ theta,
                                                float* __restrict__ kld_p) {
    const int b = blockIdx.x, tid = threadIdx.x;
    const float var2 = 1.0f - 1.0f / (float)NT;
    const float inv_var2 = 1.0f / var2;
    __shared__ float red[128];

    const float m = (tid < NT) ? mu[(size_t)b * NT + tid] : -INFINITY;
    red[tid] = m;
    __syncthreads();
    for (int off = 64; off; off >>= 1) {
        if (tid < off) red[tid] = fmaxf(red[tid], red[tid + off]);
        __syncthreads();
    }
    const float mx = red[0];
    __syncthreads();

    const float e = (tid < NT) ? expf(m - mx) : 0.f;
    red[tid] = e;
    __syncthreads();
    for (int off = 64; off; off >>= 1) {
        if (tid < off) red[tid] += red[tid + off];
        __syncthreads();
    }
    const float sum = red[0];
    __syncthreads();
    if (tid < NT) theta[(size_t)b * NT + tid] = e / sum;

    float term = 0.f;
    if (tid < NT) {
        const float l = lv[(size_t)b * NT + tid];
        term = expf(l) * inv_var2 + m * m * inv_var2 - l;
    }
    red[tid] = term;
    __syncthreads();
    for (int off = 64; off; off >>= 1) {
        if (tid < off) red[tid] += red[tid + off];
        __syncthreads();
    }
    if (tid == 0)
        kld_p[b] = 0.5f * (red[0] + (float)NT * logf(var2) - (float)NT);
}

// ---------------------------------------------------------------------------
// Per-column BN stats over batch for logit [B,V].
// ---------------------------------------------------------------------------
__global__ __launch_bounds__(256) void col_stats(const float* __restrict__ logit,
                                                 float* __restrict__ cmu,
                                                 float* __restrict__ crstd) {
    const int v = blockIdx.x * 256 + threadIdx.x;
    if (v >= NV) return;
    float s = 0.f, ss = 0.f;
    for (int b = 0; b < NB; ++b) {
        const float x = logit[(size_t)b * NV + v];
        s += x; ss += x * x;
    }
    const float mean = s / (float)NB;
    cmu[v] = mean;
    crstd[v] = rsqrtf(ss / (float)NB - mean * mean + EPS);
}

// ---------------------------------------------------------------------------
// Per-row: z = (logit-cmu)*crstd + dbnb; online LSE; recon_p[b] = sum x*(z-lse)
// ---------------------------------------------------------------------------
__global__ __launch_bounds__(256) void row_recon(const float* __restrict__ logit,
                                                 const float* __restrict__ cmu,
                                                 const float* __restrict__ crstd,
                                                 const float* __restrict__ dbnb,
                                                 const float* __restrict__ x,
                                                 float* __restrict__ recon_p) {
    const int b = blockIdx.x, tid = threadIdx.x;
    const float* lr = logit + (size_t)b * NV;
    const float* xr = x + (size_t)b * NV;

    float m_i = -INFINITY, s_i = 0.f;
    for (int v = tid; v < NV; v += 256) {
        const float z = (lr[v] - cmu[v]) * crstd[v] + dbnb[v];
        if (z > m_i) { s_i = s_i * expf(m_i - z) + 1.f; m_i = z; }
        else s_i += expf(z - m_i);
    }
    __shared__ float rm[256], rsum[256];
    rm[tid] = m_i; rsum[tid] = s_i;
    __syncthreads();
    for (int off = 128; off; off >>= 1) {
        if (tid < off) {
            const float m1 = rm[tid], m2 = rm[tid + off];
            const float s1 = rsum[tid], s2 = rsum[tid + off];
            const float mm = fmaxf(m1, m2);
            rm[tid] = mm;
            rsum[tid] = s1 * expf(m1 - mm) + s2 * expf(m2 - mm);
        }
        __syncthreads();
    }
    const float lse = rm[0] + logf(rsum[0]);
    __syncthreads();

    float acc = 0.f;
    for (int v = tid; v < NV; v += 256) {
        const float z = (lr[v] - cmu[v]) * crstd[v] + dbnb[v];
        acc = fmaf(xr[v], z - lse, acc);
    }
    rsum[tid] = acc;
    __syncthreads();
    for (int off = 128; off; off >>= 1) {
        if (tid < off) rsum[tid] += rsum[tid + off];
        __syncthreads();
    }
    if (tid == 0) recon_p[b] = rsum[0];
}

// ---------------------------------------------------------------------------
// Final: out = -mean(recon_p) + mean(kld_p)
// ---------------------------------------------------------------------------
__global__ __launch_bounds__(512) void finalize(const float* __restrict__ recon_p,
                                                const float* __restrict__ kld_p,
                                                float* __restrict__ out) {
    const int tid = threadIdx.x;
    __shared__ float r1[512], r2[512];
    r1[tid] = recon_p[tid];
    r2[tid] = kld_p[tid];
    __syncthreads();
    for (int off = 256; off; off >>= 1) {
        if (tid < off) { r1[tid] += r1[tid + off]; r2[tid] += r2[tid + off]; }
        __syncthreads();
    }
    if (tid == 0) out[0] = (-r1[0] + r2[0]) / (float)NB;
}

extern "C" void kernel_launch(void* const* d_in, const int* in_sizes, int n_in,
                              void* d_out, int out_size, void* d_ws, size_t ws_size,
                              hipStream_t stream) {
    const float* x       = (const float*)d_in[0];
    const float* emb     = (const float*)d_in[1];
    const int*   lengths = (const int*)d_in[2];
    const float* fc11_w  = (const float*)d_in[3];
    const float* fc11_b  = (const float*)d_in[4];
    const float* fc12_w  = (const float*)d_in[5];
    const float* fc12_b  = (const float*)d_in[6];
    const float* q_w     = (const float*)d_in[7];
    const float* q_b     = (const float*)d_in[8];
    const float* k_w     = (const float*)d_in[9];
    // d_in[10] = k_b: cancels in softmax -> unused
    const float* v_w     = (const float*)d_in[11];
    const float* v_b     = (const float*)d_in[12];
    const float* mean_w  = (const float*)d_in[13];
    const float* mean_b  = (const float*)d_in[14];
    const float* lvw     = (const float*)d_in[15];
    const float* lvb     = (const float*)d_in[16];
    const float* mbnb    = (const float*)d_in[17];
    const float* lbnb    = (const float*)d_in[18];
    const float* dec_w   = (const float*)d_in[19];
    const float* dec_b   = (const float*)d_in[20];
    const float* dbnb    = (const float*)d_in[21];
    float* out = (float*)d_out;

    char* base = (char*)d_ws;
    size_t off = 0;
    auto alloc = [&](size_t bytes) -> void* {
        void* p = base + off;
        off += (bytes + 255) & ~(size_t)255;
        return p;
    };

    // logit (f32, 40.96MB) aliases bf16 fc11_w (wb11 dead before decoder GEMM).
    float*          logit  = (float*)alloc((size_t)NB * NV * 4);
    unsigned short* wb11   = (unsigned short*)logit;
    unsigned short* xb     = (unsigned short*)alloc((size_t)NB * NV * 2);
    unsigned short* w12b   = (unsigned short*)alloc((size_t)NE * NE * 2);
    unsigned short* e1b    = (unsigned short*)alloc((size_t)NB * NE * 2);
    unsigned short* hb     = (unsigned short*)alloc((size_t)NB * NE * 2);
    unsigned short* qwb    = (unsigned short*)alloc((size_t)ND * NE * 2);
    unsigned short* kTb    = (unsigned short*)alloc((size_t)ND * ND * 2);
    unsigned short* vwb    = (unsigned short*)alloc((size_t)ND * ND * 2);
    unsigned short* qb     = (unsigned short*)alloc((size_t)NB * ND * 2);
    float*          qk     = (float*)alloc((size_t)NB * ND * 4);
    float*          c      = (float*)alloc((size_t)NB * ND * 4);
    unsigned short* cb     = (unsigned short*)alloc((size_t)NB * ND * 2);
    unsigned short* dib    = (unsigned short*)alloc((size_t)NB * ND * 2);
    unsigned short* headwb = (unsigned short*)alloc((size_t)NHS * ND * 2);
    float*          headbb = (float*)alloc((size_t)NHS * 4);
    float*          hl     = (float*)alloc((size_t)NB * NHS * 4);
    float*          mu     = (float*)alloc((size_t)NB * NT * 4);
    float*          lv     = (float*)alloc((size_t)NB * NT * 4);
    float*          theta  = (float*)alloc((size_t)NB * NT * 4);
    float*          cmu    = (float*)alloc((size_t)NV * 4);
    float*          crstd  = (float*)alloc((size_t)NV * 4);
    float*          rp     = (float*)alloc((size_t)NB * 4);
    float*          kp     = (float*)alloc((size_t)NB * 4);
    // part allocated LAST so split-count can adapt to remaining workspace
    const size_t part_bytes_per_s = ((size_t)NB * NE * 4 + 255) & ~(size_t)255;
    const size_t remain = (ws_size > off) ? (ws_size - off) : 0;
    const int S11 = (remain >= 16 * part_bytes_per_s) ? 16 : 8;  // fc11 split
    float* part = (float*)alloc((size_t)S11 * NB * NE * 4);
    // decwb/thetab alias part (part dead after fc12 reduce, before decoder)
    unsigned short* decwb  = (unsigned short*)part;                       // 5.15 MB
    unsigned short* thetab = (unsigned short*)((char*)part + (((size_t)NVP * NKP * 2 + 255) & ~(size_t)255));

    const dim3 blk(256);

    // ---- bf16 conversions ----
    f32_to_bf16_vec<<<(NB * NV) / 2048, blk, 0, stream>>>(x, xb);
    f32_to_bf16_vec<<<(NE * NV) / 2048, blk, 0, stream>>>(fc11_w, wb11);
    f32_to_bf16_vec<<<(NE * NE) / 2048, blk, 0, stream>>>(fc12_w, w12b);
    f32_to_bf16_vec<<<(ND * NE) / 2048, blk, 0, stream>>>(q_w, qwb);
    f32_to_bf16_vec<<<(ND * ND) / 2048, blk, 0, stream>>>(v_w, vwb);
    transpose_convert_384<<<dim3(12, 12), dim3(32, 8), 0, stream>>>(k_w, kTb);
    stack_heads_w<<<NHS, blk, 0, stream>>>(mean_w, lvw, headwb);
    stack_heads_b<<<1, NHS, 0, stream>>>(mean_b, lvb, headbb);

    // ---- fc11: e1 = softplus(x @ fc11_w^T + b) ----
    gemm_mfma_splitk<<<dim3(NE / BN, NB / BM, S11), blk, 0, stream>>>(
        xb, wb11, part, NB, NE, NV, S11, NV / BK);
    reduce_splitk<1, 1><<<(NB * NE) / 256, blk, 0, stream>>>(
        part, fc11_b, e1b, NB * NE, NE, S11);

    // ---- fc12: h = softplus(e1 @ fc12_w^T + b) ----
    gemm_mfma_splitk<<<dim3(NE / BN, NB / BM, 8), blk, 0, stream>>>(
        e1b, w12b, part, NB, NE, NE, 8, NE / BK);
    reduce_splitk<1, 1><<<(NB * NE) / 256, blk, 0, stream>>>(
        part, fc12_b, hb, NB * NE, NE, 8);

    // part is now dead -> stage decoder pad buffers into it
    pad_decw<<<NVP, 128, 0, stream>>>(dec_w, decwb);

    // ---- q = h @ q_w^T + q_b (bf16 out) ----
    gemm_mfma<1, 0, 1><<<dim3(ND / BN, NB / BM), blk, 0, stream>>>(
        hb, qwb, q_b, qb, NB, ND, NE);
    // ---- qk = q @ k_w  (via kT, no bias) ----
    gemm_mfma<0, 0, 0><<<dim3(ND / BN, NB / BM), blk, 0, stream>>>(
        qb, kTb, nullptr, qk, NB, ND, ND);
    // ---- fused attention -> c = sum_m alpha*emb ----
    attn_kernel<<<NB, 256, 0, stream>>>(qk, emb, lengths, c);
    f32_to_bf16_vec<<<(NB * ND) / 2048, blk, 0, stream>>>(c, cb);
    // ---- d_i = c @ v_w^T + v_b (bf16 out) ----
    gemm_mfma<1, 0, 1><<<dim3(ND / BN, NB / BM), blk, 0, stream>>>(
        cb, vwb, v_b, dib, NB, ND, ND);
    // ---- stacked heads: hl = d_i @ headw^T + headb (f32 [B,256]) ----
    gemm_mfma<0, 0, 1><<<dim3(NHS / BN, NB / BM), blk, 0, stream>>>(
        dib, headwb, headbb, hl, NB, NHS, ND);
    // ---- batchnorm both heads ----
    bn_batch<<<dim3(NT, 2), blk, 0, stream>>>(hl, mbnb, lbnb, mu, lv);
    // ---- theta softmax + KL partials ----
    theta_kl<<<NB, 128, 0, stream>>>(mu, lv, theta, kp);
    pad_theta<<<NB, 128, 0, stream>>>(theta, thetab);
    // ---- decoder logits: [B,NV] = theta @ dec_w^T + dec_b ----
    gemm_mfma<0, 0, 1><<<dim3(NVP / BN, NB / BM), blk, 0, stream>>>(
        thetab, decwb, dec_b, logit, NB, NV, NKP);
    // ---- column BN stats ----
    col_stats<<<(NV + 255) / 256, blk, 0, stream>>>(logit, cmu, crstd);
    // ---- per-row log-softmax dot x ----
    row_recon<<<NB, 256, 0, stream>>>(logit, cmu, crstd, dbnb, x, rp);
    // ---- final scalar ----
    finalize<<<1, 512, 0, stream>>>(rp, kp, out);
}

// Round 4
// 245.692 us; speedup vs baseline: 9.2741x; 1.4290x over previous
//
#include <hip/hip_runtime.h>
#include <cstddef>

// Shapes (fixed)
#define NB 512     // batch B
#define NM 64      // M sentences
#define NV 20000   // vocab V
#define NE 1024    // E
#define ND 384     // D
#define NT 100     // T topics
#define EPS 1e-5f

#define NVP 20096  // NV padded to 157*128
#define NKP 128    // decoder K padded (100 -> 128)
#define NHS 256    // stacked heads rows (100 mean | pad | 100 logvar | pad)

typedef __bf16 bf16x8 __attribute__((ext_vector_type(8)));
typedef float f32x4 __attribute__((ext_vector_type(4)));

__device__ __forceinline__ float softplus_f(float x) {
    return fmaxf(x, 0.f) + log1pf(expf(-fabsf(x)));
}

__device__ __forceinline__ unsigned short f2bf(float f) {
    unsigned u = __builtin_bit_cast(unsigned, f);
    unsigned r = u + 0x7FFFu + ((u >> 16) & 1u);   // RNE
    return (unsigned short)(r >> 16);
}

__device__ __forceinline__ float bf2f(unsigned short u) {
    return __builtin_bit_cast(float, (unsigned)u << 16);
}

// ---------------------------------------------------------------------------
// f32 -> bf16 bulk convert; 8 elems/thread. n must be multiple of 2048.
// ---------------------------------------------------------------------------
__global__ __launch_bounds__(256) void f32_to_bf16_vec(const float* __restrict__ in,
                                                       unsigned short* __restrict__ out) {
    const size_t i = ((size_t)blockIdx.x * 256 + threadIdx.x) * 8;
    const float4 a = *reinterpret_cast<const float4*>(in + i);
    const float4 b = *reinterpret_cast<const float4*>(in + i + 4);
    union { unsigned short u[8]; uint4 v; } r;
    r.u[0] = f2bf(a.x); r.u[1] = f2bf(a.y); r.u[2] = f2bf(a.z); r.u[3] = f2bf(a.w);
    r.u[4] = f2bf(b.x); r.u[5] = f2bf(b.y); r.u[6] = f2bf(b.z); r.u[7] = f2bf(b.w);
    *reinterpret_cast<uint4*>(out + i) = r.v;
}

// ---------------------------------------------------------------------------
// k_w [E,D]=[384,384] f32 -> out [D,E] bf16 (transpose-convert).
// ---------------------------------------------------------------------------
__global__ __launch_bounds__(256) void transpose_convert_384(const float* __restrict__ in,
                                                             unsigned short* __restrict__ out) {
    __shared__ float tile[32][33];
    const int bx = blockIdx.x * 32;
    const int by = blockIdx.y * 32;
    const int tx = threadIdx.x, ty = threadIdx.y;
    #pragma unroll
    for (int i = 0; i < 4; ++i)
        tile[ty + 8 * i][tx] = in[(by + ty + 8 * i) * ND + bx + tx];
    __syncthreads();
    #pragma unroll
    for (int i = 0; i < 4; ++i)
        out[(size_t)(bx + ty + 8 * i) * ND + by + tx] = f2bf(tile[tx][ty + 8 * i]);
}

// ---------------------------------------------------------------------------
// Stack mean_w/logvar_w into [256,384] bf16 (rows 0-99, 128-227; rest 0).
// ---------------------------------------------------------------------------
__global__ __launch_bounds__(256) void stack_heads_w(const float* __restrict__ mw,
                                                     const float* __restrict__ lw,
                                                     unsigned short* __restrict__ out) {
    const int r = blockIdx.x;
    const float* src = (r < NT) ? (mw + (size_t)r * ND)
                     : (r >= 128 && r < 128 + NT) ? (lw + (size_t)(r - 128) * ND) : nullptr;
    for (int c = threadIdx.x; c < ND; c += 256)
        out[(size_t)r * ND + c] = src ? f2bf(src[c]) : (unsigned short)0;
}

__global__ __launch_bounds__(256) void stack_heads_b(const float* __restrict__ mb,
                                                     const float* __restrict__ lb,
                                                     float* __restrict__ out) {
    const int r = threadIdx.x;
    out[r] = (r < NT) ? mb[r] : (r >= 128 && r < 128 + NT) ? lb[r - 128] : 0.f;
}

// ---------------------------------------------------------------------------
// dec_w [NV,NT] f32 -> [NVP,NKP] bf16 zero-padded.
// ---------------------------------------------------------------------------
__global__ __launch_bounds__(128) void pad_decw(const float* __restrict__ in,
                                                unsigned short* __restrict__ out) {
    const int n = blockIdx.x, k = threadIdx.x;
    out[(size_t)n * NKP + k] = (n < NV && k < NT) ? f2bf(in[(size_t)n * NT + k]) : (unsigned short)0;
}

// ---------------------------------------------------------------------------
// MFMA GEMM core: 128x128 tile, BK=32, 4 waves (2x2), 16x16x32 bf16 frags.
// ---------------------------------------------------------------------------
#define BM 128
#define BN 128
#define BK 32

// Split-K partials: partial[s][m][n] = sum_{k in chunk s} A[m,k]*Bw[n,k]
__global__ __launch_bounds__(256) void gemm_mfma_splitk(
        const unsigned short* __restrict__ A,
        const unsigned short* __restrict__ Bw,
        float* __restrict__ partial,
        int M, int N, int K, int S, int steps_total) {
    __shared__ __align__(16) unsigned short Asl[BM * BK];
    __shared__ __align__(16) unsigned short Bsl[BN * BK];
    const int tid = threadIdx.x;
    const int bn = blockIdx.x, bm = blockIdx.y, s = blockIdx.z;
    const int row0 = bm * BM, col0 = bn * BN;
    const int k_begin = (int)(((long)s * steps_total) / S) * BK;
    const int k_end   = (int)(((long)(s + 1) * steps_total) / S) * BK;

    const int srow = tid >> 2;
    const int scol = (tid & 3) * 8;
    const int wave = tid >> 6, lane = tid & 63;
    const int wm = wave >> 1, wn = wave & 1;
    const int lrow = lane & 15, lkb = lane >> 4;

    f32x4 acc[4][4] = {};
    const unsigned short* Ab = A + (size_t)row0 * K;
    const unsigned short* Bb = Bw + (size_t)col0 * K;

    for (int k0 = k_begin; k0 < k_end; k0 += BK) {
        #pragma unroll
        for (int i = 0; i < 2; ++i) {
            const int r = i * 64 + srow;
            __builtin_amdgcn_global_load_lds(
                (const __attribute__((address_space(1))) void*)(Ab + (size_t)r * K + k0 + scol),
                (__attribute__((address_space(3))) void*)(&Asl[(i * 256 + tid) * 8]),
                16, 0, 0);
            __builtin_amdgcn_global_load_lds(
                (const __attribute__((address_space(1))) void*)(Bb + (size_t)r * K + k0 + scol),
                (__attribute__((address_space(3))) void*)(&Bsl[(i * 256 + tid) * 8]),
                16, 0, 0);
        }
        __syncthreads();
        bf16x8 af[4], bfr[4];
        #pragma unroll
        for (int i = 0; i < 4; ++i) {
            af[i]  = *reinterpret_cast<const bf16x8*>(&Asl[(wm * 64 + i * 16 + lrow) * BK + lkb * 8]);
            bfr[i] = *reinterpret_cast<const bf16x8*>(&Bsl[(wn * 64 + i * 16 + lrow) * BK + lkb * 8]);
        }
        #pragma unroll
        for (int i = 0; i < 4; ++i)
            #pragma unroll
            for (int j = 0; j < 4; ++j)
                acc[i][j] = __builtin_amdgcn_mfma_f32_16x16x32_bf16(af[i], bfr[j], acc[i][j], 0, 0, 0);
        __syncthreads();
    }

    float* P = partial + (size_t)s * M * N;
    #pragma unroll
    for (int i = 0; i < 4; ++i) {
        const int rbase = row0 + wm * 64 + i * 16 + lkb * 4;
        #pragma unroll
        for (int j = 0; j < 4; ++j) {
            const int col = col0 + wn * 64 + j * 16 + lrow;
            #pragma unroll
            for (int r = 0; r < 4; ++r)
                P[(size_t)(rbase + r) * N + col] = acc[i][j][r];
        }
    }
}

// Single-pass MFMA GEMM with fused epilogue: C = act(A@Bw^T + bias).
// COLSTATS: also emit per-(rowblock,wm-wave) column sum/sumsq partials to
// colp[{0,1}][8][NVP] (deterministic shfl reduction, no atomics).
template<int OUT_BF16, int ACT, int HASBIAS, int COLSTATS>
__global__ __launch_bounds__(256) void gemm_mfma(
        const unsigned short* __restrict__ A,
        const unsigned short* __restrict__ Bw,
        const float* __restrict__ bias,
        void* __restrict__ Cout,
        float* __restrict__ colp,
        int M, int Nout, int K) {
    __shared__ __align__(16) unsigned short Asl[BM * BK];
    __shared__ __align__(16) unsigned short Bsl[BN * BK];
    const int tid = threadIdx.x;
    const int row0 = blockIdx.y * BM, col0 = blockIdx.x * BN;
    const int srow = tid >> 2;
    const int scol = (tid & 3) * 8;
    const int wave = tid >> 6, lane = tid & 63;
    const int wm = wave >> 1, wn = wave & 1;
    const int lrow = lane & 15, lkb = lane >> 4;

    f32x4 acc[4][4] = {};
    const unsigned short* Ab = A + (size_t)row0 * K;
    const unsigned short* Bb = Bw + (size_t)col0 * K;

    for (int k0 = 0; k0 < K; k0 += BK) {
        #pragma unroll
        for (int i = 0; i < 2; ++i) {
            const int r = i * 64 + srow;
            __builtin_amdgcn_global_load_lds(
                (const __attribute__((address_space(1))) void*)(Ab + (size_t)r * K + k0 + scol),
                (__attribute__((address_space(3))) void*)(&Asl[(i * 256 + tid) * 8]),
                16, 0, 0);
            __builtin_amdgcn_global_load_lds(
                (const __attribute__((address_space(1))) void*)(Bb + (size_t)r * K + k0 + scol),
                (__attribute__((address_space(3))) void*)(&Bsl[(i * 256 + tid) * 8]),
                16, 0, 0);
        }
        __syncthreads();
        bf16x8 af[4], bfr[4];
        #pragma unroll
        for (int i = 0; i < 4; ++i) {
            af[i]  = *reinterpret_cast<const bf16x8*>(&Asl[(wm * 64 + i * 16 + lrow) * BK + lkb * 8]);
            bfr[i] = *reinterpret_cast<const bf16x8*>(&Bsl[(wn * 64 + i * 16 + lrow) * BK + lkb * 8]);
        }
        #pragma unroll
        for (int i = 0; i < 4; ++i)
            #pragma unroll
            for (int j = 0; j < 4; ++j)
                acc[i][j] = __builtin_amdgcn_mfma_f32_16x16x32_bf16(af[i], bfr[j], acc[i][j], 0, 0, 0);
        __syncthreads();
    }

    #pragma unroll
    for (int j = 0; j < 4; ++j) {
        const int col = col0 + wn * 64 + j * 16 + lrow;
        const bool cok = col < Nout;
        const float bv = HASBIAS ? (cok ? bias[col] : 0.f) : 0.f;
        float csum = 0.f, csq = 0.f;
        #pragma unroll
        for (int i = 0; i < 4; ++i) {
            const int rbase = row0 + wm * 64 + i * 16 + lkb * 4;
            #pragma unroll
            for (int r = 0; r < 4; ++r) {
                float v = acc[i][j][r] + bv;
                if (ACT == 1) v = softplus_f(v);
                if (COLSTATS) { csum += v; csq = fmaf(v, v, csq); }
                if (cok) {
                    if (OUT_BF16)
                        ((unsigned short*)Cout)[(size_t)(rbase + r) * Nout + col] = f2bf(v);
                    else
                        ((float*)Cout)[(size_t)(rbase + r) * Nout + col] = v;
                }
            }
        }
        if (COLSTATS) {
            csum += __shfl_xor(csum, 16); csum += __shfl_xor(csum, 32);
            csq  += __shfl_xor(csq, 16);  csq  += __shfl_xor(csq, 32);
            if (lkb == 0) {
                const int w8 = blockIdx.y * 2 + wm;   // 0..7
                colp[(size_t)w8 * NVP + col] = csum;
                colp[(size_t)(8 + w8) * NVP + col] = csq;
            }
        }
    }
}

// ---------------------------------------------------------------------------
// Split-K reduce + bias + optional softplus; output f32 or bf16.
// ---------------------------------------------------------------------------
template<int OUT_BF16, int ACT>
__global__ __launch_bounds__(256) void reduce_splitk(const float* __restrict__ partial,
                                                     const float* __restrict__ bias,
                                                     void* __restrict__ out,
                                                     int MN, int N, int S) {
    const int i = blockIdx.x * 256 + threadIdx.x;
    if (i >= MN) return;
    float sum = 0.f;
    for (int s = 0; s < S; ++s) sum += partial[(size_t)s * MN + i];
    sum += bias[i % N];
    if (ACT) sum = softplus_f(sum);
    if (OUT_BF16) ((unsigned short*)out)[i] = f2bf(sum);
    else          ((float*)out)[i] = sum;
}

// ---------------------------------------------------------------------------
// Fused ragged attention, emb tile staged in LDS as bf16 (read emb ONCE):
// scores -> masked softmax -> c[b,d] = sum_m alpha*emb -> bf16 out.
// ---------------------------------------------------------------------------
__global__ __launch_bounds__(256) void attn_kernel(const float* __restrict__ qk,
                                                   const float* __restrict__ emb,
                                                   const int* __restrict__ lengths,
                                                   unsigned short* __restrict__ cb) {
    const int b = blockIdx.x;
    const int tid = threadIdx.x;
    __shared__ unsigned short es[NM * ND];  // 48 KB
    __shared__ float qs[ND];
    __shared__ float sc[NM];

    const float* ebase = emb + (size_t)b * NM * ND;
    for (int i = tid; i < NM * ND / 4; i += 256) {
        const float4 v = *reinterpret_cast<const float4*>(ebase + (size_t)i * 4);
        ushort4 o;
        o.x = f2bf(v.x); o.y = f2bf(v.y); o.z = f2bf(v.z); o.w = f2bf(v.w);
        *reinterpret_cast<ushort4*>(&es[i * 4]) = o;
    }
    for (int d = tid; d < ND; d += 256) qs[d] = qk[(size_t)b * ND + d];
    __syncthreads();

    const int wave = tid >> 6, lane = tid & 63;
    const float scale = 0.05103103630798288f;  // 1/sqrt(384)

    for (int m = wave; m < NM; m += 4) {
        float s = 0.f;
        for (int d = lane; d < ND; d += 64) s = fmaf(bf2f(es[m * ND + d]), qs[d], s);
        #pragma unroll
        for (int off = 32; off; off >>= 1) s += __shfl_xor(s, off);
        if (lane == 0) sc[m] = s * scale;
    }
    __syncthreads();

    const int len = lengths[b];
    if (tid < 64) {
        float s = (tid < len) ? sc[tid] : -INFINITY;
        float mx = s;
        #pragma unroll
        for (int off = 32; off; off >>= 1) mx = fmaxf(mx, __shfl_xor(mx, off));
        float e = (tid < len) ? expf(s - mx) : 0.f;
        float sum = e;
        #pragma unroll
        for (int off = 32; off; off >>= 1) sum += __shfl_xor(sum, off);
        sc[tid] = e / sum;
    }
    __syncthreads();

    for (int d = tid; d < ND; d += 256) {
        float acc = 0.f;
        for (int m = 0; m < len; ++m) acc = fmaf(sc[m], bf2f(es[m * ND + d]), acc);
        cb[(size_t)b * ND + d] = f2bf(acc);
    }
}

// ---------------------------------------------------------------------------
// BatchNorm over batch axis reading stacked heads hl [B,256].
// ---------------------------------------------------------------------------
__global__ __launch_bounds__(256) void bn_batch(const float* __restrict__ hl,
                                                const float* __restrict__ mbnb,
                                                const float* __restrict__ lbnb,
                                                float* __restrict__ mu,
                                                float* __restrict__ lv) {
    const int t = blockIdx.x;
    const int sel = blockIdx.y;
    const int col = sel ? 128 + t : t;
    const float* bnb = sel ? lbnb : mbnb;
    float* dst = sel ? lv : mu;
    const int tid = threadIdx.x;

    float s = 0.f, ss = 0.f;
    for (int b = tid; b < NB; b += 256) {
        const float v = hl[(size_t)b * NHS + col];
        s += v; ss += v * v;
    }
    __shared__ float rs[256], rss[256];
    rs[tid] = s; rss[tid] = ss;
    __syncthreads();
    for (int off = 128; off; off >>= 1) {
        if (tid < off) { rs[tid] += rs[tid + off]; rss[tid] += rss[tid + off]; }
        __syncthreads();
    }
    const float mean = rs[0] / (float)NB;
    const float var = rss[0] / (float)NB - mean * mean;
    const float rstd = rsqrtf(var + EPS);
    const float bb = bnb[t];
    for (int b = tid; b < NB; b += 256) {
        dst[(size_t)b * NT + t] = (hl[(size_t)b * NHS + col] - mean) * rstd + bb;
    }
}

// ---------------------------------------------------------------------------
// Per-row softmax over T -> thetab (bf16, zero-padded to 128) + KL partial.
// ---------------------------------------------------------------------------
__global__ __launch_bounds__(128) void theta_kl(const float* __restrict__ mu,
                                                const float* __restrict__ lv,
                                                unsigned short* __restrict__ thetab,
                                                float* __restrict__ kld_p) {
    const int b = blockIdx.x, tid = threadIdx.x;
    const float var2 = 1.0f - 1.0f / (float)NT;
    const float inv_var2 = 1.0f / var2;
    __shared__ float red[128];

    const float m = (tid < NT) ? mu[(size_t)b * NT + tid] : -INFINITY;
    red[tid] = m;
    __syncthreads();
    for (int off = 64; off; off >>= 1) {
        if (tid < off) red[tid] = fmaxf(red[tid], red[tid + off]);
        __syncthreads();
    }
    const float mx = red[0];
    __syncthreads();

    const float e = (tid < NT) ? expf(m - mx) : 0.f;
    red[tid] = e;
    __syncthreads();
    for (int off = 64; off; off >>= 1) {
        if (tid < off) red[tid] += red[tid + off];
        __syncthreads();
    }
    const float sum = red[0];
    __syncthreads();
    thetab[(size_t)b * NKP + tid] = (tid < NT) ? f2bf(e / sum) : (unsigned short)0;

    float term = 0.f;
    if (tid < NT) {
        const float l = lv[(size_t)b * NT + tid];
        term = expf(l) * inv_var2 + m * m * inv_var2 - l;
    }
    red[tid] = term;
    __syncthreads();
    for (int off = 64; off; off >>= 1) {
        if (tid < off) red[tid] += red[tid + off];
        __syncthreads();
    }
    if (tid == 0)
        kld_p[b] = 0.5f * (red[0] + (float)NT * logf(var2) - (float)NT);
}

// ---------------------------------------------------------------------------
// Combine the 8 per-wave column partials -> cmu, crstd.
// ---------------------------------------------------------------------------
__global__ __launch_bounds__(256) void stats_final(const float* __restrict__ colp,
                                                   float* __restrict__ cmu,
                                                   float* __restrict__ crstd) {
    const int v = blockIdx.x * 256 + threadIdx.x;
    if (v >= NV) return;
    float s = 0.f, q = 0.f;
    #pragma unroll
    for (int w = 0; w < 8; ++w) {
        s += colp[(size_t)w * NVP + v];
        q += colp[(size_t)(8 + w) * NVP + v];
    }
    const float mean = s / (float)NB;
    cmu[v] = mean;
    crstd[v] = rsqrtf(q / (float)NB - mean * mean + EPS);
}

// ---------------------------------------------------------------------------
// SINGLE pass over bf16 logit + bf16 x:
// online LSE of z; xz = sum x*z; xs = sum x; recon_p = xz - lse*xs.
// ---------------------------------------------------------------------------
__global__ __launch_bounds__(256) void row_recon(const unsigned short* __restrict__ logitb,
                                                 const unsigned short* __restrict__ xb,
                                                 const float* __restrict__ cmu,
                                                 const float* __restrict__ crstd,
                                                 const float* __restrict__ dbnb,
                                                 float* __restrict__ recon_p) {
    const int b = blockIdx.x, tid = threadIdx.x;
    const unsigned short* lr = logitb + (size_t)b * NV;
    const unsigned short* xr = xb + (size_t)b * NV;

    float m_i = -INFINITY, s_i = 0.f, xz = 0.f, xs = 0.f;
    for (int v = tid * 8; v < NV; v += 2048) {
        union { uint4 v4; unsigned short u[8]; } lw, xw;
        lw.v4 = *reinterpret_cast<const uint4*>(lr + v);
        xw.v4 = *reinterpret_cast<const uint4*>(xr + v);
        const float4 c0 = *reinterpret_cast<const float4*>(cmu + v);
        const float4 c1 = *reinterpret_cast<const float4*>(cmu + v + 4);
        const float4 r0 = *reinterpret_cast<const float4*>(crstd + v);
        const float4 r1 = *reinterpret_cast<const float4*>(crstd + v + 4);
        const float4 d0 = *reinterpret_cast<const float4*>(dbnb + v);
        const float4 d1 = *reinterpret_cast<const float4*>(dbnb + v + 4);
        const float cm[8] = {c0.x,c0.y,c0.z,c0.w,c1.x,c1.y,c1.z,c1.w};
        const float cr[8] = {r0.x,r0.y,r0.z,r0.w,r1.x,r1.y,r1.z,r1.w};
        const float db[8] = {d0.x,d0.y,d0.z,d0.w,d1.x,d1.y,d1.z,d1.w};
        float z[8];
        #pragma unroll
        for (int j = 0; j < 8; ++j)
            z[j] = fmaf(bf2f(lw.u[j]) - cm[j], cr[j], db[j]);
        float mx = z[0];
        #pragma unroll
        for (int j = 1; j < 8; ++j) mx = fmaxf(mx, z[j]);
        const float mnew = fmaxf(m_i, mx);
        float e8 = 0.f;
        #pragma unroll
        for (int j = 0; j < 8; ++j) e8 += expf(z[j] - mnew);
        s_i = s_i * expf(m_i - mnew) + e8;
        m_i = mnew;
        #pragma unroll
        for (int j = 0; j < 8; ++j) {
            const float xv = bf2f(xw.u[j]);
            xz = fmaf(xv, z[j], xz);
            xs += xv;
        }
    }

    __shared__ float rm[256], rs[256], rxz[256], rxs[256];
    rm[tid] = m_i; rs[tid] = s_i; rxz[tid] = xz; rxs[tid] = xs;
    __syncthreads();
    for (int off = 128; off; off >>= 1) {
        if (tid < off) {
            const float m1 = rm[tid], m2 = rm[tid + off];
            const float s1 = rs[tid], s2 = rs[tid + off];
            const float mm = fmaxf(m1, m2);
            rm[tid] = mm;
            rs[tid] = s1 * expf(m1 - mm) + s2 * expf(m2 - mm);
            rxz[tid] += rxz[tid + off];
            rxs[tid] += rxs[tid + off];
        }
        __syncthreads();
    }
    if (tid == 0) {
        const float lse = rm[0] + logf(rs[0]);
        recon_p[b] = rxz[0] - lse * rxs[0];
    }
}

// ---------------------------------------------------------------------------
// Final: out = -mean(recon_p) + mean(kld_p)
// ---------------------------------------------------------------------------
__global__ __launch_bounds__(512) void finalize(const float* __restrict__ recon_p,
                                                const float* __restrict__ kld_p,
                                                float* __restrict__ out) {
    const int tid = threadIdx.x;
    __shared__ float r1[512], r2[512];
    r1[tid] = recon_p[tid];
    r2[tid] = kld_p[tid];
    __syncthreads();
    for (int off = 256; off; off >>= 1) {
        if (tid < off) { r1[tid] += r1[tid + off]; r2[tid] += r2[tid + off]; }
        __syncthreads();
    }
    if (tid == 0) out[0] = (-r1[0] + r2[0]) / (float)NB;
}

extern "C" void kernel_launch(void* const* d_in, const int* in_sizes, int n_in,
                              void* d_out, int out_size, void* d_ws, size_t ws_size,
                              hipStream_t stream) {
    const float* x       = (const float*)d_in[0];
    const float* emb     = (const float*)d_in[1];
    const int*   lengths = (const int*)d_in[2];
    const float* fc11_w  = (const float*)d_in[3];
    const float* fc11_b  = (const float*)d_in[4];
    const float* fc12_w  = (const float*)d_in[5];
    const float* fc12_b  = (const float*)d_in[6];
    const float* q_w     = (const float*)d_in[7];
    const float* q_b     = (const float*)d_in[8];
    const float* k_w     = (const float*)d_in[9];
    // d_in[10] = k_b: cancels in softmax -> unused
    const float* v_w     = (const float*)d_in[11];
    const float* v_b     = (const float*)d_in[12];
    const float* mean_w  = (const float*)d_in[13];
    const float* mean_b  = (const float*)d_in[14];
    const float* lvw     = (const float*)d_in[15];
    const float* lvb     = (const float*)d_in[16];
    const float* mbnb    = (const float*)d_in[17];
    const float* lbnb    = (const float*)d_in[18];
    const float* dec_w   = (const float*)d_in[19];
    const float* dec_b   = (const float*)d_in[20];
    const float* dbnb    = (const float*)d_in[21];
    float* out = (float*)d_out;

    char* base = (char*)d_ws;
    size_t off = 0;
    auto alloc = [&](size_t bytes) -> void* {
        void* p = base + off;
        off += (bytes + 255) & ~(size_t)255;
        return p;
    };

    // wb11 (41MB) dead after fc11 GEMM; logitb (20.5MB) written by the much
    // later decoder GEMM -> alias logitb into wb11's space.
    unsigned short* wb11   = (unsigned short*)alloc((size_t)NE * NV * 2);
    unsigned short* logitb = wb11;
    unsigned short* xb     = (unsigned short*)alloc((size_t)NB * NV * 2);
    unsigned short* w12b   = (unsigned short*)alloc((size_t)NE * NE * 2);
    unsigned short* e1b    = (unsigned short*)alloc((size_t)NB * NE * 2);
    unsigned short* hb     = (unsigned short*)alloc((size_t)NB * NE * 2);
    unsigned short* qwb    = (unsigned short*)alloc((size_t)ND * NE * 2);
    unsigned short* kTb    = (unsigned short*)alloc((size_t)ND * ND * 2);
    unsigned short* vwb    = (unsigned short*)alloc((size_t)ND * ND * 2);
    unsigned short* qb     = (unsigned short*)alloc((size_t)NB * ND * 2);
    float*          qk     = (float*)alloc((size_t)NB * ND * 4);
    unsigned short* cb     = (unsigned short*)alloc((size_t)NB * ND * 2);
    unsigned short* dib    = (unsigned short*)alloc((size_t)NB * ND * 2);
    unsigned short* headwb = (unsigned short*)alloc((size_t)NHS * ND * 2);
    float*          headbb = (float*)alloc((size_t)NHS * 4);
    float*          hl     = (float*)alloc((size_t)NB * NHS * 4);
    float*          mu     = (float*)alloc((size_t)NB * NT * 4);
    float*          lv     = (float*)alloc((size_t)NB * NT * 4);
    float*          colp   = (float*)alloc((size_t)16 * NVP * 4);
    float*          cmu    = (float*)alloc((size_t)NV * 4);
    float*          crstd  = (float*)alloc((size_t)NV * 4);
    float*          rp     = (float*)alloc((size_t)NB * 4);
    float*          kp     = (float*)alloc((size_t)NB * 4);
    // part allocated LAST so split-count can adapt to remaining workspace
    const size_t part_bytes_per_s = ((size_t)NB * NE * 4 + 255) & ~(size_t)255;
    const size_t remain = (ws_size > off) ? (ws_size - off) : 0;
    const int S11 = (remain >= 16 * part_bytes_per_s) ? 16 : 8;  // fc11 split
    float* part = (float*)alloc((size_t)S11 * NB * NE * 4);
    // decwb/thetab alias part (part dead after fc12 reduce)
    unsigned short* decwb  = (unsigned short*)part;
    unsigned short* thetab = (unsigned short*)((char*)part + (((size_t)NVP * NKP * 2 + 255) & ~(size_t)255));

    const dim3 blk(256);

    // ---- bf16 conversions ----
    f32_to_bf16_vec<<<(NB * NV) / 2048, blk, 0, stream>>>(x, xb);
    f32_to_bf16_vec<<<(NE * NV) / 2048, blk, 0, stream>>>(fc11_w, wb11);
    f32_to_bf16_vec<<<(NE * NE) / 2048, blk, 0, stream>>>(fc12_w, w12b);
    f32_to_bf16_vec<<<(ND * NE) / 2048, blk, 0, stream>>>(q_w, qwb);
    f32_to_bf16_vec<<<(ND * ND) / 2048, blk, 0, stream>>>(v_w, vwb);
    transpose_convert_384<<<dim3(12, 12), dim3(32, 8), 0, stream>>>(k_w, kTb);
    stack_heads_w<<<NHS, blk, 0, stream>>>(mean_w, lvw, headwb);
    stack_heads_b<<<1, NHS, 0, stream>>>(mean_b, lvb, headbb);

    // ---- fc11: e1 = softplus(x @ fc11_w^T + b) ----
    gemm_mfma_splitk<<<dim3(NE / BN, NB / BM, S11), blk, 0, stream>>>(
        xb, wb11, part, NB, NE, NV, S11, NV / BK);
    reduce_splitk<1, 1><<<(NB * NE) / 256, blk, 0, stream>>>(
        part, fc11_b, e1b, NB * NE, NE, S11);

    // ---- fc12: h = softplus(e1 @ fc12_w^T + b) ----
    gemm_mfma_splitk<<<dim3(NE / BN, NB / BM, 8), blk, 0, stream>>>(
        e1b, w12b, part, NB, NE, NE, 8, NE / BK);
    reduce_splitk<1, 1><<<(NB * NE) / 256, blk, 0, stream>>>(
        part, fc12_b, hb, NB * NE, NE, 8);

    // part now dead -> stage decoder pad buffer into it
    pad_decw<<<NVP, 128, 0, stream>>>(dec_w, decwb);

    // ---- q = h @ q_w^T + q_b (bf16 out) ----
    gemm_mfma<1, 0, 1, 0><<<dim3(ND / BN, NB / BM), blk, 0, stream>>>(
        hb, qwb, q_b, qb, nullptr, NB, ND, NE);
    // ---- qk = q @ k_w  (via kT, no bias, f32 out) ----
    gemm_mfma<0, 0, 0, 0><<<dim3(ND / BN, NB / BM), blk, 0, stream>>>(
        qb, kTb, nullptr, qk, nullptr, NB, ND, ND);
    // ---- fused attention -> cb = bf16(sum_m alpha*emb) ----
    attn_kernel<<<NB, 256, 0, stream>>>(qk, emb, lengths, cb);
    // ---- d_i = c @ v_w^T + v_b (bf16 out) ----
    gemm_mfma<1, 0, 1, 0><<<dim3(ND / BN, NB / BM), blk, 0, stream>>>(
        cb, vwb, v_b, dib, nullptr, NB, ND, ND);
    // ---- stacked heads: hl = d_i @ headw^T + headb (f32 [B,256]) ----
    gemm_mfma<0, 0, 1, 0><<<dim3(NHS / BN, NB / BM), blk, 0, stream>>>(
        dib, headwb, headbb, hl, nullptr, NB, NHS, ND);
    // ---- batchnorm both heads ----
    bn_batch<<<dim3(NT, 2), blk, 0, stream>>>(hl, mbnb, lbnb, mu, lv);
    // ---- theta softmax (bf16 padded out) + KL partials ----
    theta_kl<<<NB, 128, 0, stream>>>(mu, lv, thetab, kp);
    // ---- decoder logits (bf16) + fused column stats partials ----
    gemm_mfma<1, 0, 1, 1><<<dim3(NVP / BN, NB / BM), blk, 0, stream>>>(
        thetab, decwb, dec_b, logitb, colp, NB, NV, NKP);
    stats_final<<<(NV + 255) / 256, blk, 0, stream>>>(colp, cmu, crstd);
    // ---- single-pass log-softmax dot x ----
    row_recon<<<NB, 256, 0, stream>>>(logitb, xb, cmu, crstd, dbnb, rp);
    // ---- final scalar ----
    finalize<<<1, 512, 0, stream>>>(rp, kp, out);
}

// Round 5
// 218.151 us; speedup vs baseline: 10.4450x; 1.1262x over previous
//
#include <hip/hip_runtime.h>
#include <cstddef>

// Shapes (fixed)
#define NB 512     // batch B
#define NM 64      // M sentences
#define NV 20000   // vocab V
#define NE 1024    // E
#define ND 384     // D
#define NT 100     // T topics
#define EPS 1e-5f

#define NVP 20096  // NV padded to 157*128
#define NKP 128    // decoder K padded (100 -> 128)
#define NHS 256    // stacked heads rows (100 mean | pad | 100 logvar | pad)

typedef __bf16 bf16x8 __attribute__((ext_vector_type(8)));
typedef float f32x4 __attribute__((ext_vector_type(4)));

__device__ __forceinline__ float softplus_f(float x) {
    return fmaxf(x, 0.f) + log1pf(expf(-fabsf(x)));
}

__device__ __forceinline__ unsigned short f2bf(float f) {
    unsigned u = __builtin_bit_cast(unsigned, f);
    unsigned r = u + 0x7FFFu + ((u >> 16) & 1u);   // RNE
    return (unsigned short)(r >> 16);
}

__device__ __forceinline__ float bf2f(unsigned short u) {
    return __builtin_bit_cast(float, (unsigned)u << 16);
}

// ---------------------------------------------------------------------------
// Multi-segment f32 -> bf16 convert; 8 elems/thread; per-segment blocks ni.
// ---------------------------------------------------------------------------
__global__ __launch_bounds__(256) void convert_multi(
        const float* __restrict__ s0, unsigned short* __restrict__ d0, int n0,
        const float* __restrict__ s1, unsigned short* __restrict__ d1, int n1,
        const float* __restrict__ s2, unsigned short* __restrict__ d2, int n2,
        const float* __restrict__ s3, unsigned short* __restrict__ d3, int n3,
        const float* __restrict__ s4, unsigned short* __restrict__ d4) {
    int b = blockIdx.x;
    const float* s; unsigned short* d;
    if (b < n0) { s = s0; d = d0; }
    else if ((b -= n0) < n1) { s = s1; d = d1; }
    else if ((b -= n1) < n2) { s = s2; d = d2; }
    else if ((b -= n2) < n3) { s = s3; d = d3; }
    else { b -= n3; s = s4; d = d4; }
    const size_t i = ((size_t)b * 256 + threadIdx.x) * 8;
    const float4 a = *reinterpret_cast<const float4*>(s + i);
    const float4 c = *reinterpret_cast<const float4*>(s + i + 4);
    union { unsigned short u[8]; uint4 v; } r;
    r.u[0] = f2bf(a.x); r.u[1] = f2bf(a.y); r.u[2] = f2bf(a.z); r.u[3] = f2bf(a.w);
    r.u[4] = f2bf(c.x); r.u[5] = f2bf(c.y); r.u[6] = f2bf(c.z); r.u[7] = f2bf(c.w);
    *reinterpret_cast<uint4*>(d + i) = r.v;
}

// ---------------------------------------------------------------------------
// k_w [384,384] f32 -> out [384,384]^T bf16 (transpose-convert).
// ---------------------------------------------------------------------------
__global__ __launch_bounds__(256) void transpose_convert_384(const float* __restrict__ in,
                                                             unsigned short* __restrict__ out) {
    __shared__ float tile[32][33];
    const int bx = blockIdx.x * 32;
    const int by = blockIdx.y * 32;
    const int tx = threadIdx.x, ty = threadIdx.y;
    #pragma unroll
    for (int i = 0; i < 4; ++i)
        tile[ty + 8 * i][tx] = in[(by + ty + 8 * i) * ND + bx + tx];
    __syncthreads();
    #pragma unroll
    for (int i = 0; i < 4; ++i)
        out[(size_t)(bx + ty + 8 * i) * ND + by + tx] = f2bf(tile[tx][ty + 8 * i]);
}

// ---------------------------------------------------------------------------
// Stack mean_w/logvar_w into [256,384] bf16 + (block 256) the stacked bias.
// ---------------------------------------------------------------------------
__global__ __launch_bounds__(256) void stack_heads(const float* __restrict__ mw,
                                                   const float* __restrict__ lw,
                                                   const float* __restrict__ mb,
                                                   const float* __restrict__ lb,
                                                   unsigned short* __restrict__ outw,
                                                   float* __restrict__ outb) {
    const int r = blockIdx.x;
    if (r == NHS) {
        const int t = threadIdx.x;
        outb[t] = (t < NT) ? mb[t] : (t >= 128 && t < 128 + NT) ? lb[t - 128] : 0.f;
        return;
    }
    const float* src = (r < NT) ? (mw + (size_t)r * ND)
                     : (r >= 128 && r < 128 + NT) ? (lw + (size_t)(r - 128) * ND) : nullptr;
    for (int c = threadIdx.x; c < ND; c += 256)
        outw[(size_t)r * ND + c] = src ? f2bf(src[c]) : (unsigned short)0;
}

// ---------------------------------------------------------------------------
// dec_w [NV,NT] f32 -> [NVP,NKP] bf16 zero-padded.
// ---------------------------------------------------------------------------
__global__ __launch_bounds__(128) void pad_decw(const float* __restrict__ in,
                                                unsigned short* __restrict__ out) {
    const int n = blockIdx.x, k = threadIdx.x;
    out[(size_t)n * NKP + k] = (n < NV && k < NT) ? f2bf(in[(size_t)n * NT + k]) : (unsigned short)0;
}

// ---------------------------------------------------------------------------
// MFMA GEMM core: 128x128 tile, BK=32, 4 waves (2x2), 16x16x32 bf16 frags.
// ---------------------------------------------------------------------------
#define BM 128
#define BN 128
#define BK 32

// Split-K partials (bf16): partial[s][m][n] = sum_{k chunk s} A[m,k]*Bw[n,k]
__global__ __launch_bounds__(256) void gemm_mfma_splitk(
        const unsigned short* __restrict__ A,
        const unsigned short* __restrict__ Bw,
        unsigned short* __restrict__ partial,
        int M, int N, int K, int S, int steps_total) {
    __shared__ __align__(16) unsigned short Asl[BM * BK];
    __shared__ __align__(16) unsigned short Bsl[BN * BK];
    const int tid = threadIdx.x;
    const int bn = blockIdx.x, bm = blockIdx.y, s = blockIdx.z;
    const int row0 = bm * BM, col0 = bn * BN;
    const int k_begin = (int)(((long)s * steps_total) / S) * BK;
    const int k_end   = (int)(((long)(s + 1) * steps_total) / S) * BK;

    const int srow = tid >> 2;
    const int scol = (tid & 3) * 8;
    const int wave = tid >> 6, lane = tid & 63;
    const int wm = wave >> 1, wn = wave & 1;
    const int lrow = lane & 15, lkb = lane >> 4;

    f32x4 acc[4][4] = {};
    const unsigned short* Ab = A + (size_t)row0 * K;
    const unsigned short* Bb = Bw + (size_t)col0 * K;

    for (int k0 = k_begin; k0 < k_end; k0 += BK) {
        #pragma unroll
        for (int i = 0; i < 2; ++i) {
            const int r = i * 64 + srow;
            __builtin_amdgcn_global_load_lds(
                (const __attribute__((address_space(1))) void*)(Ab + (size_t)r * K + k0 + scol),
                (__attribute__((address_space(3))) void*)(&Asl[(i * 256 + tid) * 8]),
                16, 0, 0);
            __builtin_amdgcn_global_load_lds(
                (const __attribute__((address_space(1))) void*)(Bb + (size_t)r * K + k0 + scol),
                (__attribute__((address_space(3))) void*)(&Bsl[(i * 256 + tid) * 8]),
                16, 0, 0);
        }
        __syncthreads();
        bf16x8 af[4], bfr[4];
        #pragma unroll
        for (int i = 0; i < 4; ++i) {
            af[i]  = *reinterpret_cast<const bf16x8*>(&Asl[(wm * 64 + i * 16 + lrow) * BK + lkb * 8]);
            bfr[i] = *reinterpret_cast<const bf16x8*>(&Bsl[(wn * 64 + i * 16 + lrow) * BK + lkb * 8]);
        }
        #pragma unroll
        for (int i = 0; i < 4; ++i)
            #pragma unroll
            for (int j = 0; j < 4; ++j)
                acc[i][j] = __builtin_amdgcn_mfma_f32_16x16x32_bf16(af[i], bfr[j], acc[i][j], 0, 0, 0);
        __syncthreads();
    }

    unsigned short* P = partial + (size_t)s * M * N;
    #pragma unroll
    for (int i = 0; i < 4; ++i) {
        const int rbase = row0 + wm * 64 + i * 16 + lkb * 4;
        #pragma unroll
        for (int j = 0; j < 4; ++j) {
            const int col = col0 + wn * 64 + j * 16 + lrow;
            #pragma unroll
            for (int r = 0; r < 4; ++r)
                P[(size_t)(rbase + r) * N + col] = f2bf(acc[i][j][r]);
        }
    }
}

// ---------------------------------------------------------------------------
// 64x64-tile split-K MFMA (for skinny GEMMs): 4 waves 2x2, each 32x32 out.
// Dims must divide 64; bf16 partials out.
// ---------------------------------------------------------------------------
__global__ __launch_bounds__(256) void gemm64_splitk(
        const unsigned short* __restrict__ A,
        const unsigned short* __restrict__ Bw,
        unsigned short* __restrict__ partial,
        int M, int N, int K, int S, int steps_total) {
    __shared__ __align__(16) unsigned short Asl[64 * BK];
    __shared__ __align__(16) unsigned short Bsl[64 * BK];
    const int tid = threadIdx.x;
    const int bn = blockIdx.x, bm = blockIdx.y, s = blockIdx.z;
    const int row0 = bm * 64, col0 = bn * 64;
    const int k_begin = (int)(((long)s * steps_total) / S) * BK;
    const int k_end   = (int)(((long)(s + 1) * steps_total) / S) * BK;

    const int srow = tid >> 2;
    const int scol = (tid & 3) * 8;
    const int wave = tid >> 6, lane = tid & 63;
    const int wm = wave >> 1, wn = wave & 1;
    const int lrow = lane & 15, lkb = lane >> 4;

    f32x4 acc[2][2] = {};
    const unsigned short* Ab = A + (size_t)row0 * K;
    const unsigned short* Bb = Bw + (size_t)col0 * K;

    for (int k0 = k_begin; k0 < k_end; k0 += BK) {
        __builtin_amdgcn_global_load_lds(
            (const __attribute__((address_space(1))) void*)(Ab + (size_t)srow * K + k0 + scol),
            (__attribute__((address_space(3))) void*)(&Asl[tid * 8]),
            16, 0, 0);
        __builtin_amdgcn_global_load_lds(
            (const __attribute__((address_space(1))) void*)(Bb + (size_t)srow * K + k0 + scol),
            (__attribute__((address_space(3))) void*)(&Bsl[tid * 8]),
            16, 0, 0);
        __syncthreads();
        bf16x8 af[2], bfr[2];
        #pragma unroll
        for (int i = 0; i < 2; ++i) {
            af[i]  = *reinterpret_cast<const bf16x8*>(&Asl[(wm * 32 + i * 16 + lrow) * BK + lkb * 8]);
            bfr[i] = *reinterpret_cast<const bf16x8*>(&Bsl[(wn * 32 + i * 16 + lrow) * BK + lkb * 8]);
        }
        #pragma unroll
        for (int i = 0; i < 2; ++i)
            #pragma unroll
            for (int j = 0; j < 2; ++j)
                acc[i][j] = __builtin_amdgcn_mfma_f32_16x16x32_bf16(af[i], bfr[j], acc[i][j], 0, 0, 0);
        __syncthreads();
    }

    unsigned short* P = partial + (size_t)s * M * N;
    #pragma unroll
    for (int i = 0; i < 2; ++i) {
        const int rbase = row0 + wm * 32 + i * 16 + lkb * 4;
        #pragma unroll
        for (int j = 0; j < 2; ++j) {
            const int col = col0 + wn * 32 + j * 16 + lrow;
            #pragma unroll
            for (int r = 0; r < 4; ++r)
                P[(size_t)(rbase + r) * N + col] = f2bf(acc[i][j][r]);
        }
    }
}

// ---------------------------------------------------------------------------
// Vectorized split-K reduce (bf16 partials): 8 elems/thread.
// MN must be a multiple of 2048; N a multiple of 8.
// ---------------------------------------------------------------------------
template<int OUT_BF16, int ACT, int HASBIAS>
__global__ __launch_bounds__(256) void reduce_splitk_bf(
        const unsigned short* __restrict__ partial,
        const float* __restrict__ bias,
        void* __restrict__ out, int MN, int N, int S) {
    const int i0 = (blockIdx.x * 256 + threadIdx.x) * 8;
    if (i0 >= MN) return;
    float sum[8] = {};
    for (int s = 0; s < S; ++s) {
        union { uint4 v; unsigned short u[8]; } p;
        p.v = *reinterpret_cast<const uint4*>(partial + (size_t)s * MN + i0);
        #pragma unroll
        for (int j = 0; j < 8; ++j) sum[j] += bf2f(p.u[j]);
    }
    if (HASBIAS) {
        const int nb = i0 % N;
        #pragma unroll
        for (int j = 0; j < 8; ++j) sum[j] += bias[nb + j];
    }
    if (ACT) {
        #pragma unroll
        for (int j = 0; j < 8; ++j) sum[j] = softplus_f(sum[j]);
    }
    if (OUT_BF16) {
        union { uint4 v; unsigned short u[8]; } r;
        #pragma unroll
        for (int j = 0; j < 8; ++j) r.u[j] = f2bf(sum[j]);
        *reinterpret_cast<uint4*>((unsigned short*)out + i0) = r.v;
    } else {
        float* o = (float*)out + i0;
        *reinterpret_cast<float4*>(o)     = make_float4(sum[0], sum[1], sum[2], sum[3]);
        *reinterpret_cast<float4*>(o + 4) = make_float4(sum[4], sum[5], sum[6], sum[7]);
    }
}

// Single-pass MFMA GEMM with fused epilogue: C = A@Bw^T + bias (bf16 out)
// + per-(rowblock,wave) column sum/sumsq partials (COLSTATS).
template<int OUT_BF16, int ACT, int HASBIAS, int COLSTATS>
__global__ __launch_bounds__(256) void gemm_mfma(
        const unsigned short* __restrict__ A,
        const unsigned short* __restrict__ Bw,
        const float* __restrict__ bias,
        void* __restrict__ Cout,
        float* __restrict__ colp,
        int M, int Nout, int K) {
    __shared__ __align__(16) unsigned short Asl[BM * BK];
    __shared__ __align__(16) unsigned short Bsl[BN * BK];
    const int tid = threadIdx.x;
    const int row0 = blockIdx.y * BM, col0 = blockIdx.x * BN;
    const int srow = tid >> 2;
    const int scol = (tid & 3) * 8;
    const int wave = tid >> 6, lane = tid & 63;
    const int wm = wave >> 1, wn = wave & 1;
    const int lrow = lane & 15, lkb = lane >> 4;

    f32x4 acc[4][4] = {};
    const unsigned short* Ab = A + (size_t)row0 * K;
    const unsigned short* Bb = Bw + (size_t)col0 * K;

    for (int k0 = 0; k0 < K; k0 += BK) {
        #pragma unroll
        for (int i = 0; i < 2; ++i) {
            const int r = i * 64 + srow;
            __builtin_amdgcn_global_load_lds(
                (const __attribute__((address_space(1))) void*)(Ab + (size_t)r * K + k0 + scol),
                (__attribute__((address_space(3))) void*)(&Asl[(i * 256 + tid) * 8]),
                16, 0, 0);
            __builtin_amdgcn_global_load_lds(
                (const __attribute__((address_space(1))) void*)(Bb + (size_t)r * K + k0 + scol),
                (__attribute__((address_space(3))) void*)(&Bsl[(i * 256 + tid) * 8]),
                16, 0, 0);
        }
        __syncthreads();
        bf16x8 af[4], bfr[4];
        #pragma unroll
        for (int i = 0; i < 4; ++i) {
            af[i]  = *reinterpret_cast<const bf16x8*>(&Asl[(wm * 64 + i * 16 + lrow) * BK + lkb * 8]);
            bfr[i] = *reinterpret_cast<const bf16x8*>(&Bsl[(wn * 64 + i * 16 + lrow) * BK + lkb * 8]);
        }
        #pragma unroll
        for (int i = 0; i < 4; ++i)
            #pragma unroll
            for (int j = 0; j < 4; ++j)
                acc[i][j] = __builtin_amdgcn_mfma_f32_16x16x32_bf16(af[i], bfr[j], acc[i][j], 0, 0, 0);
        __syncthreads();
    }

    #pragma unroll
    for (int j = 0; j < 4; ++j) {
        const int col = col0 + wn * 64 + j * 16 + lrow;
        const bool cok = col < Nout;
        const float bv = HASBIAS ? (cok ? bias[col] : 0.f) : 0.f;
        float csum = 0.f, csq = 0.f;
        #pragma unroll
        for (int i = 0; i < 4; ++i) {
            const int rbase = row0 + wm * 64 + i * 16 + lkb * 4;
            #pragma unroll
            for (int r = 0; r < 4; ++r) {
                float v = acc[i][j][r] + bv;
                if (ACT == 1) v = softplus_f(v);
                if (COLSTATS) { csum += v; csq = fmaf(v, v, csq); }
                if (cok) {
                    if (OUT_BF16)
                        ((unsigned short*)Cout)[(size_t)(rbase + r) * Nout + col] = f2bf(v);
                    else
                        ((float*)Cout)[(size_t)(rbase + r) * Nout + col] = v;
                }
            }
        }
        if (COLSTATS) {
            csum += __shfl_xor(csum, 16); csum += __shfl_xor(csum, 32);
            csq  += __shfl_xor(csq, 16);  csq  += __shfl_xor(csq, 32);
            if (lkb == 0) {
                const int w8 = blockIdx.y * 2 + wm;   // 0..7
                colp[(size_t)w8 * NVP + col] = csum;
                colp[(size_t)(8 + w8) * NVP + col] = csq;
            }
        }
    }
}

// ---------------------------------------------------------------------------
// Fused ragged attention, emb staged in LDS as bf16 (read emb ONCE).
// ---------------------------------------------------------------------------
__global__ __launch_bounds__(256) void attn_kernel(const float* __restrict__ qk,
                                                   const float* __restrict__ emb,
                                                   const int* __restrict__ lengths,
                                                   unsigned short* __restrict__ cb) {
    const int b = blockIdx.x;
    const int tid = threadIdx.x;
    __shared__ unsigned short es[NM * ND];  // 48 KB
    __shared__ float qs[ND];
    __shared__ float sc[NM];

    const float* ebase = emb + (size_t)b * NM * ND;
    for (int i = tid; i < NM * ND / 4; i += 256) {
        const float4 v = *reinterpret_cast<const float4*>(ebase + (size_t)i * 4);
        ushort4 o;
        o.x = f2bf(v.x); o.y = f2bf(v.y); o.z = f2bf(v.z); o.w = f2bf(v.w);
        *reinterpret_cast<ushort4*>(&es[i * 4]) = o;
    }
    for (int d = tid; d < ND; d += 256) qs[d] = qk[(size_t)b * ND + d];
    __syncthreads();

    const int wave = tid >> 6, lane = tid & 63;
    const float scale = 0.05103103630798288f;  // 1/sqrt(384)

    for (int m = wave; m < NM; m += 4) {
        float s = 0.f;
        for (int d = lane; d < ND; d += 64) s = fmaf(bf2f(es[m * ND + d]), qs[d], s);
        #pragma unroll
        for (int off = 32; off; off >>= 1) s += __shfl_xor(s, off);
        if (lane == 0) sc[m] = s * scale;
    }
    __syncthreads();

    const int len = lengths[b];
    if (tid < 64) {
        float s = (tid < len) ? sc[tid] : -INFINITY;
        float mx = s;
        #pragma unroll
        for (int off = 32; off; off >>= 1) mx = fmaxf(mx, __shfl_xor(mx, off));
        float e = (tid < len) ? expf(s - mx) : 0.f;
        float sum = e;
        #pragma unroll
        for (int off = 32; off; off >>= 1) sum += __shfl_xor(sum, off);
        sc[tid] = e / sum;
    }
    __syncthreads();

    for (int d = tid; d < ND; d += 256) {
        float acc = 0.f;
        for (int m = 0; m < len; ++m) acc = fmaf(sc[m], bf2f(es[m * ND + d]), acc);
        cb[(size_t)b * ND + d] = f2bf(acc);
    }
}

// ---------------------------------------------------------------------------
// BatchNorm over batch axis reading stacked heads hl [B,256].
// ---------------------------------------------------------------------------
__global__ __launch_bounds__(256) void bn_batch(const float* __restrict__ hl,
                                                const float* __restrict__ mbnb,
                                                const float* __restrict__ lbnb,
                                                float* __restrict__ mu,
                                                float* __restrict__ lv) {
    const int t = blockIdx.x;
    const int sel = blockIdx.y;
    const int col = sel ? 128 + t : t;
    const float* bnb = sel ? lbnb : mbnb;
    float* dst = sel ? lv : mu;
    const int tid = threadIdx.x;

    float s = 0.f, ss = 0.f;
    for (int b = tid; b < NB; b += 256) {
        const float v = hl[(size_t)b * NHS + col];
        s += v; ss += v * v;
    }
    __shared__ float rs[256], rss[256];
    rs[tid] = s; rss[tid] = ss;
    __syncthreads();
    for (int off = 128; off; off >>= 1) {
        if (tid < off) { rs[tid] += rs[tid + off]; rss[tid] += rss[tid + off]; }
        __syncthreads();
    }
    const float mean = rs[0] / (float)NB;
    const float var = rss[0] / (float)NB - mean * mean;
    const float rstd = rsqrtf(var + EPS);
    const float bb = bnb[t];
    for (int b = tid; b < NB; b += 256) {
        dst[(size_t)b * NT + t] = (hl[(size_t)b * NHS + col] - mean) * rstd + bb;
    }
}

// ---------------------------------------------------------------------------
// Per-row softmax over T -> thetab (bf16, zero-padded to 128) + KL partial.
// ---------------------------------------------------------------------------
__global__ __launch_bounds__(128) void theta_kl(const float* __restrict__ mu,
                                                const float* __restrict__ lv,
                                                unsigned short* __restrict__ thetab,
                                                float* __restrict__ kld_p) {
    const int b = blockIdx.x, tid = threadIdx.x;
    const float var2 = 1.0f - 1.0f / (float)NT;
    const float inv_var2 = 1.0f / var2;
    __shared__ float red[128];

    const float m = (tid < NT) ? mu[(size_t)b * NT + tid] : -INFINITY;
    red[tid] = m;
    __syncthreads();
    for (int off = 64; off; off >>= 1) {
        if (tid < off) red[tid] = fmaxf(red[tid], red[tid + off]);
        __syncthreads();
    }
    const float mx = red[0];
    __syncthreads();

    const float e = (tid < NT) ? expf(m - mx) : 0.f;
    red[tid] = e;
    __syncthreads();
    for (int off = 64; off; off >>= 1) {
        if (tid < off) red[tid] += red[tid + off];
        __syncthreads();
    }
    const float sum = red[0];
    __syncthreads();
    thetab[(size_t)b * NKP + tid] = (tid < NT) ? f2bf(e / sum) : (unsigned short)0;

    float term = 0.f;
    if (tid < NT) {
        const float l = lv[(size_t)b * NT + tid];
        term = expf(l) * inv_var2 + m * m * inv_var2 - l;
    }
    red[tid] = term;
    __syncthreads();
    for (int off = 64; off; off >>= 1) {
        if (tid < off) red[tid] += red[tid + off];
        __syncthreads();
    }
    if (tid == 0)
        kld_p[b] = 0.5f * (red[0] + (float)NT * logf(var2) - (float)NT);
}

// ---------------------------------------------------------------------------
// Combine the 8 per-wave column partials -> cmu, crstd.
// ---------------------------------------------------------------------------
__global__ __launch_bounds__(256) void stats_final(const float* __restrict__ colp,
                                                   float* __restrict__ cmu,
                                                   float* __restrict__ crstd) {
    const int v = blockIdx.x * 256 + threadIdx.x;
    if (v >= NV) return;
    float s = 0.f, q = 0.f;
    #pragma unroll
    for (int w = 0; w < 8; ++w) {
        s += colp[(size_t)w * NVP + v];
        q += colp[(size_t)(8 + w) * NVP + v];
    }
    const float mean = s / (float)NB;
    cmu[v] = mean;
    crstd[v] = rsqrtf(q / (float)NB - mean * mean + EPS);
}

// ---------------------------------------------------------------------------
// SINGLE pass over bf16 logit + bf16 x:
// online LSE of z; xz = sum x*z; xs = sum x; recon_p = xz - lse*xs.
// ---------------------------------------------------------------------------
__global__ __launch_bounds__(256) void row_recon(const unsigned short* __restrict__ logitb,
                                                 const unsigned short* __restrict__ xb,
                                                 const float* __restrict__ cmu,
                                                 const float* __restrict__ crstd,
                                                 const float* __restrict__ dbnb,
                                                 float* __restrict__ recon_p) {
    const int b = blockIdx.x, tid = threadIdx.x;
    const unsigned short* lr = logitb + (size_t)b * NV;
    const unsigned short* xr = xb + (size_t)b * NV;

    float m_i = -INFINITY, s_i = 0.f, xz = 0.f, xs = 0.f;
    for (int v = tid * 8; v < NV; v += 2048) {
        union { uint4 v4; unsigned short u[8]; } lw, xw;
        lw.v4 = *reinterpret_cast<const uint4*>(lr + v);
        xw.v4 = *reinterpret_cast<const uint4*>(xr + v);
        const float4 c0 = *reinterpret_cast<const float4*>(cmu + v);
        const float4 c1 = *reinterpret_cast<const float4*>(cmu + v + 4);
        const float4 r0 = *reinterpret_cast<const float4*>(crstd + v);
        const float4 r1 = *reinterpret_cast<const float4*>(crstd + v + 4);
        const float4 d0 = *reinterpret_cast<const float4*>(dbnb + v);
        const float4 d1 = *reinterpret_cast<const float4*>(dbnb + v + 4);
        const float cm[8] = {c0.x,c0.y,c0.z,c0.w,c1.x,c1.y,c1.z,c1.w};
        const float cr[8] = {r0.x,r0.y,r0.z,r0.w,r1.x,r1.y,r1.z,r1.w};
        const float db[8] = {d0.x,d0.y,d0.z,d0.w,d1.x,d1.y,d1.z,d1.w};
        float z[8];
        #pragma unroll
        for (int j = 0; j < 8; ++j)
            z[j] = fmaf(bf2f(lw.u[j]) - cm[j], cr[j], db[j]);
        float mx = z[0];
        #pragma unroll
        for (int j = 1; j < 8; ++j) mx = fmaxf(mx, z[j]);
        const float mnew = fmaxf(m_i, mx);
        float e8 = 0.f;
        #pragma unroll
        for (int j = 0; j < 8; ++j) e8 += expf(z[j] - mnew);
        s_i = s_i * expf(m_i - mnew) + e8;
        m_i = mnew;
        #pragma unroll
        for (int j = 0; j < 8; ++j) {
            const float xv = bf2f(xw.u[j]);
            xz = fmaf(xv, z[j], xz);
            xs += xv;
        }
    }

    __shared__ float rm[256], rs[256], rxz[256], rxs[256];
    rm[tid] = m_i; rs[tid] = s_i; rxz[tid] = xz; rxs[tid] = xs;
    __syncthreads();
    for (int off = 128; off; off >>= 1) {
        if (tid < off) {
            const float m1 = rm[tid], m2 = rm[tid + off];
            const float s1 = rs[tid], s2 = rs[tid + off];
            const float mm = fmaxf(m1, m2);
            rm[tid] = mm;
            rs[tid] = s1 * expf(m1 - mm) + s2 * expf(m2 - mm);
            rxz[tid] += rxz[tid + off];
            rxs[tid] += rxs[tid + off];
        }
        __syncthreads();
    }
    if (tid == 0) {
        const float lse = rm[0] + logf(rs[0]);
        recon_p[b] = rxz[0] - lse * rxs[0];
    }
}

// ---------------------------------------------------------------------------
// Final: out = -mean(recon_p) + mean(kld_p)
// ---------------------------------------------------------------------------
__global__ __launch_bounds__(512) void finalize(const float* __restrict__ recon_p,
                                                const float* __restrict__ kld_p,
                                                float* __restrict__ out) {
    const int tid = threadIdx.x;
    __shared__ float r1[512], r2[512];
    r1[tid] = recon_p[tid];
    r2[tid] = kld_p[tid];
    __syncthreads();
    for (int off = 256; off; off >>= 1) {
        if (tid < off) { r1[tid] += r1[tid + off]; r2[tid] += r2[tid + off]; }
        __syncthreads();
    }
    if (tid == 0) out[0] = (-r1[0] + r2[0]) / (float)NB;
}

extern "C" void kernel_launch(void* const* d_in, const int* in_sizes, int n_in,
                              void* d_out, int out_size, void* d_ws, size_t ws_size,
                              hipStream_t stream) {
    const float* x       = (const float*)d_in[0];
    const float* emb     = (const float*)d_in[1];
    const int*   lengths = (const int*)d_in[2];
    const float* fc11_w  = (const float*)d_in[3];
    const float* fc11_b  = (const float*)d_in[4];
    const float* fc12_w  = (const float*)d_in[5];
    const float* fc12_b  = (const float*)d_in[6];
    const float* q_w     = (const float*)d_in[7];
    const float* q_b     = (const float*)d_in[8];
    const float* k_w     = (const float*)d_in[9];
    // d_in[10] = k_b: cancels in softmax -> unused
    const float* v_w     = (const float*)d_in[11];
    const float* v_b     = (const float*)d_in[12];
    const float* mean_w  = (const float*)d_in[13];
    const float* mean_b  = (const float*)d_in[14];
    const float* lvw     = (const float*)d_in[15];
    const float* lvb     = (const float*)d_in[16];
    const float* mbnb    = (const float*)d_in[17];
    const float* lbnb    = (const float*)d_in[18];
    const float* dec_w   = (const float*)d_in[19];
    const float* dec_b   = (const float*)d_in[20];
    const float* dbnb    = (const float*)d_in[21];
    float* out = (float*)d_out;

    char* base = (char*)d_ws;
    size_t off = 0;
    auto alloc = [&](size_t bytes) -> void* {
        void* p = base + off;
        off += (bytes + 255) & ~(size_t)255;
        return p;
    };

    // wb11 (41MB) dead after fc11 GEMM; logitb (20.5MB) aliases it.
    unsigned short* wb11   = (unsigned short*)alloc((size_t)NE * NV * 2);
    unsigned short* logitb = wb11;
    unsigned short* xb     = (unsigned short*)alloc((size_t)NB * NV * 2);
    unsigned short* w12b   = (unsigned short*)alloc((size_t)NE * NE * 2);
    unsigned short* e1b    = (unsigned short*)alloc((size_t)NB * NE * 2);
    unsigned short* hb     = (unsigned short*)alloc((size_t)NB * NE * 2);
    unsigned short* qwb    = (unsigned short*)alloc((size_t)ND * NE * 2);
    unsigned short* kTb    = (unsigned short*)alloc((size_t)ND * ND * 2);
    unsigned short* vwb    = (unsigned short*)alloc((size_t)ND * ND * 2);
    unsigned short* qb     = (unsigned short*)alloc((size_t)NB * ND * 2);
    float*          qk     = (float*)alloc((size_t)NB * ND * 4);
    unsigned short* cb     = (unsigned short*)alloc((size_t)NB * ND * 2);
    unsigned short* dib    = (unsigned short*)alloc((size_t)NB * ND * 2);
    unsigned short* headwb = (unsigned short*)alloc((size_t)NHS * ND * 2);
    float*          headbb = (float*)alloc((size_t)NHS * 4);
    float*          hl     = (float*)alloc((size_t)NB * NHS * 4);
    float*          mu     = (float*)alloc((size_t)NB * NT * 4);
    float*          lv     = (float*)alloc((size_t)NB * NT * 4);
    float*          colp   = (float*)alloc((size_t)16 * NVP * 4);
    float*          cmu    = (float*)alloc((size_t)NV * 4);
    float*          crstd  = (float*)alloc((size_t)NV * 4);
    float*          rp     = (float*)alloc((size_t)NB * 4);
    float*          kp     = (float*)alloc((size_t)NB * 4);
    // small-GEMM bf16 split-K partials (max: q S=16 -> 6.3 MB)
    unsigned short* smallp = (unsigned short*)alloc((size_t)16 * NB * ND * 2);
    // big partials LAST; split-count adapts to remaining workspace (bf16)
    const size_t part_bytes_per_s = ((size_t)NB * NE * 2 + 255) & ~(size_t)255;
    const size_t remain = (ws_size > off) ? (ws_size - off) : 0;
    const int S11 = (remain >= 32 * part_bytes_per_s) ? 32
                  : (remain >= 16 * part_bytes_per_s) ? 16 : 8;
    unsigned short* partb = (unsigned short*)alloc((size_t)S11 * NB * NE * 2);
    // decwb/thetab alias partb (dead after fc12 reduce, before decoder)
    unsigned short* decwb  = partb;
    unsigned short* thetab = (unsigned short*)((char*)partb + (((size_t)NVP * NKP * 2 + 255) & ~(size_t)255));

    const dim3 blk(256);

    // ---- bf16 conversions (one merged kernel + transpose + head stack) ----
    convert_multi<<<15776, blk, 0, stream>>>(
        x, xb, (NB * NV) / 2048,
        fc11_w, wb11, (NE * NV) / 2048,
        fc12_w, w12b, (NE * NE) / 2048,
        q_w, qwb, (ND * NE) / 2048,
        v_w, vwb);
    transpose_convert_384<<<dim3(12, 12), dim3(32, 8), 0, stream>>>(k_w, kTb);
    stack_heads<<<NHS + 1, blk, 0, stream>>>(mean_w, lvw, mean_b, lvb, headwb, headbb);

    // ---- fc11: e1 = softplus(x @ fc11_w^T + b) ----
    gemm_mfma_splitk<<<dim3(NE / BN, NB / BM, S11), blk, 0, stream>>>(
        xb, wb11, partb, NB, NE, NV, S11, NV / BK);
    reduce_splitk_bf<1, 1, 1><<<(NB * NE) / 2048, blk, 0, stream>>>(
        partb, fc11_b, e1b, NB * NE, NE, S11);

    // ---- fc12: h = softplus(e1 @ fc12_w^T + b) ----
    gemm_mfma_splitk<<<dim3(NE / BN, NB / BM, 8), blk, 0, stream>>>(
        e1b, w12b, partb, NB, NE, NE, 8, NE / BK);
    reduce_splitk_bf<1, 1, 1><<<(NB * NE) / 2048, blk, 0, stream>>>(
        partb, fc12_b, hb, NB * NE, NE, 8);

    // partb now dead -> stage decoder pad buffer into it
    pad_decw<<<NVP, 128, 0, stream>>>(dec_w, decwb);

    // ---- q = h @ q_w^T + q_b (bf16) ----
    gemm64_splitk<<<dim3(ND / 64, NB / 64, 16), blk, 0, stream>>>(
        hb, qwb, smallp, NB, ND, NE, 16, NE / BK);
    reduce_splitk_bf<1, 0, 1><<<(NB * ND) / 2048, blk, 0, stream>>>(
        smallp, q_b, qb, NB * ND, ND, 16);
    // ---- qk = q @ k_w (via kT, no bias, f32) ----
    gemm64_splitk<<<dim3(ND / 64, NB / 64, 8), blk, 0, stream>>>(
        qb, kTb, smallp, NB, ND, ND, 8, ND / BK);
    reduce_splitk_bf<0, 0, 0><<<(NB * ND) / 2048, blk, 0, stream>>>(
        smallp, nullptr, qk, NB * ND, ND, 8);
    // ---- fused attention -> cb = bf16(sum_m alpha*emb) ----
    attn_kernel<<<NB, 256, 0, stream>>>(qk, emb, lengths, cb);
    // ---- d_i = c @ v_w^T + v_b (bf16) ----
    gemm64_splitk<<<dim3(ND / 64, NB / 64, 8), blk, 0, stream>>>(
        cb, vwb, smallp, NB, ND, ND, 8, ND / BK);
    reduce_splitk_bf<1, 0, 1><<<(NB * ND) / 2048, blk, 0, stream>>>(
        smallp, v_b, dib, NB * ND, ND, 8);
    // ---- stacked heads: hl = d_i @ headw^T + headb (f32 [B,256]) ----
    gemm64_splitk<<<dim3(NHS / 64, NB / 64, 8), blk, 0, stream>>>(
        dib, headwb, smallp, NB, NHS, ND, 8, ND / BK);
    reduce_splitk_bf<0, 0, 1><<<(NB * NHS) / 2048, blk, 0, stream>>>(
        smallp, headbb, hl, NB * NHS, NHS, 8);
    // ---- batchnorm both heads ----
    bn_batch<<<dim3(NT, 2), blk, 0, stream>>>(hl, mbnb, lbnb, mu, lv);
    // ---- theta softmax (bf16 padded) + KL partials ----
    theta_kl<<<NB, 128, 0, stream>>>(mu, lv, thetab, kp);
    // ---- decoder logits (bf16) + fused column stats partials ----
    gemm_mfma<1, 0, 1, 1><<<dim3(NVP / BN, NB / BM), blk, 0, stream>>>(
        thetab, decwb, dec_b, logitb, colp, NB, NV, NKP);
    stats_final<<<(NV + 255) / 256, blk, 0, stream>>>(colp, cmu, crstd);
    // ---- single-pass log-softmax dot x ----
    row_recon<<<NB, 256, 0, stream>>>(logitb, xb, cmu, crstd, dbnb, rp);
    // ---- final scalar ----
    finalize<<<1, 512, 0, stream>>>(rp, kp, out);
}

// Round 6
// 195.453 us; speedup vs baseline: 11.6579x; 1.1161x over previous
//
#include <hip/hip_runtime.h>
#include <cstddef>

// Shapes (fixed)
#define NB 512     // batch B
#define NM 64      // M sentences
#define NV 20000   // vocab V
#define NE 1024    // E
#define ND 384     // D
#define NT 100     // T topics
#define EPS 1e-5f

#define NVP 20096  // NV padded to 157*128
#define NKP 128    // decoder K padded (100 -> 128)
#define NHS 256    // stacked heads rows (100 mean | pad | 100 logvar | pad)

typedef __bf16 bf16x8 __attribute__((ext_vector_type(8)));
typedef float f32x4 __attribute__((ext_vector_type(4)));

__device__ __forceinline__ float softplus_f(float x) {
    return fmaxf(x, 0.f) + log1pf(expf(-fabsf(x)));
}

__device__ __forceinline__ unsigned short f2bf(float f) {
    unsigned u = __builtin_bit_cast(unsigned, f);
    unsigned r = u + 0x7FFFu + ((u >> 16) & 1u);   // RNE
    return (unsigned short)(r >> 16);
}

__device__ __forceinline__ float bf2f(unsigned short u) {
    return __builtin_bit_cast(float, (unsigned)u << 16);
}

__device__ __forceinline__ uint4 pack_bf8(float4 a, float4 b) {
    union { unsigned short u[8]; uint4 v; } r;
    r.u[0] = f2bf(a.x); r.u[1] = f2bf(a.y); r.u[2] = f2bf(a.z); r.u[3] = f2bf(a.w);
    r.u[4] = f2bf(b.x); r.u[5] = f2bf(b.y); r.u[6] = f2bf(b.z); r.u[7] = f2bf(b.w);
    return r.v;
}

__device__ __forceinline__ void convert8(const float* __restrict__ s,
                                         unsigned short* __restrict__ d,
                                         int b, int tid) {
    const size_t i = ((size_t)b * 256 + tid) * 8;
    const float4 a = *reinterpret_cast<const float4*>(s + i);
    const float4 c = *reinterpret_cast<const float4*>(s + i + 4);
    *reinterpret_cast<uint4*>(d + i) = pack_bf8(a, c);
}

// ---------------------------------------------------------------------------
// ONE prep kernel: fc12/q/v converts + k_w transpose + head stack + dec_w pad.
// Segments by block range (all independent).
// ---------------------------------------------------------------------------
#define PREP_C12 512                   // NE*NE/2048
#define PREP_QW  192                   // ND*NE/2048
#define PREP_VW  72                    // ND*ND/2048
#define PREP_TR  144                   // 12x12 transpose tiles
#define PREP_HD  257                   // head stack rows + bias
#define PREP_DW  (NVP / 2)             // dec_w pad, 2 rows/block
#define PREP_BLOCKS (PREP_C12 + PREP_QW + PREP_VW + PREP_TR + PREP_HD + PREP_DW)

__global__ __launch_bounds__(256) void prep_kernel(
        const float* __restrict__ fc12_w, unsigned short* __restrict__ w12b,
        const float* __restrict__ q_w,    unsigned short* __restrict__ qwb,
        const float* __restrict__ v_w,    unsigned short* __restrict__ vwb,
        const float* __restrict__ k_w,    unsigned short* __restrict__ kTb,
        const float* __restrict__ mw, const float* __restrict__ lw,
        const float* __restrict__ mb, const float* __restrict__ lb,
        unsigned short* __restrict__ headwb, float* __restrict__ headbb,
        const float* __restrict__ dec_w,  unsigned short* __restrict__ decwb) {
    __shared__ float tile[32][33];
    int b = blockIdx.x;
    const int tid = threadIdx.x;
    if (b < PREP_C12) { convert8(fc12_w, w12b, b, tid); return; }
    b -= PREP_C12;
    if (b < PREP_QW) { convert8(q_w, qwb, b, tid); return; }
    b -= PREP_QW;
    if (b < PREP_VW) { convert8(v_w, vwb, b, tid); return; }
    b -= PREP_VW;
    if (b < PREP_TR) {
        const int bx = (b % 12) * 32, by = (b / 12) * 32;
        const int tx = tid & 31, ty = tid >> 5;
        #pragma unroll
        for (int i = 0; i < 4; ++i)
            tile[ty + 8 * i][tx] = k_w[(size_t)(by + ty + 8 * i) * ND + bx + tx];
        __syncthreads();
        #pragma unroll
        for (int i = 0; i < 4; ++i)
            kTb[(size_t)(bx + ty + 8 * i) * ND + by + tx] = f2bf(tile[tx][ty + 8 * i]);
        return;
    }
    b -= PREP_TR;
    if (b < PREP_HD) {
        if (b == NHS) {
            if (tid < NHS)
                headbb[tid] = (tid < NT) ? mb[tid]
                            : (tid >= 128 && tid < 128 + NT) ? lb[tid - 128] : 0.f;
            return;
        }
        const float* src = (b < NT) ? (mw + (size_t)b * ND)
                         : (b >= 128 && b < 128 + NT) ? (lw + (size_t)(b - 128) * ND) : nullptr;
        for (int c = tid; c < ND; c += 256)
            headwb[(size_t)b * ND + c] = src ? f2bf(src[c]) : (unsigned short)0;
        return;
    }
    b -= PREP_HD;
    {   // dec_w pad: 2 rows per block
        const int n = b * 2 + (tid >> 7);
        const int k = tid & 127;
        decwb[(size_t)n * NKP + k] =
            (n < NV && k < NT) ? f2bf(dec_w[(size_t)n * NT + k]) : (unsigned short)0;
    }
}

// ---------------------------------------------------------------------------
// MFMA GEMM core params: 128x128 tile, BK=32, 4 waves (2x2), 16x16x32 frags.
// ---------------------------------------------------------------------------
#define BM 128
#define BN 128
#define BK 32

// ---------------------------------------------------------------------------
// fc11: FUSED-CONVERT split-K GEMM. A,Bw are f32 [M,K]/[N,K]; staged to LDS
// as bf16 in-register (same RNE as the old convert kernel). 1D grid with
// XCD-chunked swizzle: bm innermost (B-panel sharers together), then bn
// (A-panel sharers), then s; each XCD chunk covers S/8 consecutive s values.
// bf16 partials out. Requires S%8==0, gx*gy*S%8==0.
// ---------------------------------------------------------------------------
__global__ __launch_bounds__(256) void gemm_f32_splitk(
        const float* __restrict__ A,
        const float* __restrict__ Bw,
        unsigned short* __restrict__ partial,
        int M, int N, int K, int S, int steps_total, int gx, int gy) {
    __shared__ __align__(16) unsigned short Asl[BM * BK];
    __shared__ __align__(16) unsigned short Bsl[BN * BK];
    const int tid = threadIdx.x;
    // swizzled decomposition (assumes XCD = blockIdx.x % 8 round-robin)
    const int l = blockIdx.x >> 3;            // chunk-local id
    const int xcd = blockIdx.x & 7;
    const int bm = l % gy;
    const int rest = l / gy;
    const int bn = rest % gx;
    const int s_loc = rest / gx;
    const int s = xcd * (S >> 3) + s_loc;

    const int row0 = bm * BM, col0 = bn * BN;
    const int k_begin = (int)(((long)s * steps_total) / S) * BK;
    const int k_end   = (int)(((long)(s + 1) * steps_total) / S) * BK;

    const int sr = tid >> 2;          // 0..63
    const int sc = (tid & 3) * 8;     // 0,8,16,24
    const int wave = tid >> 6, lane = tid & 63;
    const int wm = wave >> 1, wn = wave & 1;
    const int lrow = lane & 15, lkb = lane >> 4;

    f32x4 acc[4][4] = {};
    const float* Ab = A + (size_t)row0 * K;
    const float* Bb = Bw + (size_t)col0 * K;

    for (int k0 = k_begin; k0 < k_end; k0 += BK) {
        float4 ra[2][2], rb[2][2];
        #pragma unroll
        for (int h = 0; h < 2; ++h) {
            const float* pa = Ab + (size_t)(h * 64 + sr) * K + k0 + sc;
            const float* pb = Bb + (size_t)(h * 64 + sr) * K + k0 + sc;
            ra[h][0] = *reinterpret_cast<const float4*>(pa);
            ra[h][1] = *reinterpret_cast<const float4*>(pa + 4);
            rb[h][0] = *reinterpret_cast<const float4*>(pb);
            rb[h][1] = *reinterpret_cast<const float4*>(pb + 4);
        }
        __syncthreads();   // previous iteration's LDS reads complete
        #pragma unroll
        for (int h = 0; h < 2; ++h) {
            *reinterpret_cast<uint4*>(&Asl[(h * 64 + sr) * BK + sc]) = pack_bf8(ra[h][0], ra[h][1]);
            *reinterpret_cast<uint4*>(&Bsl[(h * 64 + sr) * BK + sc]) = pack_bf8(rb[h][0], rb[h][1]);
        }
        __syncthreads();
        bf16x8 af[4], bfr[4];
        #pragma unroll
        for (int i = 0; i < 4; ++i) {
            af[i]  = *reinterpret_cast<const bf16x8*>(&Asl[(wm * 64 + i * 16 + lrow) * BK + lkb * 8]);
            bfr[i] = *reinterpret_cast<const bf16x8*>(&Bsl[(wn * 64 + i * 16 + lrow) * BK + lkb * 8]);
        }
        #pragma unroll
        for (int i = 0; i < 4; ++i)
            #pragma unroll
            for (int j = 0; j < 4; ++j)
                acc[i][j] = __builtin_amdgcn_mfma_f32_16x16x32_bf16(af[i], bfr[j], acc[i][j], 0, 0, 0);
    }

    unsigned short* P = partial + (size_t)s * M * N;
    #pragma unroll
    for (int i = 0; i < 4; ++i) {
        const int rbase = row0 + wm * 64 + i * 16 + lkb * 4;
        #pragma unroll
        for (int j = 0; j < 4; ++j) {
            const int col = col0 + wn * 64 + j * 16 + lrow;
            #pragma unroll
            for (int r = 0; r < 4; ++r)
                P[(size_t)(rbase + r) * N + col] = f2bf(acc[i][j][r]);
        }
    }
}

// ---------------------------------------------------------------------------
// bf16-input split-K GEMM (fc12): global_load_lds staging, bf16 partials.
// ---------------------------------------------------------------------------
__global__ __launch_bounds__(256) void gemm_mfma_splitk(
        const unsigned short* __restrict__ A,
        const unsigned short* __restrict__ Bw,
        unsigned short* __restrict__ partial,
        int M, int N, int K, int S, int steps_total) {
    __shared__ __align__(16) unsigned short Asl[BM * BK];
    __shared__ __align__(16) unsigned short Bsl[BN * BK];
    const int tid = threadIdx.x;
    const int bn = blockIdx.x, bm = blockIdx.y, s = blockIdx.z;
    const int row0 = bm * BM, col0 = bn * BN;
    const int k_begin = (int)(((long)s * steps_total) / S) * BK;
    const int k_end   = (int)(((long)(s + 1) * steps_total) / S) * BK;

    const int srow = tid >> 2;
    const int scol = (tid & 3) * 8;
    const int wave = tid >> 6, lane = tid & 63;
    const int wm = wave >> 1, wn = wave & 1;
    const int lrow = lane & 15, lkb = lane >> 4;

    f32x4 acc[4][4] = {};
    const unsigned short* Ab = A + (size_t)row0 * K;
    const unsigned short* Bb = Bw + (size_t)col0 * K;

    for (int k0 = k_begin; k0 < k_end; k0 += BK) {
        #pragma unroll
        for (int i = 0; i < 2; ++i) {
            const int r = i * 64 + srow;
            __builtin_amdgcn_global_load_lds(
                (const __attribute__((address_space(1))) void*)(Ab + (size_t)r * K + k0 + scol),
                (__attribute__((address_space(3))) void*)(&Asl[(i * 256 + tid) * 8]),
                16, 0, 0);
            __builtin_amdgcn_global_load_lds(
                (const __attribute__((address_space(1))) void*)(Bb + (size_t)r * K + k0 + scol),
                (__attribute__((address_space(3))) void*)(&Bsl[(i * 256 + tid) * 8]),
                16, 0, 0);
        }
        __syncthreads();
        bf16x8 af[4], bfr[4];
        #pragma unroll
        for (int i = 0; i < 4; ++i) {
            af[i]  = *reinterpret_cast<const bf16x8*>(&Asl[(wm * 64 + i * 16 + lrow) * BK + lkb * 8]);
            bfr[i] = *reinterpret_cast<const bf16x8*>(&Bsl[(wn * 64 + i * 16 + lrow) * BK + lkb * 8]);
        }
        #pragma unroll
        for (int i = 0; i < 4; ++i)
            #pragma unroll
            for (int j = 0; j < 4; ++j)
                acc[i][j] = __builtin_amdgcn_mfma_f32_16x16x32_bf16(af[i], bfr[j], acc[i][j], 0, 0, 0);
        __syncthreads();
    }

    unsigned short* P = partial + (size_t)s * M * N;
    #pragma unroll
    for (int i = 0; i < 4; ++i) {
        const int rbase = row0 + wm * 64 + i * 16 + lkb * 4;
        #pragma unroll
        for (int j = 0; j < 4; ++j) {
            const int col = col0 + wn * 64 + j * 16 + lrow;
            #pragma unroll
            for (int r = 0; r < 4; ++r)
                P[(size_t)(rbase + r) * N + col] = f2bf(acc[i][j][r]);
        }
    }
}

// ---------------------------------------------------------------------------
// 64x64-tile split-K MFMA (skinny GEMMs); bf16 partials.
// ---------------------------------------------------------------------------
__global__ __launch_bounds__(256) void gemm64_splitk(
        const unsigned short* __restrict__ A,
        const unsigned short* __restrict__ Bw,
        unsigned short* __restrict__ partial,
        int M, int N, int K, int S, int steps_total) {
    __shared__ __align__(16) unsigned short Asl[64 * BK];
    __shared__ __align__(16) unsigned short Bsl[64 * BK];
    const int tid = threadIdx.x;
    const int bn = blockIdx.x, bm = blockIdx.y, s = blockIdx.z;
    const int row0 = bm * 64, col0 = bn * 64;
    const int k_begin = (int)(((long)s * steps_total) / S) * BK;
    const int k_end   = (int)(((long)(s + 1) * steps_total) / S) * BK;

    const int srow = tid >> 2;
    const int scol = (tid & 3) * 8;
    const int wave = tid >> 6, lane = tid & 63;
    const int wm = wave >> 1, wn = wave & 1;
    const int lrow = lane & 15, lkb = lane >> 4;

    f32x4 acc[2][2] = {};
    const unsigned short* Ab = A + (size_t)row0 * K;
    const unsigned short* Bb = Bw + (size_t)col0 * K;

    for (int k0 = k_begin; k0 < k_end; k0 += BK) {
        __builtin_amdgcn_global_load_lds(
            (const __attribute__((address_space(1))) void*)(Ab + (size_t)srow * K + k0 + scol),
            (__attribute__((address_space(3))) void*)(&Asl[tid * 8]),
            16, 0, 0);
        __builtin_amdgcn_global_load_lds(
            (const __attribute__((address_space(1))) void*)(Bb + (size_t)srow * K + k0 + scol),
            (__attribute__((address_space(3))) void*)(&Bsl[tid * 8]),
            16, 0, 0);
        __syncthreads();
        bf16x8 af[2], bfr[2];
        #pragma unroll
        for (int i = 0; i < 2; ++i) {
            af[i]  = *reinterpret_cast<const bf16x8*>(&Asl[(wm * 32 + i * 16 + lrow) * BK + lkb * 8]);
            bfr[i] = *reinterpret_cast<const bf16x8*>(&Bsl[(wn * 32 + i * 16 + lrow) * BK + lkb * 8]);
        }
        #pragma unroll
        for (int i = 0; i < 2; ++i)
            #pragma unroll
            for (int j = 0; j < 2; ++j)
                acc[i][j] = __builtin_amdgcn_mfma_f32_16x16x32_bf16(af[i], bfr[j], acc[i][j], 0, 0, 0);
        __syncthreads();
    }

    unsigned short* P = partial + (size_t)s * M * N;
    #pragma unroll
    for (int i = 0; i < 2; ++i) {
        const int rbase = row0 + wm * 32 + i * 16 + lkb * 4;
        #pragma unroll
        for (int j = 0; j < 2; ++j) {
            const int col = col0 + wn * 32 + j * 16 + lrow;
            #pragma unroll
            for (int r = 0; r < 4; ++r)
                P[(size_t)(rbase + r) * N + col] = f2bf(acc[i][j][r]);
        }
    }
}

// ---------------------------------------------------------------------------
// Vectorized split-K reduce (bf16 partials): 8 elems/thread.
// ---------------------------------------------------------------------------
template<int OUT_BF16, int ACT, int HASBIAS>
__global__ __launch_bounds__(256) void reduce_splitk_bf(
        const unsigned short* __restrict__ partial,
        const float* __restrict__ bias,
        void* __restrict__ out, int MN, int N, int S) {
    const int i0 = (blockIdx.x * 256 + threadIdx.x) * 8;
    if (i0 >= MN) return;
    float sum[8] = {};
    for (int s = 0; s < S; ++s) {
        union { uint4 v; unsigned short u[8]; } p;
        p.v = *reinterpret_cast<const uint4*>(partial + (size_t)s * MN + i0);
        #pragma unroll
        for (int j = 0; j < 8; ++j) sum[j] += bf2f(p.u[j]);
    }
    if (HASBIAS) {
        const int nb = i0 % N;
        #pragma unroll
        for (int j = 0; j < 8; ++j) sum[j] += bias[nb + j];
    }
    if (ACT) {
        #pragma unroll
        for (int j = 0; j < 8; ++j) sum[j] = softplus_f(sum[j]);
    }
    if (OUT_BF16) {
        union { uint4 v; unsigned short u[8]; } r;
        #pragma unroll
        for (int j = 0; j < 8; ++j) r.u[j] = f2bf(sum[j]);
        *reinterpret_cast<uint4*>((unsigned short*)out + i0) = r.v;
    } else {
        float* o = (float*)out + i0;
        *reinterpret_cast<float4*>(o)     = make_float4(sum[0], sum[1], sum[2], sum[3]);
        *reinterpret_cast<float4*>(o + 4) = make_float4(sum[4], sum[5], sum[6], sum[7]);
    }
}

// Single-pass MFMA GEMM with fused epilogue (decoder): C = A@Bw^T + bias,
// bf16 out + per-(rowblock,wave) column sum/sumsq partials.
template<int OUT_BF16, int ACT, int HASBIAS, int COLSTATS>
__global__ __launch_bounds__(256) void gemm_mfma(
        const unsigned short* __restrict__ A,
        const unsigned short* __restrict__ Bw,
        const float* __restrict__ bias,
        void* __restrict__ Cout,
        float* __restrict__ colp,
        int M, int Nout, int K) {
    __shared__ __align__(16) unsigned short Asl[BM * BK];
    __shared__ __align__(16) unsigned short Bsl[BN * BK];
    const int tid = threadIdx.x;
    const int row0 = blockIdx.y * BM, col0 = blockIdx.x * BN;
    const int srow = tid >> 2;
    const int scol = (tid & 3) * 8;
    const int wave = tid >> 6, lane = tid & 63;
    const int wm = wave >> 1, wn = wave & 1;
    const int lrow = lane & 15, lkb = lane >> 4;

    f32x4 acc[4][4] = {};
    const unsigned short* Ab = A + (size_t)row0 * K;
    const unsigned short* Bb = Bw + (size_t)col0 * K;

    for (int k0 = 0; k0 < K; k0 += BK) {
        #pragma unroll
        for (int i = 0; i < 2; ++i) {
            const int r = i * 64 + srow;
            __builtin_amdgcn_global_load_lds(
                (const __attribute__((address_space(1))) void*)(Ab + (size_t)r * K + k0 + scol),
                (__attribute__((address_space(3))) void*)(&Asl[(i * 256 + tid) * 8]),
                16, 0, 0);
            __builtin_amdgcn_global_load_lds(
                (const __attribute__((address_space(1))) void*)(Bb + (size_t)r * K + k0 + scol),
                (__attribute__((address_space(3))) void*)(&Bsl[(i * 256 + tid) * 8]),
                16, 0, 0);
        }
        __syncthreads();
        bf16x8 af[4], bfr[4];
        #pragma unroll
        for (int i = 0; i < 4; ++i) {
            af[i]  = *reinterpret_cast<const bf16x8*>(&Asl[(wm * 64 + i * 16 + lrow) * BK + lkb * 8]);
            bfr[i] = *reinterpret_cast<const bf16x8*>(&Bsl[(wn * 64 + i * 16 + lrow) * BK + lkb * 8]);
        }
        #pragma unroll
        for (int i = 0; i < 4; ++i)
            #pragma unroll
            for (int j = 0; j < 4; ++j)
                acc[i][j] = __builtin_amdgcn_mfma_f32_16x16x32_bf16(af[i], bfr[j], acc[i][j], 0, 0, 0);
        __syncthreads();
    }

    #pragma unroll
    for (int j = 0; j < 4; ++j) {
        const int col = col0 + wn * 64 + j * 16 + lrow;
        const bool cok = col < Nout;
        const float bv = HASBIAS ? (cok ? bias[col] : 0.f) : 0.f;
        float csum = 0.f, csq = 0.f;
        #pragma unroll
        for (int i = 0; i < 4; ++i) {
            const int rbase = row0 + wm * 64 + i * 16 + lkb * 4;
            #pragma unroll
            for (int r = 0; r < 4; ++r) {
                float v = acc[i][j][r] + bv;
                if (ACT == 1) v = softplus_f(v);
                if (COLSTATS) { csum += v; csq = fmaf(v, v, csq); }
                if (cok) {
                    if (OUT_BF16)
                        ((unsigned short*)Cout)[(size_t)(rbase + r) * Nout + col] = f2bf(v);
                    else
                        ((float*)Cout)[(size_t)(rbase + r) * Nout + col] = v;
                }
            }
        }
        if (COLSTATS) {
            csum += __shfl_xor(csum, 16); csum += __shfl_xor(csum, 32);
            csq  += __shfl_xor(csq, 16);  csq  += __shfl_xor(csq, 32);
            if (lkb == 0) {
                const int w8 = blockIdx.y * 2 + wm;   // 0..7
                colp[(size_t)w8 * NVP + col] = csum;
                colp[(size_t)(8 + w8) * NVP + col] = csq;
            }
        }
    }
}

// ---------------------------------------------------------------------------
// Fused ragged attention + qk split-K reduce; emb staged in LDS as bf16.
// qkp: bf16 partials [8][NB][ND] from the qk GEMM.
// ---------------------------------------------------------------------------
__global__ __launch_bounds__(256) void attn_kernel(const unsigned short* __restrict__ qkp,
                                                   const float* __restrict__ emb,
                                                   const int* __restrict__ lengths,
                                                   unsigned short* __restrict__ cb) {
    const int b = blockIdx.x;
    const int tid = threadIdx.x;
    __shared__ unsigned short es[NM * ND];  // 48 KB
    __shared__ float qs[ND];
    __shared__ float sc[NM];

    const float* ebase = emb + (size_t)b * NM * ND;
    for (int i = tid; i < NM * ND / 4; i += 256) {
        const float4 v = *reinterpret_cast<const float4*>(ebase + (size_t)i * 4);
        ushort4 o;
        o.x = f2bf(v.x); o.y = f2bf(v.y); o.z = f2bf(v.z); o.w = f2bf(v.w);
        *reinterpret_cast<ushort4*>(&es[i * 4]) = o;
    }
    for (int d = tid; d < ND; d += 256) {
        float acc = 0.f;
        #pragma unroll
        for (int s = 0; s < 8; ++s)
            acc += bf2f(qkp[((size_t)s * NB + b) * ND + d]);
        qs[d] = acc;
    }
    __syncthreads();

    const int wave = tid >> 6, lane = tid & 63;
    const float scale = 0.05103103630798288f;  // 1/sqrt(384)

    for (int m = wave; m < NM; m += 4) {
        float s = 0.f;
        for (int d = lane; d < ND; d += 64) s = fmaf(bf2f(es[m * ND + d]), qs[d], s);
        #pragma unroll
        for (int off = 32; off; off >>= 1) s += __shfl_xor(s, off);
        if (lane == 0) sc[m] = s * scale;
    }
    __syncthreads();

    const int len = lengths[b];
    if (tid < 64) {
        float s = (tid < len) ? sc[tid] : -INFINITY;
        float mx = s;
        #pragma unroll
        for (int off = 32; off; off >>= 1) mx = fmaxf(mx, __shfl_xor(mx, off));
        float e = (tid < len) ? expf(s - mx) : 0.f;
        float sum = e;
        #pragma unroll
        for (int off = 32; off; off >>= 1) sum += __shfl_xor(sum, off);
        sc[tid] = e / sum;
    }
    __syncthreads();

    for (int d = tid; d < ND; d += 256) {
        float acc = 0.f;
        for (int m = 0; m < len; ++m) acc = fmaf(sc[m], bf2f(es[m * ND + d]), acc);
        cb[(size_t)b * ND + d] = f2bf(acc);
    }
}

// ---------------------------------------------------------------------------
// BatchNorm over batch axis reading stacked heads hl [B,256].
// ---------------------------------------------------------------------------
__global__ __launch_bounds__(256) void bn_batch(const float* __restrict__ hl,
                                                const float* __restrict__ mbnb,
                                                const float* __restrict__ lbnb,
                                                float* __restrict__ mu,
                                                float* __restrict__ lv) {
    const int t = blockIdx.x;
    const int sel = blockIdx.y;
    const int col = sel ? 128 + t : t;
    const float* bnb = sel ? lbnb : mbnb;
    float* dst = sel ? lv : mu;
    const int tid = threadIdx.x;

    float s = 0.f, ss = 0.f;
    for (int b = tid; b < NB; b += 256) {
        const float v = hl[(size_t)b * NHS + col];
        s += v; ss += v * v;
    }
    __shared__ float rs[256], rss[256];
    rs[tid] = s; rss[tid] = ss;
    __syncthreads();
    for (int off = 128; off; off >>= 1) {
        if (tid < off) { rs[tid] += rs[tid + off]; rss[tid] += rss[tid + off]; }
        __syncthreads();
    }
    const float mean = rs[0] / (float)NB;
    const float var = rss[0] / (float)NB - mean * mean;
    const float rstd = rsqrtf(var + EPS);
    const float bb = bnb[t];
    for (int b = tid; b < NB; b += 256) {
        dst[(size_t)b * NT + t] = (hl[(size_t)b * NHS + col] - mean) * rstd + bb;
    }
}

// ---------------------------------------------------------------------------
// Per-row softmax over T -> thetab (bf16, zero-padded to 128) + KL partial.
// ---------------------------------------------------------------------------
__global__ __launch_bounds__(128) void theta_kl(const float* __restrict__ mu,
                                                const float* __restrict__ lv,
                                                unsigned short* __restrict__ thetab,
                                                float* __restrict__ kld_p) {
    const int b = blockIdx.x, tid = threadIdx.x;
    const float var2 = 1.0f - 1.0f / (float)NT;
    const float inv_var2 = 1.0f / var2;
    __shared__ float red[128];

    const float m = (tid < NT) ? mu[(size_t)b * NT + tid] : -INFINITY;
    red[tid] = m;
    __syncthreads();
    for (int off = 64; off; off >>= 1) {
        if (tid < off) red[tid] = fmaxf(red[tid], red[tid + off]);
        __syncthreads();
    }
    const float mx = red[0];
    __syncthreads();

    const float e = (tid < NT) ? expf(m - mx) : 0.f;
    red[tid] = e;
    __syncthreads();
    for (int off = 64; off; off >>= 1) {
        if (tid < off) red[tid] += red[tid + off];
        __syncthreads();
    }
    const float sum = red[0];
    __syncthreads();
    thetab[(size_t)b * NKP + tid] = (tid < NT) ? f2bf(e / sum) : (unsigned short)0;

    float term = 0.f;
    if (tid < NT) {
        const float l = lv[(size_t)b * NT + tid];
        term = expf(l) * inv_var2 + m * m * inv_var2 - l;
    }
    red[tid] = term;
    __syncthreads();
    for (int off = 64; off; off >>= 1) {
        if (tid < off) red[tid] += red[tid + off];
        __syncthreads();
    }
    if (tid == 0)
        kld_p[b] = 0.5f * (red[0] + (float)NT * logf(var2) - (float)NT);
}

// ---------------------------------------------------------------------------
// Combine the 8 per-wave column partials -> cmu, crstd.
// ---------------------------------------------------------------------------
__global__ __launch_bounds__(256) void stats_final(const float* __restrict__ colp,
                                                   float* __restrict__ cmu,
                                                   float* __restrict__ crstd) {
    const int v = blockIdx.x * 256 + threadIdx.x;
    if (v >= NV) return;
    float s = 0.f, q = 0.f;
    #pragma unroll
    for (int w = 0; w < 8; ++w) {
        s += colp[(size_t)w * NVP + v];
        q += colp[(size_t)(8 + w) * NVP + v];
    }
    const float mean = s / (float)NB;
    cmu[v] = mean;
    crstd[v] = rsqrtf(q / (float)NB - mean * mean + EPS);
}

// ---------------------------------------------------------------------------
// SINGLE pass over bf16 logit + f32 x:
// online LSE of z; xz = sum x*z; xs = sum x; recon_p = xz - lse*xs.
// ---------------------------------------------------------------------------
__global__ __launch_bounds__(256) void row_recon(const unsigned short* __restrict__ logitb,
                                                 const float* __restrict__ x,
                                                 const float* __restrict__ cmu,
                                                 const float* __restrict__ crstd,
                                                 const float* __restrict__ dbnb,
                                                 float* __restrict__ recon_p) {
    const int b = blockIdx.x, tid = threadIdx.x;
    const unsigned short* lr = logitb + (size_t)b * NV;
    const float* xr = x + (size_t)b * NV;

    float m_i = -INFINITY, s_i = 0.f, xz = 0.f, xs = 0.f;
    for (int v = tid * 8; v < NV; v += 2048) {
        union { uint4 v4; unsigned short u[8]; } lw;
        lw.v4 = *reinterpret_cast<const uint4*>(lr + v);
        const float4 x0 = *reinterpret_cast<const float4*>(xr + v);
        const float4 x1 = *reinterpret_cast<const float4*>(xr + v + 4);
        const float4 c0 = *reinterpret_cast<const float4*>(cmu + v);
        const float4 c1 = *reinterpret_cast<const float4*>(cmu + v + 4);
        const float4 r0 = *reinterpret_cast<const float4*>(crstd + v);
        const float4 r1 = *reinterpret_cast<const float4*>(crstd + v + 4);
        const float4 d0 = *reinterpret_cast<const float4*>(dbnb + v);
        const float4 d1 = *reinterpret_cast<const float4*>(dbnb + v + 4);
        const float xv[8] = {x0.x,x0.y,x0.z,x0.w,x1.x,x1.y,x1.z,x1.w};
        const float cm[8] = {c0.x,c0.y,c0.z,c0.w,c1.x,c1.y,c1.z,c1.w};
        const float cr[8] = {r0.x,r0.y,r0.z,r0.w,r1.x,r1.y,r1.z,r1.w};
        const float db[8] = {d0.x,d0.y,d0.z,d0.w,d1.x,d1.y,d1.z,d1.w};
        float z[8];
        #pragma unroll
        for (int j = 0; j < 8; ++j)
            z[j] = fmaf(bf2f(lw.u[j]) - cm[j], cr[j], db[j]);
        float mx = z[0];
        #pragma unroll
        for (int j = 1; j < 8; ++j) mx = fmaxf(mx, z[j]);
        const float mnew = fmaxf(m_i, mx);
        float e8 = 0.f;
        #pragma unroll
        for (int j = 0; j < 8; ++j) e8 += expf(z[j] - mnew);
        s_i = s_i * expf(m_i - mnew) + e8;
        m_i = mnew;
        #pragma unroll
        for (int j = 0; j < 8; ++j) {
            xz = fmaf(xv[j], z[j], xz);
            xs += xv[j];
        }
    }

    __shared__ float rm[256], rs[256], rxz[256], rxs[256];
    rm[tid] = m_i; rs[tid] = s_i; rxz[tid] = xz; rxs[tid] = xs;
    __syncthreads();
    for (int off = 128; off; off >>= 1) {
        if (tid < off) {
            const float m1 = rm[tid], m2 = rm[tid + off];
            const float s1 = rs[tid], s2 = rs[tid + off];
            const float mm = fmaxf(m1, m2);
            rm[tid] = mm;
            rs[tid] = s1 * expf(m1 - mm) + s2 * expf(m2 - mm);
            rxz[tid] += rxz[tid + off];
            rxs[tid] += rxs[tid + off];
        }
        __syncthreads();
    }
    if (tid == 0) {
        const float lse = rm[0] + logf(rs[0]);
        recon_p[b] = rxz[0] - lse * rxs[0];
    }
}

// ---------------------------------------------------------------------------
// Final: out = -mean(recon_p) + mean(kld_p)
// ---------------------------------------------------------------------------
__global__ __launch_bounds__(512) void finalize(const float* __restrict__ recon_p,
                                                const float* __restrict__ kld_p,
                                                float* __restrict__ out) {
    const int tid = threadIdx.x;
    __shared__ float r1[512], r2[512];
    r1[tid] = recon_p[tid];
    r2[tid] = kld_p[tid];
    __syncthreads();
    for (int off = 256; off; off >>= 1) {
        if (tid < off) { r1[tid] += r1[tid + off]; r2[tid] += r2[tid + off]; }
        __syncthreads();
    }
    if (tid == 0) out[0] = (-r1[0] + r2[0]) / (float)NB;
}

extern "C" void kernel_launch(void* const* d_in, const int* in_sizes, int n_in,
                              void* d_out, int out_size, void* d_ws, size_t ws_size,
                              hipStream_t stream) {
    const float* x       = (const float*)d_in[0];
    const float* emb     = (const float*)d_in[1];
    const int*   lengths = (const int*)d_in[2];
    const float* fc11_w  = (const float*)d_in[3];
    const float* fc11_b  = (const float*)d_in[4];
    const float* fc12_w  = (const float*)d_in[5];
    const float* fc12_b  = (const float*)d_in[6];
    const float* q_w     = (const float*)d_in[7];
    const float* q_b     = (const float*)d_in[8];
    const float* k_w     = (const float*)d_in[9];
    // d_in[10] = k_b: cancels in softmax -> unused
    const float* v_w     = (const float*)d_in[11];
    const float* v_b     = (const float*)d_in[12];
    const float* mean_w  = (const float*)d_in[13];
    const float* mean_b  = (const float*)d_in[14];
    const float* lvw     = (const float*)d_in[15];
    const float* lvb     = (const float*)d_in[16];
    const float* mbnb    = (const float*)d_in[17];
    const float* lbnb    = (const float*)d_in[18];
    const float* dec_w   = (const float*)d_in[19];
    const float* dec_b   = (const float*)d_in[20];
    const float* dbnb    = (const float*)d_in[21];
    float* out = (float*)d_out;

    char* base = (char*)d_ws;
    size_t off = 0;
    auto alloc = [&](size_t bytes) -> void* {
        void* p = base + off;
        off += (bytes + 255) & ~(size_t)255;
        return p;
    };

    unsigned short* logitb = (unsigned short*)alloc((size_t)NB * NV * 2);
    unsigned short* w12b   = (unsigned short*)alloc((size_t)NE * NE * 2);
    unsigned short* e1b    = (unsigned short*)alloc((size_t)NB * NE * 2);
    unsigned short* hb     = (unsigned short*)alloc((size_t)NB * NE * 2);
    unsigned short* qwb    = (unsigned short*)alloc((size_t)ND * NE * 2);
    unsigned short* kTb    = (unsigned short*)alloc((size_t)ND * ND * 2);
    unsigned short* vwb    = (unsigned short*)alloc((size_t)ND * ND * 2);
    unsigned short* qb     = (unsigned short*)alloc((size_t)NB * ND * 2);
    unsigned short* cb     = (unsigned short*)alloc((size_t)NB * ND * 2);
    unsigned short* dib    = (unsigned short*)alloc((size_t)NB * ND * 2);
    unsigned short* headwb = (unsigned short*)alloc((size_t)NHS * ND * 2);
    float*          headbb = (float*)alloc((size_t)NHS * 4);
    float*          hl     = (float*)alloc((size_t)NB * NHS * 4);
    float*          mu     = (float*)alloc((size_t)NB * NT * 4);
    float*          lv     = (float*)alloc((size_t)NB * NT * 4);
    float*          colp   = (float*)alloc((size_t)16 * NVP * 4);
    float*          cmu    = (float*)alloc((size_t)NV * 4);
    float*          crstd  = (float*)alloc((size_t)NV * 4);
    float*          rp     = (float*)alloc((size_t)NB * 4);
    float*          kp     = (float*)alloc((size_t)NB * 4);
    unsigned short* decwb  = (unsigned short*)alloc((size_t)NVP * NKP * 2);
    unsigned short* thetab = (unsigned short*)alloc((size_t)NB * NKP * 2);
    // small-GEMM bf16 split-K partials (max: q S=16 -> 6.3 MB)
    unsigned short* smallp = (unsigned short*)alloc((size_t)16 * NB * ND * 2);
    // big partials LAST; split adapts to remaining workspace (S%8==0 needed)
    const size_t part_bytes_per_s = ((size_t)NB * NE * 2 + 255) & ~(size_t)255;
    const size_t remain = (ws_size > off) ? (ws_size - off) : 0;
    const int S11 = (remain >= 32 * part_bytes_per_s) ? 32
                  : (remain >= 16 * part_bytes_per_s) ? 16 : 8;
    unsigned short* partb = (unsigned short*)alloc((size_t)S11 * NB * NE * 2);

    const dim3 blk(256);

    // ---- one prep kernel: converts + transpose + head stack + dec_w pad ----
    prep_kernel<<<PREP_BLOCKS, blk, 0, stream>>>(
        fc12_w, w12b, q_w, qwb, v_w, vwb, k_w, kTb,
        mean_w, lvw, mean_b, lvb, headwb, headbb, dec_w, decwb);

    // ---- fc11: e1 = softplus(x @ fc11_w^T + b), FUSED f32->bf16 staging ----
    gemm_f32_splitk<<<(NE / BN) * (NB / BM) * S11, blk, 0, stream>>>(
        x, fc11_w, partb, NB, NE, NV, S11, NV / BK, NE / BN, NB / BM);
    reduce_splitk_bf<1, 1, 1><<<(NB * NE) / 2048, blk, 0, stream>>>(
        partb, fc11_b, e1b, NB * NE, NE, S11);

    // ---- fc12: h = softplus(e1 @ fc12_w^T + b) ----
    gemm_mfma_splitk<<<dim3(NE / BN, NB / BM, 8), blk, 0, stream>>>(
        e1b, w12b, partb, NB, NE, NE, 8, NE / BK);
    reduce_splitk_bf<1, 1, 1><<<(NB * NE) / 2048, blk, 0, stream>>>(
        partb, fc12_b, hb, NB * NE, NE, 8);

    // ---- q = h @ q_w^T + q_b (bf16) ----
    gemm64_splitk<<<dim3(ND / 64, NB / 64, 16), blk, 0, stream>>>(
        hb, qwb, smallp, NB, ND, NE, 16, NE / BK);
    reduce_splitk_bf<1, 0, 1><<<(NB * ND) / 2048, blk, 0, stream>>>(
        smallp, q_b, qb, NB * ND, ND, 16);
    // ---- qk = q @ k_w (via kT): partials only; reduce fused into attn ----
    gemm64_splitk<<<dim3(ND / 64, NB / 64, 8), blk, 0, stream>>>(
        qb, kTb, smallp, NB, ND, ND, 8, ND / BK);
    // ---- fused attention (+qk reduce) -> cb = bf16(sum_m alpha*emb) ----
    attn_kernel<<<NB, 256, 0, stream>>>(smallp, emb, lengths, cb);
    // ---- d_i = c @ v_w^T + v_b (bf16) ----
    gemm64_splitk<<<dim3(ND / 64, NB / 64, 8), blk, 0, stream>>>(
        cb, vwb, smallp, NB, ND, ND, 8, ND / BK);
    reduce_splitk_bf<1, 0, 1><<<(NB * ND) / 2048, blk, 0, stream>>>(
        smallp, v_b, dib, NB * ND, ND, 8);
    // ---- stacked heads: hl = d_i @ headw^T + headb (f32 [B,256]) ----
    gemm64_splitk<<<dim3(NHS / 64, NB / 64, 8), blk, 0, stream>>>(
        dib, headwb, smallp, NB, NHS, ND, 8, ND / BK);
    reduce_splitk_bf<0, 0, 1><<<(NB * NHS) / 2048, blk, 0, stream>>>(
        smallp, headbb, hl, NB * NHS, NHS, 8);
    // ---- batchnorm both heads ----
    bn_batch<<<dim3(NT, 2), blk, 0, stream>>>(hl, mbnb, lbnb, mu, lv);
    // ---- theta softmax (bf16 padded) + KL partials ----
    theta_kl<<<NB, 128, 0, stream>>>(mu, lv, thetab, kp);
    // ---- decoder logits (bf16) + fused column stats partials ----
    gemm_mfma<1, 0, 1, 1><<<dim3(NVP / BN, NB / BM), blk, 0, stream>>>(
        thetab, decwb, dec_b, logitb, colp, NB, NV, NKP);
    stats_final<<<(NV + 255) / 256, blk, 0, stream>>>(colp, cmu, crstd);
    // ---- single-pass log-softmax dot x (f32 x) ----
    row_recon<<<NB, 256, 0, stream>>>(logitb, x, cmu, crstd, dbnb, rp);
    // ---- final scalar ----
    finalize<<<1, 512, 0, stream>>>(rp, kp, out);
}

// Round 7
// 181.265 us; speedup vs baseline: 12.5704x; 1.0783x over previous
//
#include <hip/hip_runtime.h>
#include <cstddef>

// Shapes (fixed)
#define NB 512     // batch B
#define NM 64      // M sentences
#define NV 20000   // vocab V
#define NE 1024    // E
#define ND 384     // D
#define NT 100     // T topics
#define EPS 1e-5f

#define NVP 20096  // NV padded to 157*128
#define NKP 128    // decoder K padded (100 -> 128)
#define NHS 256    // stacked heads rows (100 mean | pad | 100 logvar | pad)

typedef __bf16 bf16x8 __attribute__((ext_vector_type(8)));
typedef float f32x4 __attribute__((ext_vector_type(4)));

__device__ __forceinline__ float softplus_f(float x) {
    return fmaxf(x, 0.f) + log1pf(expf(-fabsf(x)));
}

__device__ __forceinline__ unsigned short f2bf(float f) {
    unsigned u = __builtin_bit_cast(unsigned, f);
    unsigned r = u + 0x7FFFu + ((u >> 16) & 1u);   // RNE
    return (unsigned short)(r >> 16);
}

__device__ __forceinline__ float bf2f(unsigned short u) {
    return __builtin_bit_cast(float, (unsigned)u << 16);
}

// Native-cast pack: compiler emits v_cvt_pk_bf16_f32 (RNE), ~6x fewer VALU
// ops than the manual bit-math path.
__device__ __forceinline__ uint4 pack_bf8(float4 a, float4 b) {
    bf16x8 v;
    v[0] = (__bf16)a.x; v[1] = (__bf16)a.y; v[2] = (__bf16)a.z; v[3] = (__bf16)a.w;
    v[4] = (__bf16)b.x; v[5] = (__bf16)b.y; v[6] = (__bf16)b.z; v[7] = (__bf16)b.w;
    return __builtin_bit_cast(uint4, v);
}

__device__ __forceinline__ void convert8(const float* __restrict__ s,
                                         unsigned short* __restrict__ d,
                                         int b, int tid) {
    const size_t i = ((size_t)b * 256 + tid) * 8;
    const float4 a = *reinterpret_cast<const float4*>(s + i);
    const float4 c = *reinterpret_cast<const float4*>(s + i + 4);
    *reinterpret_cast<uint4*>(d + i) = pack_bf8(a, c);
}

// ---------------------------------------------------------------------------
// ONE prep kernel: fc12/q/v converts + k_w transpose + head stack + dec_w pad.
// ---------------------------------------------------------------------------
#define PREP_C12 512                   // NE*NE/2048
#define PREP_QW  192                   // ND*NE/2048
#define PREP_VW  72                    // ND*ND/2048
#define PREP_TR  144                   // 12x12 transpose tiles
#define PREP_HD  257                   // head stack rows + bias
#define PREP_DW  (NVP / 2)             // dec_w pad, 2 rows/block
#define PREP_BLOCKS (PREP_C12 + PREP_QW + PREP_VW + PREP_TR + PREP_HD + PREP_DW)

__global__ __launch_bounds__(256) void prep_kernel(
        const float* __restrict__ fc12_w, unsigned short* __restrict__ w12b,
        const float* __restrict__ q_w,    unsigned short* __restrict__ qwb,
        const float* __restrict__ v_w,    unsigned short* __restrict__ vwb,
        const float* __restrict__ k_w,    unsigned short* __restrict__ kTb,
        const float* __restrict__ mw, const float* __restrict__ lw,
        const float* __restrict__ mb, const float* __restrict__ lb,
        unsigned short* __restrict__ headwb, float* __restrict__ headbb,
        const float* __restrict__ dec_w,  unsigned short* __restrict__ decwb) {
    __shared__ float tile[32][33];
    int b = blockIdx.x;
    const int tid = threadIdx.x;
    if (b < PREP_C12) { convert8(fc12_w, w12b, b, tid); return; }
    b -= PREP_C12;
    if (b < PREP_QW) { convert8(q_w, qwb, b, tid); return; }
    b -= PREP_QW;
    if (b < PREP_VW) { convert8(v_w, vwb, b, tid); return; }
    b -= PREP_VW;
    if (b < PREP_TR) {
        const int bx = (b % 12) * 32, by = (b / 12) * 32;
        const int tx = tid & 31, ty = tid >> 5;
        #pragma unroll
        for (int i = 0; i < 4; ++i)
            tile[ty + 8 * i][tx] = k_w[(size_t)(by + ty + 8 * i) * ND + bx + tx];
        __syncthreads();
        #pragma unroll
        for (int i = 0; i < 4; ++i)
            kTb[(size_t)(bx + ty + 8 * i) * ND + by + tx] = f2bf(tile[tx][ty + 8 * i]);
        return;
    }
    b -= PREP_TR;
    if (b < PREP_HD) {
        if (b == NHS) {
            if (tid < NHS)
                headbb[tid] = (tid < NT) ? mb[tid]
                            : (tid >= 128 && tid < 128 + NT) ? lb[tid - 128] : 0.f;
            return;
        }
        const float* src = (b < NT) ? (mw + (size_t)b * ND)
                         : (b >= 128 && b < 128 + NT) ? (lw + (size_t)(b - 128) * ND) : nullptr;
        for (int c = tid; c < ND; c += 256)
            headwb[(size_t)b * ND + c] = src ? f2bf(src[c]) : (unsigned short)0;
        return;
    }
    b -= PREP_HD;
    {   // dec_w pad: 2 rows per block
        const int n = b * 2 + (tid >> 7);
        const int k = tid & 127;
        decwb[(size_t)n * NKP + k] =
            (n < NV && k < NT) ? f2bf(dec_w[(size_t)n * NT + k]) : (unsigned short)0;
    }
}

// ---------------------------------------------------------------------------
// MFMA GEMM core params: 128x128 tile, BK=32, 4 waves (2x2), 16x16x32 frags.
// ---------------------------------------------------------------------------
#define BM 128
#define BN 128
#define BK 32

// ---------------------------------------------------------------------------
// fc11: FUSED-CONVERT split-K GEMM, T14-pipelined:
// per iter: issue next-tile f32 loads -> MFMA current LDS tile -> barrier ->
// cvt_pk-convert + ds_write next tile -> barrier. XCD-chunked swizzle.
// bf16 partials out. Requires S%8==0.
// ---------------------------------------------------------------------------
__global__ __launch_bounds__(256) void gemm_f32_splitk(
        const float* __restrict__ A,
        const float* __restrict__ Bw,
        unsigned short* __restrict__ partial,
        int M, int N, int K, int S, int steps_total, int gx, int gy) {
    __shared__ __align__(16) unsigned short Asl[BM * BK];
    __shared__ __align__(16) unsigned short Bsl[BN * BK];
    const int tid = threadIdx.x;
    // swizzled decomposition (XCD = blockIdx.x % 8 round-robin)
    const int l = blockIdx.x >> 3;
    const int xcd = blockIdx.x & 7;
    const int bm = l % gy;
    const int rest = l / gy;
    const int bn = rest % gx;
    const int s_loc = rest / gx;
    const int s = xcd * (S >> 3) + s_loc;

    const int row0 = bm * BM, col0 = bn * BN;
    const int k_begin = (int)(((long)s * steps_total) / S) * BK;
    const int k_end   = (int)(((long)(s + 1) * steps_total) / S) * BK;
    const int nsteps = (k_end - k_begin) / BK;

    const int sr = tid >> 2;          // 0..63
    const int sc = (tid & 3) * 8;     // 0,8,16,24
    const int wave = tid >> 6, lane = tid & 63;
    const int wm = wave >> 1, wn = wave & 1;
    const int lrow = lane & 15, lkb = lane >> 4;

    f32x4 acc[4][4] = {};
    const float* Ab = A + (size_t)row0 * K;
    const float* Bb = Bw + (size_t)col0 * K;

    float4 ra[2][2], rb[2][2];

#define LOADREGS(K0)                                                          \
    {                                                                         \
        _Pragma("unroll")                                                     \
        for (int h = 0; h < 2; ++h) {                                         \
            const float* pa = Ab + (size_t)(h * 64 + sr) * K + (K0) + sc;     \
            const float* pb = Bb + (size_t)(h * 64 + sr) * K + (K0) + sc;     \
            ra[h][0] = *reinterpret_cast<const float4*>(pa);                  \
            ra[h][1] = *reinterpret_cast<const float4*>(pa + 4);              \
            rb[h][0] = *reinterpret_cast<const float4*>(pb);                  \
            rb[h][1] = *reinterpret_cast<const float4*>(pb + 4);              \
        }                                                                     \
    }

#define WRITELDS()                                                            \
    {                                                                         \
        _Pragma("unroll")                                                     \
        for (int h = 0; h < 2; ++h) {                                         \
            *reinterpret_cast<uint4*>(&Asl[(h * 64 + sr) * BK + sc]) =        \
                pack_bf8(ra[h][0], ra[h][1]);                                 \
            *reinterpret_cast<uint4*>(&Bsl[(h * 64 + sr) * BK + sc]) =        \
                pack_bf8(rb[h][0], rb[h][1]);                                 \
        }                                                                     \
    }

    // prologue: stage tile 0
    LOADREGS(k_begin);
    WRITELDS();
    __syncthreads();

    for (int t = 0; t < nsteps; ++t) {
        const bool has_next = (t + 1) < nsteps;
        if (has_next) LOADREGS(k_begin + (t + 1) * BK);   // async, hidden by MFMA

        bf16x8 af[4], bfr[4];
        #pragma unroll
        for (int i = 0; i < 4; ++i) {
            af[i]  = *reinterpret_cast<const bf16x8*>(&Asl[(wm * 64 + i * 16 + lrow) * BK + lkb * 8]);
            bfr[i] = *reinterpret_cast<const bf16x8*>(&Bsl[(wn * 64 + i * 16 + lrow) * BK + lkb * 8]);
        }
        #pragma unroll
        for (int i = 0; i < 4; ++i)
            #pragma unroll
            for (int j = 0; j < 4; ++j)
                acc[i][j] = __builtin_amdgcn_mfma_f32_16x16x32_bf16(af[i], bfr[j], acc[i][j], 0, 0, 0);

        __syncthreads();                  // all waves done reading tile t
        if (has_next) WRITELDS();         // vmcnt wait + convert + write t+1
        __syncthreads();                  // tile t+1 visible
    }
#undef LOADREGS
#undef WRITELDS

    unsigned short* P = partial + (size_t)s * M * N;
    #pragma unroll
    for (int i = 0; i < 4; ++i) {
        const int rbase = row0 + wm * 64 + i * 16 + lkb * 4;
        #pragma unroll
        for (int j = 0; j < 4; ++j) {
            const int col = col0 + wn * 64 + j * 16 + lrow;
            #pragma unroll
            for (int r = 0; r < 4; ++r)
                P[(size_t)(rbase + r) * N + col] = f2bf(acc[i][j][r]);
        }
    }
}

// ---------------------------------------------------------------------------
// bf16-input split-K GEMM (fc12): global_load_lds staging, bf16 partials.
// ---------------------------------------------------------------------------
__global__ __launch_bounds__(256) void gemm_mfma_splitk(
        const unsigned short* __restrict__ A,
        const unsigned short* __restrict__ Bw,
        unsigned short* __restrict__ partial,
        int M, int N, int K, int S, int steps_total) {
    __shared__ __align__(16) unsigned short Asl[BM * BK];
    __shared__ __align__(16) unsigned short Bsl[BN * BK];
    const int tid = threadIdx.x;
    const int bn = blockIdx.x, bm = blockIdx.y, s = blockIdx.z;
    const int row0 = bm * BM, col0 = bn * BN;
    const int k_begin = (int)(((long)s * steps_total) / S) * BK;
    const int k_end   = (int)(((long)(s + 1) * steps_total) / S) * BK;

    const int srow = tid >> 2;
    const int scol = (tid & 3) * 8;
    const int wave = tid >> 6, lane = tid & 63;
    const int wm = wave >> 1, wn = wave & 1;
    const int lrow = lane & 15, lkb = lane >> 4;

    f32x4 acc[4][4] = {};
    const unsigned short* Ab = A + (size_t)row0 * K;
    const unsigned short* Bb = Bw + (size_t)col0 * K;

    for (int k0 = k_begin; k0 < k_end; k0 += BK) {
        #pragma unroll
        for (int i = 0; i < 2; ++i) {
            const int r = i * 64 + srow;
            __builtin_amdgcn_global_load_lds(
                (const __attribute__((address_space(1))) void*)(Ab + (size_t)r * K + k0 + scol),
                (__attribute__((address_space(3))) void*)(&Asl[(i * 256 + tid) * 8]),
                16, 0, 0);
            __builtin_amdgcn_global_load_lds(
                (const __attribute__((address_space(1))) void*)(Bb + (size_t)r * K + k0 + scol),
                (__attribute__((address_space(3))) void*)(&Bsl[(i * 256 + tid) * 8]),
                16, 0, 0);
        }
        __syncthreads();
        bf16x8 af[4], bfr[4];
        #pragma unroll
        for (int i = 0; i < 4; ++i) {
            af[i]  = *reinterpret_cast<const bf16x8*>(&Asl[(wm * 64 + i * 16 + lrow) * BK + lkb * 8]);
            bfr[i] = *reinterpret_cast<const bf16x8*>(&Bsl[(wn * 64 + i * 16 + lrow) * BK + lkb * 8]);
        }
        #pragma unroll
        for (int i = 0; i < 4; ++i)
            #pragma unroll
            for (int j = 0; j < 4; ++j)
                acc[i][j] = __builtin_amdgcn_mfma_f32_16x16x32_bf16(af[i], bfr[j], acc[i][j], 0, 0, 0);
        __syncthreads();
    }

    unsigned short* P = partial + (size_t)s * M * N;
    #pragma unroll
    for (int i = 0; i < 4; ++i) {
        const int rbase = row0 + wm * 64 + i * 16 + lkb * 4;
        #pragma unroll
        for (int j = 0; j < 4; ++j) {
            const int col = col0 + wn * 64 + j * 16 + lrow;
            #pragma unroll
            for (int r = 0; r < 4; ++r)
                P[(size_t)(rbase + r) * N + col] = f2bf(acc[i][j][r]);
        }
    }
}

// ---------------------------------------------------------------------------
// 64x64-tile split-K MFMA (skinny GEMMs); bf16 partials.
// ---------------------------------------------------------------------------
__global__ __launch_bounds__(256) void gemm64_splitk(
        const unsigned short* __restrict__ A,
        const unsigned short* __restrict__ Bw,
        unsigned short* __restrict__ partial,
        int M, int N, int K, int S, int steps_total) {
    __shared__ __align__(16) unsigned short Asl[64 * BK];
    __shared__ __align__(16) unsigned short Bsl[64 * BK];
    const int tid = threadIdx.x;
    const int bn = blockIdx.x, bm = blockIdx.y, s = blockIdx.z;
    const int row0 = bm * 64, col0 = bn * 64;
    const int k_begin = (int)(((long)s * steps_total) / S) * BK;
    const int k_end   = (int)(((long)(s + 1) * steps_total) / S) * BK;

    const int srow = tid >> 2;
    const int scol = (tid & 3) * 8;
    const int wave = tid >> 6, lane = tid & 63;
    const int wm = wave >> 1, wn = wave & 1;
    const int lrow = lane & 15, lkb = lane >> 4;

    f32x4 acc[2][2] = {};
    const unsigned short* Ab = A + (size_t)row0 * K;
    const unsigned short* Bb = Bw + (size_t)col0 * K;

    for (int k0 = k_begin; k0 < k_end; k0 += BK) {
        __builtin_amdgcn_global_load_lds(
            (const __attribute__((address_space(1))) void*)(Ab + (size_t)srow * K + k0 + scol),
            (__attribute__((address_space(3))) void*)(&Asl[tid * 8]),
            16, 0, 0);
        __builtin_amdgcn_global_load_lds(
            (const __attribute__((address_space(1))) void*)(Bb + (size_t)srow * K + k0 + scol),
            (__attribute__((address_space(3))) void*)(&Bsl[tid * 8]),
            16, 0, 0);
        __syncthreads();
        bf16x8 af[2], bfr[2];
        #pragma unroll
        for (int i = 0; i < 2; ++i) {
            af[i]  = *reinterpret_cast<const bf16x8*>(&Asl[(wm * 32 + i * 16 + lrow) * BK + lkb * 8]);
            bfr[i] = *reinterpret_cast<const bf16x8*>(&Bsl[(wn * 32 + i * 16 + lrow) * BK + lkb * 8]);
        }
        #pragma unroll
        for (int i = 0; i < 2; ++i)
            #pragma unroll
            for (int j = 0; j < 2; ++j)
                acc[i][j] = __builtin_amdgcn_mfma_f32_16x16x32_bf16(af[i], bfr[j], acc[i][j], 0, 0, 0);
        __syncthreads();
    }

    unsigned short* P = partial + (size_t)s * M * N;
    #pragma unroll
    for (int i = 0; i < 2; ++i) {
        const int rbase = row0 + wm * 32 + i * 16 + lkb * 4;
        #pragma unroll
        for (int j = 0; j < 2; ++j) {
            const int col = col0 + wn * 32 + j * 16 + lrow;
            #pragma unroll
            for (int r = 0; r < 4; ++r)
                P[(size_t)(rbase + r) * N + col] = f2bf(acc[i][j][r]);
        }
    }
}

// ---------------------------------------------------------------------------
// Vectorized split-K reduce (bf16 partials): 8 elems/thread.
// ---------------------------------------------------------------------------
template<int OUT_BF16, int ACT, int HASBIAS>
__global__ __launch_bounds__(256) void reduce_splitk_bf(
        const unsigned short* __restrict__ partial,
        const float* __restrict__ bias,
        void* __restrict__ out, int MN, int N, int S) {
    const int i0 = (blockIdx.x * 256 + threadIdx.x) * 8;
    if (i0 >= MN) return;
    float sum[8] = {};
    for (int s = 0; s < S; ++s) {
        union { uint4 v; unsigned short u[8]; } p;
        p.v = *reinterpret_cast<const uint4*>(partial + (size_t)s * MN + i0);
        #pragma unroll
        for (int j = 0; j < 8; ++j) sum[j] += bf2f(p.u[j]);
    }
    if (HASBIAS) {
        const int nb = i0 % N;
        #pragma unroll
        for (int j = 0; j < 8; ++j) sum[j] += bias[nb + j];
    }
    if (ACT) {
        #pragma unroll
        for (int j = 0; j < 8; ++j) sum[j] = softplus_f(sum[j]);
    }
    if (OUT_BF16) {
        union { uint4 v; unsigned short u[8]; } r;
        #pragma unroll
        for (int j = 0; j < 8; ++j) r.u[j] = f2bf(sum[j]);
        *reinterpret_cast<uint4*>((unsigned short*)out + i0) = r.v;
    } else {
        float* o = (float*)out + i0;
        *reinterpret_cast<float4*>(o)     = make_float4(sum[0], sum[1], sum[2], sum[3]);
        *reinterpret_cast<float4*>(o + 4) = make_float4(sum[4], sum[5], sum[6], sum[7]);
    }
}

// Single-pass MFMA GEMM with fused epilogue (decoder): C = A@Bw^T + bias,
// bf16 out + per-(rowblock,wave) column sum/sumsq partials.
template<int OUT_BF16, int ACT, int HASBIAS, int COLSTATS>
__global__ __launch_bounds__(256) void gemm_mfma(
        const unsigned short* __restrict__ A,
        const unsigned short* __restrict__ Bw,
        const float* __restrict__ bias,
        void* __restrict__ Cout,
        float* __restrict__ colp,
        int M, int Nout, int K) {
    __shared__ __align__(16) unsigned short Asl[BM * BK];
    __shared__ __align__(16) unsigned short Bsl[BN * BK];
    const int tid = threadIdx.x;
    const int row0 = blockIdx.y * BM, col0 = blockIdx.x * BN;
    const int srow = tid >> 2;
    const int scol = (tid & 3) * 8;
    const int wave = tid >> 6, lane = tid & 63;
    const int wm = wave >> 1, wn = wave & 1;
    const int lrow = lane & 15, lkb = lane >> 4;

    f32x4 acc[4][4] = {};
    const unsigned short* Ab = A + (size_t)row0 * K;
    const unsigned short* Bb = Bw + (size_t)col0 * K;

    for (int k0 = 0; k0 < K; k0 += BK) {
        #pragma unroll
        for (int i = 0; i < 2; ++i) {
            const int r = i * 64 + srow;
            __builtin_amdgcn_global_load_lds(
                (const __attribute__((address_space(1))) void*)(Ab + (size_t)r * K + k0 + scol),
                (__attribute__((address_space(3))) void*)(&Asl[(i * 256 + tid) * 8]),
                16, 0, 0);
            __builtin_amdgcn_global_load_lds(
                (const __attribute__((address_space(1))) void*)(Bb + (size_t)r * K + k0 + scol),
                (__attribute__((address_space(3))) void*)(&Bsl[(i * 256 + tid) * 8]),
                16, 0, 0);
        }
        __syncthreads();
        bf16x8 af[4], bfr[4];
        #pragma unroll
        for (int i = 0; i < 4; ++i) {
            af[i]  = *reinterpret_cast<const bf16x8*>(&Asl[(wm * 64 + i * 16 + lrow) * BK + lkb * 8]);
            bfr[i] = *reinterpret_cast<const bf16x8*>(&Bsl[(wn * 64 + i * 16 + lrow) * BK + lkb * 8]);
        }
        #pragma unroll
        for (int i = 0; i < 4; ++i)
            #pragma unroll
            for (int j = 0; j < 4; ++j)
                acc[i][j] = __builtin_amdgcn_mfma_f32_16x16x32_bf16(af[i], bfr[j], acc[i][j], 0, 0, 0);
        __syncthreads();
    }

    #pragma unroll
    for (int j = 0; j < 4; ++j) {
        const int col = col0 + wn * 64 + j * 16 + lrow;
        const bool cok = col < Nout;
        const float bv = HASBIAS ? (cok ? bias[col] : 0.f) : 0.f;
        float csum = 0.f, csq = 0.f;
        #pragma unroll
        for (int i = 0; i < 4; ++i) {
            const int rbase = row0 + wm * 64 + i * 16 + lkb * 4;
            #pragma unroll
            for (int r = 0; r < 4; ++r) {
                float v = acc[i][j][r] + bv;
                if (ACT == 1) v = softplus_f(v);
                if (COLSTATS) { csum += v; csq = fmaf(v, v, csq); }
                if (cok) {
                    if (OUT_BF16)
                        ((unsigned short*)Cout)[(size_t)(rbase + r) * Nout + col] = f2bf(v);
                    else
                        ((float*)Cout)[(size_t)(rbase + r) * Nout + col] = v;
                }
            }
        }
        if (COLSTATS) {
            csum += __shfl_xor(csum, 16); csum += __shfl_xor(csum, 32);
            csq  += __shfl_xor(csq, 16);  csq  += __shfl_xor(csq, 32);
            if (lkb == 0) {
                const int w8 = blockIdx.y * 2 + wm;   // 0..7
                colp[(size_t)w8 * NVP + col] = csum;
                colp[(size_t)(8 + w8) * NVP + col] = csq;
            }
        }
    }
}

// ---------------------------------------------------------------------------
// Fused ragged attention + qk split-K reduce; emb staged in LDS as bf16.
// ---------------------------------------------------------------------------
__global__ __launch_bounds__(256) void attn_kernel(const unsigned short* __restrict__ qkp,
                                                   const float* __restrict__ emb,
                                                   const int* __restrict__ lengths,
                                                   unsigned short* __restrict__ cb) {
    const int b = blockIdx.x;
    const int tid = threadIdx.x;
    __shared__ unsigned short es[NM * ND];  // 48 KB
    __shared__ float qs[ND];
    __shared__ float sc[NM];

    const float* ebase = emb + (size_t)b * NM * ND;
    for (int i = tid; i < NM * ND / 8; i += 256) {
        const float4 v0 = *reinterpret_cast<const float4*>(ebase + (size_t)i * 8);
        const float4 v1 = *reinterpret_cast<const float4*>(ebase + (size_t)i * 8 + 4);
        *reinterpret_cast<uint4*>(&es[i * 8]) = pack_bf8(v0, v1);
    }
    for (int d = tid; d < ND; d += 256) {
        float acc = 0.f;
        #pragma unroll
        for (int s = 0; s < 8; ++s)
            acc += bf2f(qkp[((size_t)s * NB + b) * ND + d]);
        qs[d] = acc;
    }
    __syncthreads();

    const int wave = tid >> 6, lane = tid & 63;
    const float scale = 0.05103103630798288f;  // 1/sqrt(384)

    for (int m = wave; m < NM; m += 4) {
        float s = 0.f;
        for (int d = lane; d < ND; d += 64) s = fmaf(bf2f(es[m * ND + d]), qs[d], s);
        #pragma unroll
        for (int off = 32; off; off >>= 1) s += __shfl_xor(s, off);
        if (lane == 0) sc[m] = s * scale;
    }
    __syncthreads();

    const int len = lengths[b];
    if (tid < 64) {
        float s = (tid < len) ? sc[tid] : -INFINITY;
        float mx = s;
        #pragma unroll
        for (int off = 32; off; off >>= 1) mx = fmaxf(mx, __shfl_xor(mx, off));
        float e = (tid < len) ? expf(s - mx) : 0.f;
        float sum = e;
        #pragma unroll
        for (int off = 32; off; off >>= 1) sum += __shfl_xor(sum, off);
        sc[tid] = e / sum;
    }
    __syncthreads();

    for (int d = tid; d < ND; d += 256) {
        float acc = 0.f;
        for (int m = 0; m < len; ++m) acc = fmaf(sc[m], bf2f(es[m * ND + d]), acc);
        cb[(size_t)b * ND + d] = f2bf(acc);
    }
}

// ---------------------------------------------------------------------------
// BatchNorm over batch axis reading stacked heads hl [B,256].
// ---------------------------------------------------------------------------
__global__ __launch_bounds__(256) void bn_batch(const float* __restrict__ hl,
                                                const float* __restrict__ mbnb,
                                                const float* __restrict__ lbnb,
                                                float* __restrict__ mu,
                                                float* __restrict__ lv) {
    const int t = blockIdx.x;
    const int sel = blockIdx.y;
    const int col = sel ? 128 + t : t;
    const float* bnb = sel ? lbnb : mbnb;
    float* dst = sel ? lv : mu;
    const int tid = threadIdx.x;

    float s = 0.f, ss = 0.f;
    for (int b = tid; b < NB; b += 256) {
        const float v = hl[(size_t)b * NHS + col];
        s += v; ss += v * v;
    }
    __shared__ float rs[256], rss[256];
    rs[tid] = s; rss[tid] = ss;
    __syncthreads();
    for (int off = 128; off; off >>= 1) {
        if (tid < off) { rs[tid] += rs[tid + off]; rss[tid] += rss[tid + off]; }
        __syncthreads();
    }
    const float mean = rs[0] / (float)NB;
    const float var = rss[0] / (float)NB - mean * mean;
    const float rstd = rsqrtf(var + EPS);
    const float bb = bnb[t];
    for (int b = tid; b < NB; b += 256) {
        dst[(size_t)b * NT + t] = (hl[(size_t)b * NHS + col] - mean) * rstd + bb;
    }
}

// ---------------------------------------------------------------------------
// Per-row softmax over T -> thetab (bf16, zero-padded to 128) + KL partial.
// ---------------------------------------------------------------------------
__global__ __launch_bounds__(128) void theta_kl(const float* __restrict__ mu,
                                                const float* __restrict__ lv,
                                                unsigned short* __restrict__ thetab,
                                                float* __restrict__ kld_p) {
    const int b = blockIdx.x, tid = threadIdx.x;
    const float var2 = 1.0f - 1.0f / (float)NT;
    const float inv_var2 = 1.0f / var2;
    __shared__ float red[128];

    const float m = (tid < NT) ? mu[(size_t)b * NT + tid] : -INFINITY;
    red[tid] = m;
    __syncthreads();
    for (int off = 64; off; off >>= 1) {
        if (tid < off) red[tid] = fmaxf(red[tid], red[tid + off]);
        __syncthreads();
    }
    const float mx = red[0];
    __syncthreads();

    const float e = (tid < NT) ? expf(m - mx) : 0.f;
    red[tid] = e;
    __syncthreads();
    for (int off = 64; off; off >>= 1) {
        if (tid < off) red[tid] += red[tid + off];
        __syncthreads();
    }
    const float sum = red[0];
    __syncthreads();
    thetab[(size_t)b * NKP + tid] = (tid < NT) ? f2bf(e / sum) : (unsigned short)0;

    float term = 0.f;
    if (tid < NT) {
        const float l = lv[(size_t)b * NT + tid];
        term = expf(l) * inv_var2 + m * m * inv_var2 - l;
    }
    red[tid] = term;
    __syncthreads();
    for (int off = 64; off; off >>= 1) {
        if (tid < off) red[tid] += red[tid + off];
        __syncthreads();
    }
    if (tid == 0)
        kld_p[b] = 0.5f * (red[0] + (float)NT * logf(var2) - (float)NT);
}

// ---------------------------------------------------------------------------
// Combine the 8 per-wave column partials -> cmu, crstd.
// ---------------------------------------------------------------------------
__global__ __launch_bounds__(256) void stats_final(const float* __restrict__ colp,
                                                   float* __restrict__ cmu,
                                                   float* __restrict__ crstd) {
    const int v = blockIdx.x * 256 + threadIdx.x;
    if (v >= NV) return;
    float s = 0.f, q = 0.f;
    #pragma unroll
    for (int w = 0; w < 8; ++w) {
        s += colp[(size_t)w * NVP + v];
        q += colp[(size_t)(8 + w) * NVP + v];
    }
    const float mean = s / (float)NB;
    cmu[v] = mean;
    crstd[v] = rsqrtf(q / (float)NB - mean * mean + EPS);
}

// ---------------------------------------------------------------------------
// SINGLE pass over bf16 logit + f32 x:
// online LSE of z; xz = sum x*z; xs = sum x; recon_p = xz - lse*xs.
// ---------------------------------------------------------------------------
__global__ __launch_bounds__(256) void row_recon(const unsigned short* __restrict__ logitb,
                                                 const float* __restrict__ x,
                                                 const float* __restrict__ cmu,
                                                 const float* __restrict__ crstd,
                                                 const float* __restrict__ dbnb,
                                                 float* __restrict__ recon_p) {
    const int b = blockIdx.x, tid = threadIdx.x;
    const unsigned short* lr = logitb + (size_t)b * NV;
    const float* xr = x + (size_t)b * NV;

    float m_i = -INFINITY, s_i = 0.f, xz = 0.f, xs = 0.f;
    for (int v = tid * 8; v < NV; v += 2048) {
        union { uint4 v4; unsigned short u[8]; } lw;
        lw.v4 = *reinterpret_cast<const uint4*>(lr + v);
        const float4 x0 = *reinterpret_cast<const float4*>(xr + v);
        const float4 x1 = *reinterpret_cast<const float4*>(xr + v + 4);
        const float4 c0 = *reinterpret_cast<const float4*>(cmu + v);
        const float4 c1 = *reinterpret_cast<const float4*>(cmu + v + 4);
        const float4 r0 = *reinterpret_cast<const float4*>(crstd + v);
        const float4 r1 = *reinterpret_cast<const float4*>(crstd + v + 4);
        const float4 d0 = *reinterpret_cast<const float4*>(dbnb + v);
        const float4 d1 = *reinterpret_cast<const float4*>(dbnb + v + 4);
        const float xv[8] = {x0.x,x0.y,x0.z,x0.w,x1.x,x1.y,x1.z,x1.w};
        const float cm[8] = {c0.x,c0.y,c0.z,c0.w,c1.x,c1.y,c1.z,c1.w};
        const float cr[8] = {r0.x,r0.y,r0.z,r0.w,r1.x,r1.y,r1.z,r1.w};
        const float db[8] = {d0.x,d0.y,d0.z,d0.w,d1.x,d1.y,d1.z,d1.w};
        float z[8];
        #pragma unroll
        for (int j = 0; j < 8; ++j)
            z[j] = fmaf(bf2f(lw.u[j]) - cm[j], cr[j], db[j]);
        float mx = z[0];
        #pragma unroll
        for (int j = 1; j < 8; ++j) mx = fmaxf(mx, z[j]);
        const float mnew = fmaxf(m_i, mx);
        float e8 = 0.f;
        #pragma unroll
        for (int j = 0; j < 8; ++j) e8 += expf(z[j] - mnew);
        s_i = s_i * expf(m_i - mnew) + e8;
        m_i = mnew;
        #pragma unroll
        for (int j = 0; j < 8; ++j) {
            xz = fmaf(xv[j], z[j], xz);
            xs += xv[j];
        }
    }

    __shared__ float rm[256], rs[256], rxz[256], rxs[256];
    rm[tid] = m_i; rs[tid] = s_i; rxz[tid] = xz; rxs[tid] = xs;
    __syncthreads();
    for (int off = 128; off; off >>= 1) {
        if (tid < off) {
            const float m1 = rm[tid], m2 = rm[tid + off];
            const float s1 = rs[tid], s2 = rs[tid + off];
            const float mm = fmaxf(m1, m2);
            rm[tid] = mm;
            rs[tid] = s1 * expf(m1 - mm) + s2 * expf(m2 - mm);
            rxz[tid] += rxz[tid + off];
            rxs[tid] += rxs[tid + off];
        }
        __syncthreads();
    }
    if (tid == 0) {
        const float lse = rm[0] + logf(rs[0]);
        recon_p[b] = rxz[0] - lse * rxs[0];
    }
}

// ---------------------------------------------------------------------------
// Final: out = -mean(recon_p) + mean(kld_p)
// ---------------------------------------------------------------------------
__global__ __launch_bounds__(512) void finalize(const float* __restrict__ recon_p,
                                                const float* __restrict__ kld_p,
                                                float* __restrict__ out) {
    const int tid = threadIdx.x;
    __shared__ float r1[512], r2[512];
    r1[tid] = recon_p[tid];
    r2[tid] = kld_p[tid];
    __syncthreads();
    for (int off = 256; off; off >>= 1) {
        if (tid < off) { r1[tid] += r1[tid + off]; r2[tid] += r2[tid + off]; }
        __syncthreads();
    }
    if (tid == 0) out[0] = (-r1[0] + r2[0]) / (float)NB;
}

extern "C" void kernel_launch(void* const* d_in, const int* in_sizes, int n_in,
                              void* d_out, int out_size, void* d_ws, size_t ws_size,
                              hipStream_t stream) {
    const float* x       = (const float*)d_in[0];
    const float* emb     = (const float*)d_in[1];
    const int*   lengths = (const int*)d_in[2];
    const float* fc11_w  = (const float*)d_in[3];
    const float* fc11_b  = (const float*)d_in[4];
    const float* fc12_w  = (const float*)d_in[5];
    const float* fc12_b  = (const float*)d_in[6];
    const float* q_w     = (const float*)d_in[7];
    const float* q_b     = (const float*)d_in[8];
    const float* k_w     = (const float*)d_in[9];
    // d_in[10] = k_b: cancels in softmax -> unused
    const float* v_w     = (const float*)d_in[11];
    const float* v_b     = (const float*)d_in[12];
    const float* mean_w  = (const float*)d_in[13];
    const float* mean_b  = (const float*)d_in[14];
    const float* lvw     = (const float*)d_in[15];
    const float* lvb     = (const float*)d_in[16];
    const float* mbnb    = (const float*)d_in[17];
    const float* lbnb    = (const float*)d_in[18];
    const float* dec_w   = (const float*)d_in[19];
    const float* dec_b   = (const float*)d_in[20];
    const float* dbnb    = (const float*)d_in[21];
    float* out = (float*)d_out;

    char* base = (char*)d_ws;
    size_t off = 0;
    auto alloc = [&](size_t bytes) -> void* {
        void* p = base + off;
        off += (bytes + 255) & ~(size_t)255;
        return p;
    };

    unsigned short* logitb = (unsigned short*)alloc((size_t)NB * NV * 2);
    unsigned short* w12b   = (unsigned short*)alloc((size_t)NE * NE * 2);
    unsigned short* e1b    = (unsigned short*)alloc((size_t)NB * NE * 2);
    unsigned short* hb     = (unsigned short*)alloc((size_t)NB * NE * 2);
    unsigned short* qwb    = (unsigned short*)alloc((size_t)ND * NE * 2);
    unsigned short* kTb    = (unsigned short*)alloc((size_t)ND * ND * 2);
    unsigned short* vwb    = (unsigned short*)alloc((size_t)ND * ND * 2);
    unsigned short* qb     = (unsigned short*)alloc((size_t)NB * ND * 2);
    unsigned short* cb     = (unsigned short*)alloc((size_t)NB * ND * 2);
    unsigned short* dib    = (unsigned short*)alloc((size_t)NB * ND * 2);
    unsigned short* headwb = (unsigned short*)alloc((size_t)NHS * ND * 2);
    float*          headbb = (float*)alloc((size_t)NHS * 4);
    float*          hl     = (float*)alloc((size_t)NB * NHS * 4);
    float*          mu     = (float*)alloc((size_t)NB * NT * 4);
    float*          lv     = (float*)alloc((size_t)NB * NT * 4);
    float*          colp   = (float*)alloc((size_t)16 * NVP * 4);
    float*          cmu    = (float*)alloc((size_t)NV * 4);
    float*          crstd  = (float*)alloc((size_t)NV * 4);
    float*          rp     = (float*)alloc((size_t)NB * 4);
    float*          kp     = (float*)alloc((size_t)NB * 4);
    unsigned short* decwb  = (unsigned short*)alloc((size_t)NVP * NKP * 2);
    unsigned short* thetab = (unsigned short*)alloc((size_t)NB * NKP * 2);
    // small-GEMM bf16 split-K partials (max: q S=16 -> 6.3 MB)
    unsigned short* smallp = (unsigned short*)alloc((size_t)16 * NB * ND * 2);
    // big partials LAST; split adapts to remaining workspace (S%8==0 needed)
    const size_t part_bytes_per_s = ((size_t)NB * NE * 2 + 255) & ~(size_t)255;
    const size_t remain = (ws_size > off) ? (ws_size - off) : 0;
    const int S11 = (remain >= 32 * part_bytes_per_s) ? 32
                  : (remain >= 16 * part_bytes_per_s) ? 16 : 8;
    unsigned short* partb = (unsigned short*)alloc((size_t)S11 * NB * NE * 2);

    const dim3 blk(256);

    // ---- one prep kernel: converts + transpose + head stack + dec_w pad ----
    prep_kernel<<<PREP_BLOCKS, blk, 0, stream>>>(
        fc12_w, w12b, q_w, qwb, v_w, vwb, k_w, kTb,
        mean_w, lvw, mean_b, lvb, headwb, headbb, dec_w, decwb);

    // ---- fc11: e1 = softplus(x @ fc11_w^T + b), fused-convert, pipelined ----
    gemm_f32_splitk<<<(NE / BN) * (NB / BM) * S11, blk, 0, stream>>>(
        x, fc11_w, partb, NB, NE, NV, S11, NV / BK, NE / BN, NB / BM);
    reduce_splitk_bf<1, 1, 1><<<(NB * NE) / 2048, blk, 0, stream>>>(
        partb, fc11_b, e1b, NB * NE, NE, S11);

    // ---- fc12: h = softplus(e1 @ fc12_w^T + b) ----
    gemm_mfma_splitk<<<dim3(NE / BN, NB / BM, 8), blk, 0, stream>>>(
        e1b, w12b, partb, NB, NE, NE, 8, NE / BK);
    reduce_splitk_bf<1, 1, 1><<<(NB * NE) / 2048, blk, 0, stream>>>(
        partb, fc12_b, hb, NB * NE, NE, 8);

    // ---- q = h @ q_w^T + q_b (bf16) ----
    gemm64_splitk<<<dim3(ND / 64, NB / 64, 16), blk, 0, stream>>>(
        hb, qwb, smallp, NB, ND, NE, 16, NE / BK);
    reduce_splitk_bf<1, 0, 1><<<(NB * ND) / 2048, blk, 0, stream>>>(
        smallp, q_b, qb, NB * ND, ND, 16);
    // ---- qk = q @ k_w (via kT): partials only; reduce fused into attn ----
    gemm64_splitk<<<dim3(ND / 64, NB / 64, 8), blk, 0, stream>>>(
        qb, kTb, smallp, NB, ND, ND, 8, ND / BK);
    // ---- fused attention (+qk reduce) -> cb = bf16(sum_m alpha*emb) ----
    attn_kernel<<<NB, 256, 0, stream>>>(smallp, emb, lengths, cb);
    // ---- d_i = c @ v_w^T + v_b (bf16) ----
    gemm64_splitk<<<dim3(ND / 64, NB / 64, 8), blk, 0, stream>>>(
        cb, vwb, smallp, NB, ND, ND, 8, ND / BK);
    reduce_splitk_bf<1, 0, 1><<<(NB * ND) / 2048, blk, 0, stream>>>(
        smallp, v_b, dib, NB * ND, ND, 8);
    // ---- stacked heads: hl = d_i @ headw^T + headb (f32 [B,256]) ----
    gemm64_splitk<<<dim3(NHS / 64, NB / 64, 8), blk, 0, stream>>>(
        dib, headwb, smallp, NB, NHS, ND, 8, ND / BK);
    reduce_splitk_bf<0, 0, 1><<<(NB * NHS) / 2048, blk, 0, stream>>>(
        smallp, headbb, hl, NB * NHS, NHS, 8);
    // ---- batchnorm both heads ----
    bn_batch<<<dim3(NT, 2), blk, 0, stream>>>(hl, mbnb, lbnb, mu, lv);
    // ---- theta softmax (bf16 padded) + KL partials ----
    theta_kl<<<NB, 128, 0, stream>>>(mu, lv, thetab, kp);
    // ---- decoder logits (bf16) + fused column stats partials ----
    gemm_mfma<1, 0, 1, 1><<<dim3(NVP / BN, NB / BM), blk, 0, stream>>>(
        thetab, decwb, dec_b, logitb, colp, NB, NV, NKP);
    stats_final<<<(NV + 255) / 256, blk, 0, stream>>>(colp, cmu, crstd);
    // ---- single-pass log-softmax dot x (f32 x) ----
    row_recon<<<NB, 256, 0, stream>>>(logitb, x, cmu, crstd, dbnb, rp);
    // ---- final scalar ----
    finalize<<<1, 512, 0, stream>>>(rp, kp, out);
}

// Round 8
// 167.463 us; speedup vs baseline: 13.6064x; 1.0824x over previous
//
#include <hip/hip_runtime.h>
#include <cstddef>

// Shapes (fixed)
#define NB 512     // batch B
#define NM 64      // M sentences
#define NV 20000   // vocab V
#define NE 1024    // E
#define ND 384     // D
#define NT 100     // T topics
#define EPS 1e-5f

#define NVP 20096  // NV padded to 157*128
#define NKP 128    // decoder K padded (100 -> 128)
#define NHS 256    // stacked heads rows (100 mean | pad | 100 logvar | pad)

typedef __bf16 bf16x8 __attribute__((ext_vector_type(8)));
typedef float f32x4 __attribute__((ext_vector_type(4)));

__device__ __forceinline__ float softplus_f(float x) {
    return fmaxf(x, 0.f) + log1pf(expf(-fabsf(x)));
}

__device__ __forceinline__ unsigned short f2bf(float f) {
    unsigned u = __builtin_bit_cast(unsigned, f);
    unsigned r = u + 0x7FFFu + ((u >> 16) & 1u);   // RNE
    return (unsigned short)(r >> 16);
}

__device__ __forceinline__ float bf2f(unsigned short u) {
    return __builtin_bit_cast(float, (unsigned)u << 16);
}

// Native-cast pack: compiler emits v_cvt_pk_bf16_f32 (RNE).
__device__ __forceinline__ uint4 pack_bf8(float4 a, float4 b) {
    bf16x8 v;
    v[0] = (__bf16)a.x; v[1] = (__bf16)a.y; v[2] = (__bf16)a.z; v[3] = (__bf16)a.w;
    v[4] = (__bf16)b.x; v[5] = (__bf16)b.y; v[6] = (__bf16)b.z; v[7] = (__bf16)b.w;
    return __builtin_bit_cast(uint4, v);
}

__device__ __forceinline__ void convert8(const float* __restrict__ s,
                                         unsigned short* __restrict__ d,
                                         int b, int tid) {
    const size_t i = ((size_t)b * 256 + tid) * 8;
    const float4 a = *reinterpret_cast<const float4*>(s + i);
    const float4 c = *reinterpret_cast<const float4*>(s + i + 4);
    *reinterpret_cast<uint4*>(d + i) = pack_bf8(a, c);
}

// ---------------------------------------------------------------------------
// ONE prep kernel: fc12/q/v converts + k_w transpose + head stack + dec_w pad.
// ---------------------------------------------------------------------------
#define PREP_C12 512                   // NE*NE/2048
#define PREP_QW  192                   // ND*NE/2048
#define PREP_VW  72                    // ND*ND/2048
#define PREP_TR  144                   // 12x12 transpose tiles
#define PREP_HD  257                   // head stack rows + bias
#define PREP_DW  (NVP / 2)             // dec_w pad, 2 rows/block
#define PREP_BLOCKS (PREP_C12 + PREP_QW + PREP_VW + PREP_TR + PREP_HD + PREP_DW)

__global__ __launch_bounds__(256) void prep_kernel(
        const float* __restrict__ fc12_w, unsigned short* __restrict__ w12b,
        const float* __restrict__ q_w,    unsigned short* __restrict__ qwb,
        const float* __restrict__ v_w,    unsigned short* __restrict__ vwb,
        const float* __restrict__ k_w,    unsigned short* __restrict__ kTb,
        const float* __restrict__ mw, const float* __restrict__ lw,
        const float* __restrict__ mb, const float* __restrict__ lb,
        unsigned short* __restrict__ headwb, float* __restrict__ headbb,
        const float* __restrict__ dec_w,  unsigned short* __restrict__ decwb) {
    __shared__ float tile[32][33];
    int b = blockIdx.x;
    const int tid = threadIdx.x;
    if (b < PREP_C12) { convert8(fc12_w, w12b, b, tid); return; }
    b -= PREP_C12;
    if (b < PREP_QW) { convert8(q_w, qwb, b, tid); return; }
    b -= PREP_QW;
    if (b < PREP_VW) { convert8(v_w, vwb, b, tid); return; }
    b -= PREP_VW;
    if (b < PREP_TR) {
        const int bx = (b % 12) * 32, by = (b / 12) * 32;
        const int tx = tid & 31, ty = tid >> 5;
        #pragma unroll
        for (int i = 0; i < 4; ++i)
            tile[ty + 8 * i][tx] = k_w[(size_t)(by + ty + 8 * i) * ND + bx + tx];
        __syncthreads();
        #pragma unroll
        for (int i = 0; i < 4; ++i)
            kTb[(size_t)(bx + ty + 8 * i) * ND + by + tx] = f2bf(tile[tx][ty + 8 * i]);
        return;
    }
    b -= PREP_TR;
    if (b < PREP_HD) {
        if (b == NHS) {
            if (tid < NHS)
                headbb[tid] = (tid < NT) ? mb[tid]
                            : (tid >= 128 && tid < 128 + NT) ? lb[tid - 128] : 0.f;
            return;
        }
        const float* src = (b < NT) ? (mw + (size_t)b * ND)
                         : (b >= 128 && b < 128 + NT) ? (lw + (size_t)(b - 128) * ND) : nullptr;
        for (int c = tid; c < ND; c += 256)
            headwb[(size_t)b * ND + c] = src ? f2bf(src[c]) : (unsigned short)0;
        return;
    }
    b -= PREP_HD;
    {   // dec_w pad: 2 rows per block
        const int n = b * 2 + (tid >> 7);
        const int k = tid & 127;
        decwb[(size_t)n * NKP + k] =
            (n < NV && k < NT) ? f2bf(dec_w[(size_t)n * NT + k]) : (unsigned short)0;
    }
}

// ---------------------------------------------------------------------------
// MFMA GEMM core params.
// ---------------------------------------------------------------------------
#define BM 128
#define BN 128
#define BK 32

// Swizzled LDS offset (bf16 units) for [row][BK] tiles accessed in 16B slots:
// slot ^= (row>>1)&3 spreads the 16-row frag read across all banks (2-way, free).
__device__ __forceinline__ int lds_off(int row, int slot) {
    return row * BK + ((slot ^ ((row >> 1) & 3)) << 3);
}

// ---------------------------------------------------------------------------
// fc11: FUSED-CONVERT split-K GEMM, 256x256 tile, 512 thr (8 waves 2x4),
// T14-pipelined, XOR-swizzled LDS, XCD-chunked so all 8 (bm,bn) tiles of the
// same K-chunk s share one XCD's L2 (x-chunk 1.3MB + w-chunk 2.6MB < 4MB L2).
// Grid = 8*S (1D). Requires S%8==0. bf16 partials out.
// ---------------------------------------------------------------------------
__global__ __launch_bounds__(512, 2) void gemm_f32_256(
        const float* __restrict__ A,
        const float* __restrict__ Bw,
        unsigned short* __restrict__ partial,
        int M, int N, int K, int S, int steps_total) {
    __shared__ __align__(16) unsigned short Asl[256 * BK];  // 16 KB
    __shared__ __align__(16) unsigned short Bsl[256 * BK];  // 16 KB
    const int tid = threadIdx.x;
    const int xcd = blockIdx.x & 7;
    const int l = blockIdx.x >> 3;         // 0..S-1
    const int tile = l & 7;
    const int s = xcd + 8 * (l >> 3);      // all 8 tiles of s on one XCD
    const int bm = tile & 1, bn = tile >> 1;
    const int row0 = bm * 256, col0 = bn * 256;
    const int k_begin = (int)(((long)s * steps_total) / S) * BK;
    const int k_end   = (int)(((long)(s + 1) * steps_total) / S) * BK;
    const int nsteps = (k_end - k_begin) / BK;

    const int sr = tid >> 1;               // 0..255 (staged row)
    const int sc = (tid & 1) * 16;         // f32 col base: 0 or 16
    const int sslot = (tid & 1) * 2;       // 16B slot base: 0 or 2
    const int wave = tid >> 6, lane = tid & 63;
    const int wm = wave >> 2, wn = wave & 3;   // 2x4 wave grid
    const int lrow = lane & 15, lkb = lane >> 4;

    f32x4 acc[8][4] = {};
    const float* Ab = A + (size_t)row0 * K;
    const float* Bb = Bw + (size_t)col0 * K;

    float4 ra[4], rb[4];

#define LOADREGS(K0)                                                          \
    {                                                                         \
        const float* pa = Ab + (size_t)sr * K + (K0) + sc;                    \
        const float* pb = Bb + (size_t)sr * K + (K0) + sc;                    \
        ra[0] = *reinterpret_cast<const float4*>(pa);                         \
        ra[1] = *reinterpret_cast<const float4*>(pa + 4);                     \
        ra[2] = *reinterpret_cast<const float4*>(pa + 8);                     \
        ra[3] = *reinterpret_cast<const float4*>(pa + 12);                    \
        rb[0] = *reinterpret_cast<const float4*>(pb);                         \
        rb[1] = *reinterpret_cast<const float4*>(pb + 4);                     \
        rb[2] = *reinterpret_cast<const float4*>(pb + 8);                     \
        rb[3] = *reinterpret_cast<const float4*>(pb + 12);                    \
    }

#define WRITELDS()                                                            \
    {                                                                         \
        *reinterpret_cast<uint4*>(&Asl[lds_off(sr, sslot)])     = pack_bf8(ra[0], ra[1]); \
        *reinterpret_cast<uint4*>(&Asl[lds_off(sr, sslot + 1)]) = pack_bf8(ra[2], ra[3]); \
        *reinterpret_cast<uint4*>(&Bsl[lds_off(sr, sslot)])     = pack_bf8(rb[0], rb[1]); \
        *reinterpret_cast<uint4*>(&Bsl[lds_off(sr, sslot + 1)]) = pack_bf8(rb[2], rb[3]); \
    }

    // prologue: stage tile 0
    LOADREGS(k_begin);
    WRITELDS();
    __syncthreads();

    for (int t = 0; t < nsteps; ++t) {
        const bool has_next = (t + 1) < nsteps;
        if (has_next) LOADREGS(k_begin + (t + 1) * BK);   // hidden under MFMA

        bf16x8 af[8], bfr[4];
        #pragma unroll
        for (int i = 0; i < 8; ++i)
            af[i] = *reinterpret_cast<const bf16x8*>(&Asl[lds_off(wm * 128 + i * 16 + lrow, lkb)]);
        #pragma unroll
        for (int j = 0; j < 4; ++j)
            bfr[j] = *reinterpret_cast<const bf16x8*>(&Bsl[lds_off(wn * 64 + j * 16 + lrow, lkb)]);
        #pragma unroll
        for (int i = 0; i < 8; ++i)
            #pragma unroll
            for (int j = 0; j < 4; ++j)
                acc[i][j] = __builtin_amdgcn_mfma_f32_16x16x32_bf16(af[i], bfr[j], acc[i][j], 0, 0, 0);

        __syncthreads();                  // all waves done reading tile t
        if (has_next) WRITELDS();         // vmcnt wait + convert + write t+1
        __syncthreads();
    }
#undef LOADREGS
#undef WRITELDS

    unsigned short* P = partial + (size_t)s * M * N;
    #pragma unroll
    for (int i = 0; i < 8; ++i) {
        const int rbase = row0 + wm * 128 + i * 16 + lkb * 4;
        #pragma unroll
        for (int j = 0; j < 4; ++j) {
            const int col = col0 + wn * 64 + j * 16 + lrow;
            #pragma unroll
            for (int r = 0; r < 4; ++r)
                P[(size_t)(rbase + r) * N + col] = f2bf(acc[i][j][r]);
        }
    }
}

// ---------------------------------------------------------------------------
// bf16-input split-K GEMM (fc12): global_load_lds staging, bf16 partials.
// ---------------------------------------------------------------------------
__global__ __launch_bounds__(256) void gemm_mfma_splitk(
        const unsigned short* __restrict__ A,
        const unsigned short* __restrict__ Bw,
        unsigned short* __restrict__ partial,
        int M, int N, int K, int S, int steps_total) {
    __shared__ __align__(16) unsigned short Asl[BM * BK];
    __shared__ __align__(16) unsigned short Bsl[BN * BK];
    const int tid = threadIdx.x;
    const int bn = blockIdx.x, bm = blockIdx.y, s = blockIdx.z;
    const int row0 = bm * BM, col0 = bn * BN;
    const int k_begin = (int)(((long)s * steps_total) / S) * BK;
    const int k_end   = (int)(((long)(s + 1) * steps_total) / S) * BK;

    const int srow = tid >> 2;
    const int scol = (tid & 3) * 8;
    const int wave = tid >> 6, lane = tid & 63;
    const int wm = wave >> 1, wn = wave & 1;
    const int lrow = lane & 15, lkb = lane >> 4;

    f32x4 acc[4][4] = {};
    const unsigned short* Ab = A + (size_t)row0 * K;
    const unsigned short* Bb = Bw + (size_t)col0 * K;

    for (int k0 = k_begin; k0 < k_end; k0 += BK) {
        #pragma unroll
        for (int i = 0; i < 2; ++i) {
            const int r = i * 64 + srow;
            __builtin_amdgcn_global_load_lds(
                (const __attribute__((address_space(1))) void*)(Ab + (size_t)r * K + k0 + scol),
                (__attribute__((address_space(3))) void*)(&Asl[(i * 256 + tid) * 8]),
                16, 0, 0);
            __builtin_amdgcn_global_load_lds(
                (const __attribute__((address_space(1))) void*)(Bb + (size_t)r * K + k0 + scol),
                (__attribute__((address_space(3))) void*)(&Bsl[(i * 256 + tid) * 8]),
                16, 0, 0);
        }
        __syncthreads();
        bf16x8 af[4], bfr[4];
        #pragma unroll
        for (int i = 0; i < 4; ++i) {
            af[i]  = *reinterpret_cast<const bf16x8*>(&Asl[(wm * 64 + i * 16 + lrow) * BK + lkb * 8]);
            bfr[i] = *reinterpret_cast<const bf16x8*>(&Bsl[(wn * 64 + i * 16 + lrow) * BK + lkb * 8]);
        }
        #pragma unroll
        for (int i = 0; i < 4; ++i)
            #pragma unroll
            for (int j = 0; j < 4; ++j)
                acc[i][j] = __builtin_amdgcn_mfma_f32_16x16x32_bf16(af[i], bfr[j], acc[i][j], 0, 0, 0);
        __syncthreads();
    }

    unsigned short* P = partial + (size_t)s * M * N;
    #pragma unroll
    for (int i = 0; i < 4; ++i) {
        const int rbase = row0 + wm * 64 + i * 16 + lkb * 4;
        #pragma unroll
        for (int j = 0; j < 4; ++j) {
            const int col = col0 + wn * 64 + j * 16 + lrow;
            #pragma unroll
            for (int r = 0; r < 4; ++r)
                P[(size_t)(rbase + r) * N + col] = f2bf(acc[i][j][r]);
        }
    }
}

// ---------------------------------------------------------------------------
// 64x64-tile split-K MFMA (skinny GEMMs); bf16 partials.
// ---------------------------------------------------------------------------
__global__ __launch_bounds__(256) void gemm64_splitk(
        const unsigned short* __restrict__ A,
        const unsigned short* __restrict__ Bw,
        unsigned short* __restrict__ partial,
        int M, int N, int K, int S, int steps_total) {
    __shared__ __align__(16) unsigned short Asl[64 * BK];
    __shared__ __align__(16) unsigned short Bsl[64 * BK];
    const int tid = threadIdx.x;
    const int bn = blockIdx.x, bm = blockIdx.y, s = blockIdx.z;
    const int row0 = bm * 64, col0 = bn * 64;
    const int k_begin = (int)(((long)s * steps_total) / S) * BK;
    const int k_end   = (int)(((long)(s + 1) * steps_total) / S) * BK;

    const int srow = tid >> 2;
    const int scol = (tid & 3) * 8;
    const int wave = tid >> 6, lane = tid & 63;
    const int wm = wave >> 1, wn = wave & 1;
    const int lrow = lane & 15, lkb = lane >> 4;

    f32x4 acc[2][2] = {};
    const unsigned short* Ab = A + (size_t)row0 * K;
    const unsigned short* Bb = Bw + (size_t)col0 * K;

    for (int k0 = k_begin; k0 < k_end; k0 += BK) {
        __builtin_amdgcn_global_load_lds(
            (const __attribute__((address_space(1))) void*)(Ab + (size_t)srow * K + k0 + scol),
            (__attribute__((address_space(3))) void*)(&Asl[tid * 8]),
            16, 0, 0);
        __builtin_amdgcn_global_load_lds(
            (const __attribute__((address_space(1))) void*)(Bb + (size_t)srow * K + k0 + scol),
            (__attribute__((address_space(3))) void*)(&Bsl[tid * 8]),
            16, 0, 0);
        __syncthreads();
        bf16x8 af[2], bfr[2];
        #pragma unroll
        for (int i = 0; i < 2; ++i) {
            af[i]  = *reinterpret_cast<const bf16x8*>(&Asl[(wm * 32 + i * 16 + lrow) * BK + lkb * 8]);
            bfr[i] = *reinterpret_cast<const bf16x8*>(&Bsl[(wn * 32 + i * 16 + lrow) * BK + lkb * 8]);
        }
        #pragma unroll
        for (int i = 0; i < 2; ++i)
            #pragma unroll
            for (int j = 0; j < 2; ++j)
                acc[i][j] = __builtin_amdgcn_mfma_f32_16x16x32_bf16(af[i], bfr[j], acc[i][j], 0, 0, 0);
        __syncthreads();
    }

    unsigned short* P = partial + (size_t)s * M * N;
    #pragma unroll
    for (int i = 0; i < 2; ++i) {
        const int rbase = row0 + wm * 32 + i * 16 + lkb * 4;
        #pragma unroll
        for (int j = 0; j < 2; ++j) {
            const int col = col0 + wn * 32 + j * 16 + lrow;
            #pragma unroll
            for (int r = 0; r < 4; ++r)
                P[(size_t)(rbase + r) * N + col] = f2bf(acc[i][j][r]);
        }
    }
}

// ---------------------------------------------------------------------------
// Vectorized split-K reduce (bf16 partials): 8 elems/thread.
// ---------------------------------------------------------------------------
template<int OUT_BF16, int ACT, int HASBIAS>
__global__ __launch_bounds__(256) void reduce_splitk_bf(
        const unsigned short* __restrict__ partial,
        const float* __restrict__ bias,
        void* __restrict__ out, int MN, int N, int S) {
    const int i0 = (blockIdx.x * 256 + threadIdx.x) * 8;
    if (i0 >= MN) return;
    float sum[8] = {};
    for (int s = 0; s < S; ++s) {
        union { uint4 v; unsigned short u[8]; } p;
        p.v = *reinterpret_cast<const uint4*>(partial + (size_t)s * MN + i0);
        #pragma unroll
        for (int j = 0; j < 8; ++j) sum[j] += bf2f(p.u[j]);
    }
    if (HASBIAS) {
        const int nb = i0 % N;
        #pragma unroll
        for (int j = 0; j < 8; ++j) sum[j] += bias[nb + j];
    }
    if (ACT) {
        #pragma unroll
        for (int j = 0; j < 8; ++j) sum[j] = softplus_f(sum[j]);
    }
    if (OUT_BF16) {
        union { uint4 v; unsigned short u[8]; } r;
        #pragma unroll
        for (int j = 0; j < 8; ++j) r.u[j] = f2bf(sum[j]);
        *reinterpret_cast<uint4*>((unsigned short*)out + i0) = r.v;
    } else {
        float* o = (float*)out + i0;
        *reinterpret_cast<float4*>(o)     = make_float4(sum[0], sum[1], sum[2], sum[3]);
        *reinterpret_cast<float4*>(o + 4) = make_float4(sum[4], sum[5], sum[6], sum[7]);
    }
}

// Single-pass MFMA GEMM with fused epilogue (decoder): C = A@Bw^T + bias,
// bf16 out + per-(rowblock,wave) column sum/sumsq partials.
template<int OUT_BF16, int ACT, int HASBIAS, int COLSTATS>
__global__ __launch_bounds__(256) void gemm_mfma(
        const unsigned short* __restrict__ A,
        const unsigned short* __restrict__ Bw,
        const float* __restrict__ bias,
        void* __restrict__ Cout,
        float* __restrict__ colp,
        int M, int Nout, int K) {
    __shared__ __align__(16) unsigned short Asl[BM * BK];
    __shared__ __align__(16) unsigned short Bsl[BN * BK];
    const int tid = threadIdx.x;
    const int row0 = blockIdx.y * BM, col0 = blockIdx.x * BN;
    const int srow = tid >> 2;
    const int scol = (tid & 3) * 8;
    const int wave = tid >> 6, lane = tid & 63;
    const int wm = wave >> 1, wn = wave & 1;
    const int lrow = lane & 15, lkb = lane >> 4;

    f32x4 acc[4][4] = {};
    const unsigned short* Ab = A + (size_t)row0 * K;
    const unsigned short* Bb = Bw + (size_t)col0 * K;

    for (int k0 = 0; k0 < K; k0 += BK) {
        #pragma unroll
        for (int i = 0; i < 2; ++i) {
            const int r = i * 64 + srow;
            __builtin_amdgcn_global_load_lds(
                (const __attribute__((address_space(1))) void*)(Ab + (size_t)r * K + k0 + scol),
                (__attribute__((address_space(3))) void*)(&Asl[(i * 256 + tid) * 8]),
                16, 0, 0);
            __builtin_amdgcn_global_load_lds(
                (const __attribute__((address_space(1))) void*)(Bb + (size_t)r * K + k0 + scol),
                (__attribute__((address_space(3))) void*)(&Bsl[(i * 256 + tid) * 8]),
                16, 0, 0);
        }
        __syncthreads();
        bf16x8 af[4], bfr[4];
        #pragma unroll
        for (int i = 0; i < 4; ++i) {
            af[i]  = *reinterpret_cast<const bf16x8*>(&Asl[(wm * 64 + i * 16 + lrow) * BK + lkb * 8]);
            bfr[i] = *reinterpret_cast<const bf16x8*>(&Bsl[(wn * 64 + i * 16 + lrow) * BK + lkb * 8]);
        }
        #pragma unroll
        for (int i = 0; i < 4; ++i)
            #pragma unroll
            for (int j = 0; j < 4; ++j)
                acc[i][j] = __builtin_amdgcn_mfma_f32_16x16x32_bf16(af[i], bfr[j], acc[i][j], 0, 0, 0);
        __syncthreads();
    }

    #pragma unroll
    for (int j = 0; j < 4; ++j) {
        const int col = col0 + wn * 64 + j * 16 + lrow;
        const bool cok = col < Nout;
        const float bv = HASBIAS ? (cok ? bias[col] : 0.f) : 0.f;
        float csum = 0.f, csq = 0.f;
        #pragma unroll
        for (int i = 0; i < 4; ++i) {
            const int rbase = row0 + wm * 64 + i * 16 + lkb * 4;
            #pragma unroll
            for (int r = 0; r < 4; ++r) {
                float v = acc[i][j][r] + bv;
                if (ACT == 1) v = softplus_f(v);
                if (COLSTATS) { csum += v; csq = fmaf(v, v, csq); }
                if (cok) {
                    if (OUT_BF16)
                        ((unsigned short*)Cout)[(size_t)(rbase + r) * Nout + col] = f2bf(v);
                    else
                        ((float*)Cout)[(size_t)(rbase + r) * Nout + col] = v;
                }
            }
        }
        if (COLSTATS) {
            csum += __shfl_xor(csum, 16); csum += __shfl_xor(csum, 32);
            csq  += __shfl_xor(csq, 16);  csq  += __shfl_xor(csq, 32);
            if (lkb == 0) {
                const int w8 = blockIdx.y * 2 + wm;   // 0..7
                colp[(size_t)w8 * NVP + col] = csum;
                colp[(size_t)(8 + w8) * NVP + col] = csq;
            }
        }
    }
}

// ---------------------------------------------------------------------------
// Fused ragged attention + qk split-K reduce; emb staged in LDS as bf16.
// ---------------------------------------------------------------------------
__global__ __launch_bounds__(256) void attn_kernel(const unsigned short* __restrict__ qkp,
                                                   const float* __restrict__ emb,
                                                   const int* __restrict__ lengths,
                                                   unsigned short* __restrict__ cb) {
    const int b = blockIdx.x;
    const int tid = threadIdx.x;
    __shared__ unsigned short es[NM * ND];  // 48 KB
    __shared__ float qs[ND];
    __shared__ float sc[NM];

    const float* ebase = emb + (size_t)b * NM * ND;
    for (int i = tid; i < NM * ND / 8; i += 256) {
        const float4 v0 = *reinterpret_cast<const float4*>(ebase + (size_t)i * 8);
        const float4 v1 = *reinterpret_cast<const float4*>(ebase + (size_t)i * 8 + 4);
        *reinterpret_cast<uint4*>(&es[i * 8]) = pack_bf8(v0, v1);
    }
    for (int d = tid; d < ND; d += 256) {
        float acc = 0.f;
        #pragma unroll
        for (int s = 0; s < 8; ++s)
            acc += bf2f(qkp[((size_t)s * NB + b) * ND + d]);
        qs[d] = acc;
    }
    __syncthreads();

    const int wave = tid >> 6, lane = tid & 63;
    const float scale = 0.05103103630798288f;  // 1/sqrt(384)

    for (int m = wave; m < NM; m += 4) {
        float s = 0.f;
        for (int d = lane; d < ND; d += 64) s = fmaf(bf2f(es[m * ND + d]), qs[d], s);
        #pragma unroll
        for (int off = 32; off; off >>= 1) s += __shfl_xor(s, off);
        if (lane == 0) sc[m] = s * scale;
    }
    __syncthreads();

    const int len = lengths[b];
    if (tid < 64) {
        float s = (tid < len) ? sc[tid] : -INFINITY;
        float mx = s;
        #pragma unroll
        for (int off = 32; off; off >>= 1) mx = fmaxf(mx, __shfl_xor(mx, off));
        float e = (tid < len) ? expf(s - mx) : 0.f;
        float sum = e;
        #pragma unroll
        for (int off = 32; off; off >>= 1) sum += __shfl_xor(sum, off);
        sc[tid] = e / sum;
    }
    __syncthreads();

    for (int d = tid; d < ND; d += 256) {
        float acc = 0.f;
        for (int m = 0; m < len; ++m) acc = fmaf(sc[m], bf2f(es[m * ND + d]), acc);
        cb[(size_t)b * ND + d] = f2bf(acc);
    }
}

// ---------------------------------------------------------------------------
// BatchNorm over batch axis reading stacked heads hl [B,256].
// ---------------------------------------------------------------------------
__global__ __launch_bounds__(256) void bn_batch(const float* __restrict__ hl,
                                                const float* __restrict__ mbnb,
                                                const float* __restrict__ lbnb,
                                                float* __restrict__ mu,
                                                float* __restrict__ lv) {
    const int t = blockIdx.x;
    const int sel = blockIdx.y;
    const int col = sel ? 128 + t : t;
    const float* bnb = sel ? lbnb : mbnb;
    float* dst = sel ? lv : mu;
    const int tid = threadIdx.x;

    float s = 0.f, ss = 0.f;
    for (int b = tid; b < NB; b += 256) {
        const float v = hl[(size_t)b * NHS + col];
        s += v; ss += v * v;
    }
    __shared__ float rs[256], rss[256];
    rs[tid] = s; rss[tid] = ss;
    __syncthreads();
    for (int off = 128; off; off >>= 1) {
        if (tid < off) { rs[tid] += rs[tid + off]; rss[tid] += rss[tid + off]; }
        __syncthreads();
    }
    const float mean = rs[0] / (float)NB;
    const float var = rss[0] / (float)NB - mean * mean;
    const float rstd = rsqrtf(var + EPS);
    const float bb = bnb[t];
    for (int b = tid; b < NB; b += 256) {
        dst[(size_t)b * NT + t] = (hl[(size_t)b * NHS + col] - mean) * rstd + bb;
    }
}

// ---------------------------------------------------------------------------
// Per-row softmax over T -> thetab (bf16, zero-padded to 128) + KL partial.
// ---------------------------------------------------------------------------
__global__ __launch_bounds__(128) void theta_kl(const float* __restrict__ mu,
                                                const float* __restrict__ lv,
                                                unsigned short* __restrict__ thetab,
                                                float* __restrict__ kld_p) {
    const int b = blockIdx.x, tid = threadIdx.x;
    const float var2 = 1.0f - 1.0f / (float)NT;
    const float inv_var2 = 1.0f / var2;
    __shared__ float red[128];

    const float m = (tid < NT) ? mu[(size_t)b * NT + tid] : -INFINITY;
    red[tid] = m;
    __syncthreads();
    for (int off = 64; off; off >>= 1) {
        if (tid < off) red[tid] = fmaxf(red[tid], red[tid + off]);
        __syncthreads();
    }
    const float mx = red[0];
    __syncthreads();

    const float e = (tid < NT) ? expf(m - mx) : 0.f;
    red[tid] = e;
    __syncthreads();
    for (int off = 64; off; off >>= 1) {
        if (tid < off) red[tid] += red[tid + off];
        __syncthreads();
    }
    const float sum = red[0];
    __syncthreads();
    thetab[(size_t)b * NKP + tid] = (tid < NT) ? f2bf(e / sum) : (unsigned short)0;

    float term = 0.f;
    if (tid < NT) {
        const float l = lv[(size_t)b * NT + tid];
        term = expf(l) * inv_var2 + m * m * inv_var2 - l;
    }
    red[tid] = term;
    __syncthreads();
    for (int off = 64; off; off >>= 1) {
        if (tid < off) red[tid] += red[tid + off];
        __syncthreads();
    }
    if (tid == 0)
        kld_p[b] = 0.5f * (red[0] + (float)NT * logf(var2) - (float)NT);
}

// ---------------------------------------------------------------------------
// Combine the 8 per-wave column partials -> cmu, crstd.
// ---------------------------------------------------------------------------
__global__ __launch_bounds__(256) void stats_final(const float* __restrict__ colp,
                                                   float* __restrict__ cmu,
                                                   float* __restrict__ crstd) {
    const int v = blockIdx.x * 256 + threadIdx.x;
    if (v >= NV) return;
    float s = 0.f, q = 0.f;
    #pragma unroll
    for (int w = 0; w < 8; ++w) {
        s += colp[(size_t)w * NVP + v];
        q += colp[(size_t)(8 + w) * NVP + v];
    }
    const float mean = s / (float)NB;
    cmu[v] = mean;
    crstd[v] = rsqrtf(q / (float)NB - mean * mean + EPS);
}

// ---------------------------------------------------------------------------
// SINGLE pass over bf16 logit + f32 x:
// online LSE of z; xz = sum x*z; xs = sum x; recon_p = xz - lse*xs.
// ---------------------------------------------------------------------------
__global__ __launch_bounds__(256) void row_recon(const unsigned short* __restrict__ logitb,
                                                 const float* __restrict__ x,
                                                 const float* __restrict__ cmu,
                                                 const float* __restrict__ crstd,
                                                 const float* __restrict__ dbnb,
                                                 float* __restrict__ recon_p) {
    const int b = blockIdx.x, tid = threadIdx.x;
    const unsigned short* lr = logitb + (size_t)b * NV;
    const float* xr = x + (size_t)b * NV;

    float m_i = -INFINITY, s_i = 0.f, xz = 0.f, xs = 0.f;
    for (int v = tid * 8; v < NV; v += 2048) {
        union { uint4 v4; unsigned short u[8]; } lw;
        lw.v4 = *reinterpret_cast<const uint4*>(lr + v);
        const float4 x0 = *reinterpret_cast<const float4*>(xr + v);
        const float4 x1 = *reinterpret_cast<const float4*>(xr + v + 4);
        const float4 c0 = *reinterpret_cast<const float4*>(cmu + v);
        const float4 c1 = *reinterpret_cast<const float4*>(cmu + v + 4);
        const float4 r0 = *reinterpret_cast<const float4*>(crstd + v);
        const float4 r1 = *reinterpret_cast<const float4*>(crstd + v + 4);
        const float4 d0 = *reinterpret_cast<const float4*>(dbnb + v);
        const float4 d1 = *reinterpret_cast<const float4*>(dbnb + v + 4);
        const float xv[8] = {x0.x,x0.y,x0.z,x0.w,x1.x,x1.y,x1.z,x1.w};
        const float cm[8] = {c0.x,c0.y,c0.z,c0.w,c1.x,c1.y,c1.z,c1.w};
        const float cr[8] = {r0.x,r0.y,r0.z,r0.w,r1.x,r1.y,r1.z,r1.w};
        const float db[8] = {d0.x,d0.y,d0.z,d0.w,d1.x,d1.y,d1.z,d1.w};
        float z[8];
        #pragma unroll
        for (int j = 0; j < 8; ++j)
            z[j] = fmaf(bf2f(lw.u[j]) - cm[j], cr[j], db[j]);
        float mx = z[0];
        #pragma unroll
        for (int j = 1; j < 8; ++j) mx = fmaxf(mx, z[j]);
        const float mnew = fmaxf(m_i, mx);
        float e8 = 0.f;
        #pragma unroll
        for (int j = 0; j < 8; ++j) e8 += expf(z[j] - mnew);
        s_i = s_i * expf(m_i - mnew) + e8;
        m_i = mnew;
        #pragma unroll
        for (int j = 0; j < 8; ++j) {
            xz = fmaf(xv[j], z[j], xz);
            xs += xv[j];
        }
    }

    __shared__ float rm[256], rs[256], rxz[256], rxs[256];
    rm[tid] = m_i; rs[tid] = s_i; rxz[tid] = xz; rxs[tid] = xs;
    __syncthreads();
    for (int off = 128; off; off >>= 1) {
        if (tid < off) {
            const float m1 = rm[tid], m2 = rm[tid + off];
            const float s1 = rs[tid], s2 = rs[tid + off];
            const float mm = fmaxf(m1, m2);
            rm[tid] = mm;
            rs[tid] = s1 * expf(m1 - mm) + s2 * expf(m2 - mm);
            rxz[tid] += rxz[tid + off];
            rxs[tid] += rxs[tid + off];
        }
        __syncthreads();
    }
    if (tid == 0) {
        const float lse = rm[0] + logf(rs[0]);
        recon_p[b] = rxz[0] - lse * rxs[0];
    }
}

// ---------------------------------------------------------------------------
// Final: out = -mean(recon_p) + mean(kld_p)
// ---------------------------------------------------------------------------
__global__ __launch_bounds__(512) void finalize(const float* __restrict__ recon_p,
                                                const float* __restrict__ kld_p,
                                                float* __restrict__ out) {
    const int tid = threadIdx.x;
    __shared__ float r1[512], r2[512];
    r1[tid] = recon_p[tid];
    r2[tid] = kld_p[tid];
    __syncthreads();
    for (int off = 256; off; off >>= 1) {
        if (tid < off) { r1[tid] += r1[tid + off]; r2[tid] += r2[tid + off]; }
        __syncthreads();
    }
    if (tid == 0) out[0] = (-r1[0] + r2[0]) / (float)NB;
}

extern "C" void kernel_launch(void* const* d_in, const int* in_sizes, int n_in,
                              void* d_out, int out_size, void* d_ws, size_t ws_size,
                              hipStream_t stream) {
    const float* x       = (const float*)d_in[0];
    const float* emb     = (const float*)d_in[1];
    const int*   lengths = (const int*)d_in[2];
    const float* fc11_w  = (const float*)d_in[3];
    const float* fc11_b  = (const float*)d_in[4];
    const float* fc12_w  = (const float*)d_in[5];
    const float* fc12_b  = (const float*)d_in[6];
    const float* q_w     = (const float*)d_in[7];
    const float* q_b     = (const float*)d_in[8];
    const float* k_w     = (const float*)d_in[9];
    // d_in[10] = k_b: cancels in softmax -> unused
    const float* v_w     = (const float*)d_in[11];
    const float* v_b     = (const float*)d_in[12];
    const float* mean_w  = (const float*)d_in[13];
    const float* mean_b  = (const float*)d_in[14];
    const float* lvw     = (const float*)d_in[15];
    const float* lvb     = (const float*)d_in[16];
    const float* mbnb    = (const float*)d_in[17];
    const float* lbnb    = (const float*)d_in[18];
    const float* dec_w   = (const float*)d_in[19];
    const float* dec_b   = (const float*)d_in[20];
    const float* dbnb    = (const float*)d_in[21];
    float* out = (float*)d_out;

    char* base = (char*)d_ws;
    size_t off = 0;
    auto alloc = [&](size_t bytes) -> void* {
        void* p = base + off;
        off += (bytes + 255) & ~(size_t)255;
        return p;
    };

    unsigned short* w12b   = (unsigned short*)alloc((size_t)NE * NE * 2);
    unsigned short* e1b    = (unsigned short*)alloc((size_t)NB * NE * 2);
    unsigned short* hb     = (unsigned short*)alloc((size_t)NB * NE * 2);
    unsigned short* qwb    = (unsigned short*)alloc((size_t)ND * NE * 2);
    unsigned short* kTb    = (unsigned short*)alloc((size_t)ND * ND * 2);
    unsigned short* vwb    = (unsigned short*)alloc((size_t)ND * ND * 2);
    unsigned short* qb     = (unsigned short*)alloc((size_t)NB * ND * 2);
    unsigned short* cb     = (unsigned short*)alloc((size_t)NB * ND * 2);
    unsigned short* dib    = (unsigned short*)alloc((size_t)NB * ND * 2);
    unsigned short* headwb = (unsigned short*)alloc((size_t)NHS * ND * 2);
    float*          headbb = (float*)alloc((size_t)NHS * 4);
    float*          hl     = (float*)alloc((size_t)NB * NHS * 4);
    float*          mu     = (float*)alloc((size_t)NB * NT * 4);
    float*          lv     = (float*)alloc((size_t)NB * NT * 4);
    float*          colp   = (float*)alloc((size_t)16 * NVP * 4);
    float*          cmu    = (float*)alloc((size_t)NV * 4);
    float*          crstd  = (float*)alloc((size_t)NV * 4);
    float*          rp     = (float*)alloc((size_t)NB * 4);
    float*          kp     = (float*)alloc((size_t)NB * 4);
    unsigned short* decwb  = (unsigned short*)alloc((size_t)NVP * NKP * 2);
    unsigned short* thetab = (unsigned short*)alloc((size_t)NB * NKP * 2);
    // small-GEMM bf16 split-K partials (max: q S=16 -> 6.3 MB)
    unsigned short* smallp = (unsigned short*)alloc((size_t)16 * NB * ND * 2);
    // big partials LAST; logitb (20.5 MB, written by the much-later decoder
    // GEMM) aliases partb (dead after fc12 reduce).
    const size_t part_per_s = (size_t)NB * NE * 2;           // 1 MB per s
    const size_t logit_bytes = (size_t)NB * NV * 2;          // 20.5 MB
    const size_t remain = (ws_size > off) ? (ws_size - off) : 0;
    const int S11 = (remain >= 32 * part_per_s) ? 32
                  : (remain >= 16 * part_per_s + logit_bytes) ? 16 : 8;
    size_t part_alloc = S11 * part_per_s;
    if (part_alloc < logit_bytes) part_alloc = logit_bytes;
    unsigned short* partb = (unsigned short*)alloc(part_alloc);
    unsigned short* logitb = partb;

    const dim3 blk(256);

    // ---- one prep kernel: converts + transpose + head stack + dec_w pad ----
    prep_kernel<<<PREP_BLOCKS, blk, 0, stream>>>(
        fc12_w, w12b, q_w, qwb, v_w, vwb, k_w, kTb,
        mean_w, lvw, mean_b, lvb, headwb, headbb, dec_w, decwb);

    // ---- fc11: e1 = softplus(x @ fc11_w^T + b), 256x256 fused-convert ----
    gemm_f32_256<<<8 * S11, 512, 0, stream>>>(
        x, fc11_w, partb, NB, NE, NV, S11, NV / BK);
    reduce_splitk_bf<1, 1, 1><<<(NB * NE) / 2048, blk, 0, stream>>>(
        partb, fc11_b, e1b, NB * NE, NE, S11);

    // ---- fc12: h = softplus(e1 @ fc12_w^T + b) ----
    gemm_mfma_splitk<<<dim3(NE / BN, NB / BM, 8), blk, 0, stream>>>(
        e1b, w12b, partb, NB, NE, NE, 8, NE / BK);
    reduce_splitk_bf<1, 1, 1><<<(NB * NE) / 2048, blk, 0, stream>>>(
        partb, fc12_b, hb, NB * NE, NE, 8);

    // ---- q = h @ q_w^T + q_b (bf16) ----
    gemm64_splitk<<<dim3(ND / 64, NB / 64, 16), blk, 0, stream>>>(
        hb, qwb, smallp, NB, ND, NE, 16, NE / BK);
    reduce_splitk_bf<1, 0, 1><<<(NB * ND) / 2048, blk, 0, stream>>>(
        smallp, q_b, qb, NB * ND, ND, 16);
    // ---- qk = q @ k_w (via kT): partials only; reduce fused into attn ----
    gemm64_splitk<<<dim3(ND / 64, NB / 64, 8), blk, 0, stream>>>(
        qb, kTb, smallp, NB, ND, ND, 8, ND / BK);
    // ---- fused attention (+qk reduce) -> cb = bf16(sum_m alpha*emb) ----
    attn_kernel<<<NB, 256, 0, stream>>>(smallp, emb, lengths, cb);
    // ---- d_i = c @ v_w^T + v_b (bf16) ----
    gemm64_splitk<<<dim3(ND / 64, NB / 64, 8), blk, 0, stream>>>(
        cb, vwb, smallp, NB, ND, ND, 8, ND / BK);
    reduce_splitk_bf<1, 0, 1><<<(NB * ND) / 2048, blk, 0, stream>>>(
        smallp, v_b, dib, NB * ND, ND, 8);
    // ---- stacked heads: hl = d_i @ headw^T + headb (f32 [B,256]) ----
    gemm64_splitk<<<dim3(NHS / 64, NB / 64, 8), blk, 0, stream>>>(
        dib, headwb, smallp, NB, NHS, ND, 8, ND / BK);
    reduce_splitk_bf<0, 0, 1><<<(NB * NHS) / 2048, blk, 0, stream>>>(
        smallp, headbb, hl, NB * NHS, NHS, 8);
    // ---- batchnorm both heads ----
    bn_batch<<<dim3(NT, 2), blk, 0, stream>>>(hl, mbnb, lbnb, mu, lv);
    // ---- theta softmax (bf16 padded) + KL partials ----
    theta_kl<<<NB, 128, 0, stream>>>(mu, lv, thetab, kp);
    // ---- decoder logits (bf16) + fused column stats partials ----
    gemm_mfma<1, 0, 1, 1><<<dim3(NVP / BN, NB / BM), blk, 0, stream>>>(
        thetab, decwb, dec_b, logitb, colp, NB, NV, NKP);
    stats_final<<<(NV + 255) / 256, blk, 0, stream>>>(colp, cmu, crstd);
    // ---- single-pass log-softmax dot x (f32 x) ----
    row_recon<<<NB, 256, 0, stream>>>(logitb, x, cmu, crstd, dbnb, rp);
    // ---- final scalar ----
    finalize<<<1, 512, 0, stream>>>(rp, kp, out);
}